// Round 2
// baseline (28323.715 us; speedup 1.0000x reference)
//
#include <hip/hip_runtime.h>
#include <hip/hip_bf16.h>

#define N_NODES 40000
#define N_EDGES 640000
#define IN_CH 64
#define HID 128
#define N_LAYERS 3

typedef unsigned short u16;
typedef unsigned int u32;

__device__ __forceinline__ float bf2f(u16 u) {
    union { u32 i; float f; } v; v.i = ((u32)u) << 16; return v.f;
}
__device__ __forceinline__ u16 f2bf(float f) {
    union { float f; u32 i; } v; v.f = f;
    u32 i = v.i;
    u32 r = (i + 0x7fffu + ((i >> 16) & 1u)) >> 16;
    return (u16)r;
}
__device__ __forceinline__ float silu_f(float x) {
    return x / (1.0f + expf(-x));
}

// ---------------- dtype detection ----------------
// flags[0] = 1 if float inputs are bf16, 0 if fp32
// flags[1] = 1 if edge_index is int64, 0 if int32
__global__ void detect_kernel(const void* __restrict__ w_raw,
                              const void* __restrict__ eidx_raw,
                              int* __restrict__ flags) {
    __shared__ int s_big, s_hi;
    if (threadIdx.x == 0) { s_big = 0; s_hi = 0; }
    __syncthreads();
    const u16* w16 = (const u16*)w_raw;
    for (int i = threadIdx.x; i < 8192; i += blockDim.x) {
        float v = bf2f(w16[i]);
        if (!(fabsf(v) <= 1.0f)) s_big = 1;   // catches NaN too
    }
    const u32* e32 = (const u32*)eidx_raw;
    for (int i = threadIdx.x; i < 256; i += blockDim.x) {
        if (e32[2 * i + 1] != 0u) s_hi = 1;
    }
    __syncthreads();
    if (threadIdx.x == 0) {
        flags[0] = s_big ? 0 : 1;   // garbage under bf16 interp => fp32
        flags[1] = s_hi ? 0 : 1;    // any nonzero high word => int32
    }
}

// ---------------- conversions ----------------
__global__ void cvt_f_kernel(const void* __restrict__ in, float* __restrict__ out,
                             int n, const int* __restrict__ flags) {
    int i = blockIdx.x * blockDim.x + threadIdx.x;
    if (i >= n) return;
    out[i] = flags[0] ? bf2f(((const u16*)in)[i]) : ((const float*)in)[i];
}

__global__ void cvt_idx_kernel(const void* __restrict__ in, int* __restrict__ out,
                               int n, const int* __restrict__ flags) {
    int i = blockIdx.x * blockDim.x + threadIdx.x;
    if (i >= n) return;
    out[i] = flags[1] ? (int)(((const long long*)in)[i]) : ((const int*)in)[i];
}

// ---------------- degree ----------------
__global__ void deg_kernel(const int* __restrict__ dst, float* __restrict__ deg) {
    int i = blockIdx.x * blockDim.x + threadIdx.x;
    if (i < N_EDGES) atomicAdd(&deg[dst[i]], 1.0f);
}

// ---------------- pos init -> f32 ----------------
__global__ void posinit_kernel(const void* __restrict__ pos_raw, float* __restrict__ posf,
                               const int* __restrict__ flags) {
    int i = blockIdx.x * blockDim.x + threadIdx.x;
    if (i < N_NODES * 3)
        posf[i] = flags[0] ? bf2f(((const u16*)pos_raw)[i]) : ((const float*)pos_raw)[i];
}

// ---------------- embedding: h = x @ W + b ----------------
__global__ __launch_bounds__(64) void embed_kernel(
    const void* __restrict__ x_raw, const float* __restrict__ W, const float* __restrict__ b,
    float* __restrict__ h, const int* __restrict__ flags)
{
    __shared__ float s_x[IN_CH];
    const int n = blockIdx.x;
    const int t = threadIdx.x;
    const int isbf = flags[0];
    s_x[t] = isbf ? bf2f(((const u16*)x_raw)[n * IN_CH + t])
                  : ((const float*)x_raw)[n * IN_CH + t];
    __syncthreads();
    const int o = 2 * t;
    float a0 = b[o], a1 = b[o + 1];
#pragma unroll 8
    for (int i = 0; i < IN_CH; ++i) {
        float xi = s_x[i];
        float2 w = *(const float2*)(W + i * HID + o);
        a0 = fmaf(xi, w.x, a0);
        a1 = fmaf(xi, w.y, a1);
    }
    h[(size_t)n * HID + o] = a0;
    h[(size_t)n * HID + o + 1] = a1;
}

// ---------------- edge kernel: one wave per edge ----------------
__global__ __launch_bounds__(64) void edge_kernel(
    const int* __restrict__ src, const int* __restrict__ dst,
    const float* __restrict__ h, const float* __restrict__ posf,
    const float* __restrict__ W1, const float* __restrict__ b1,
    const float* __restrict__ W2, const float* __restrict__ b2,
    const float* __restrict__ pW1, const float* __restrict__ pb1,
    const float* __restrict__ pW2, const float* __restrict__ pb2,
    float* __restrict__ agg, float* __restrict__ pd)
{
    __shared__ float s_ein[257];
    __shared__ float s_rel[3];
    __shared__ float s_t1[HID];
    __shared__ float s_m[HID];

    const int e = blockIdx.x;
    const int t = threadIdx.x;   // 0..63
    const int s = src[e];
    const int d = dst[e];

    if (t < 3) s_rel[t] = posf[d * 3 + t] - posf[s * 3 + t];

    const int o = 2 * t;
    const float2 hd = *(const float2*)(h + (size_t)d * HID + o);
    const float2 hs = *(const float2*)(h + (size_t)s * HID + o);
    s_ein[o] = hd.x;  s_ein[o + 1] = hd.y;             // h_i = h[dst]
    s_ein[HID + o] = hs.x; s_ein[HID + o + 1] = hs.y;  // h_j = h[src]
    __syncthreads();
    if (t == 0) {
        float r0 = s_rel[0], r1 = s_rel[1], r2 = s_rel[2];
        s_ein[256] = r0 * r0 + r1 * r1 + r2 * r2;
    }
    __syncthreads();

    // ---- edge MLP layer 1: [257] -> [128], silu ----
    float a0 = b1[o], a1 = b1[o + 1];
#pragma unroll 4
    for (int i = 0; i < 2 * HID + 1; ++i) {
        float ei = s_ein[i];
        float2 w = *(const float2*)(W1 + (size_t)i * HID + o);
        a0 = fmaf(ei, w.x, a0);
        a1 = fmaf(ei, w.y, a1);
    }
    s_t1[o] = silu_f(a0);
    s_t1[o + 1] = silu_f(a1);
    __syncthreads();

    // ---- edge MLP layer 2: [128] -> [128], silu -> m ----
    a0 = b2[o]; a1 = b2[o + 1];
#pragma unroll 4
    for (int i = 0; i < HID; ++i) {
        float ti = s_t1[i];
        float2 w = *(const float2*)(W2 + (size_t)i * HID + o);
        a0 = fmaf(ti, w.x, a0);
        a1 = fmaf(ti, w.y, a1);
    }
    float m0 = silu_f(a0);
    float m1 = silu_f(a1);

    atomicAdd(&agg[(size_t)d * HID + o], m0);
    atomicAdd(&agg[(size_t)d * HID + o + 1], m1);

    s_m[o] = m0; s_m[o + 1] = m1;
    __syncthreads();

    // ---- pos MLP: silu(m @ pW1 + pb1) @ pW2 + pb2 -> scalar w ----
    a0 = pb1[o]; a1 = pb1[o + 1];
#pragma unroll 4
    for (int i = 0; i < HID; ++i) {
        float mi = s_m[i];
        float2 w = *(const float2*)(pW1 + (size_t)i * HID + o);
        a0 = fmaf(mi, w.x, a0);
        a1 = fmaf(mi, w.y, a1);
    }
    a0 = silu_f(a0);
    a1 = silu_f(a1);
    float2 w2 = *(const float2*)(pW2 + o);
    float pc = a0 * w2.x + a1 * w2.y;
#pragma unroll
    for (int off = 32; off > 0; off >>= 1) pc += __shfl_down(pc, off, 64);
    if (t == 0) {
        float w = pc + pb2[0];
        atomicAdd(&pd[(size_t)d * 3 + 0], s_rel[0] * w);
        atomicAdd(&pd[(size_t)d * 3 + 1], s_rel[1] * w);
        atomicAdd(&pd[(size_t)d * 3 + 2], s_rel[2] * w);
    }
}

// ---------------- node kernel: one wave per node ----------------
__global__ __launch_bounds__(64) void node_kernel(
    const float* __restrict__ h_in, const float* __restrict__ agg,
    const float* __restrict__ W1, const float* __restrict__ b1,
    const float* __restrict__ W2, const float* __restrict__ b2,
    float* __restrict__ h_out,
    float* __restrict__ posf, const float* __restrict__ pd, const float* __restrict__ deg)
{
    __shared__ float s_in[2 * HID];
    __shared__ float s_t1[HID];
    const int n = blockIdx.x;
    const int t = threadIdx.x;
    const int o = 2 * t;
    const float2 ha = *(const float2*)(h_in + (size_t)n * HID + o);
    const float2 ag = *(const float2*)(agg + (size_t)n * HID + o);
    s_in[o] = ha.x; s_in[o + 1] = ha.y;
    s_in[HID + o] = ag.x; s_in[HID + o + 1] = ag.y;
    __syncthreads();

    float a0 = b1[o], a1 = b1[o + 1];
#pragma unroll 4
    for (int i = 0; i < 2 * HID; ++i) {
        float xi = s_in[i];
        float2 w = *(const float2*)(W1 + (size_t)i * HID + o);
        a0 = fmaf(xi, w.x, a0);
        a1 = fmaf(xi, w.y, a1);
    }
    s_t1[o] = silu_f(a0);
    s_t1[o + 1] = silu_f(a1);
    __syncthreads();

    a0 = b2[o]; a1 = b2[o + 1];
#pragma unroll 4
    for (int i = 0; i < HID; ++i) {
        float ti = s_t1[i];
        float2 w = *(const float2*)(W2 + (size_t)i * HID + o);
        a0 = fmaf(ti, w.x, a0);
        a1 = fmaf(ti, w.y, a1);
    }
    h_out[(size_t)n * HID + o] = a0;
    h_out[(size_t)n * HID + o + 1] = a1;

    if (t < 3) {
        float dg = deg[n];
        dg = dg < 1.0f ? 1.0f : dg;
        posf[n * 3 + t] += pd[n * 3 + t] / dg;
    }
}

// ---------------- output: f32 -> (bf16 | f32) per flag ----------------
__global__ void out_kernel(const float* __restrict__ h, const float* __restrict__ posf,
                           void* __restrict__ out, const int* __restrict__ flags)
{
    int i = blockIdx.x * blockDim.x + threadIdx.x;
    const int isbf = flags[0];
    if (i < N_NODES * HID) {
        if (isbf) ((u16*)out)[i] = f2bf(h[i]);
        else      ((float*)out)[i] = h[i];
    }
    if (i < N_NODES * 3) {
        if (isbf) ((u16*)out)[N_NODES * HID + i] = f2bf(posf[i]);
        else      ((float*)out)[N_NODES * HID + i] = posf[i];
    }
}

extern "C" void kernel_launch(void* const* d_in, const int* in_sizes, int n_in,
                              void* d_out, int out_size, void* d_ws, size_t ws_size,
                              hipStream_t stream) {
    (void)in_sizes; (void)n_in; (void)out_size; (void)ws_size;

    const void* eidx_raw = d_in[0];
    const void* x_raw    = d_in[1];
    const void* pos_raw  = d_in[2];
    const void* embW_raw = d_in[3];
    const void* embB_raw = d_in[4];
    const void* eW1_raw  = d_in[5];
    const void* eB1_raw  = d_in[6];
    const void* eW2_raw  = d_in[7];
    const void* eB2_raw  = d_in[8];
    const void* nW1_raw  = d_in[9];
    const void* nB1_raw  = d_in[10];
    const void* nW2_raw  = d_in[11];
    const void* nB2_raw  = d_in[12];
    const void* pW1_raw  = d_in[13];
    const void* pB1_raw  = d_in[14];
    const void* pW2_raw  = d_in[15];
    const void* pB2_raw  = d_in[16];

    float* ws   = (float*)d_ws;
    float* h0   = ws;                            // 5,120,000
    float* h1   = h0 + (size_t)N_NODES * HID;    // 5,120,000
    float* posf = h1 + (size_t)N_NODES * HID;    //   120,000
    float* agg  = posf + (size_t)N_NODES * 3;    // 5,120,000
    float* pd   = agg + (size_t)N_NODES * HID;   //   120,000
    float* deg  = pd + (size_t)N_NODES * 3;      //    40,000
    float* wf   = deg + N_NODES;                 //   355,076 (converted fp32 weights)

    // converted-weight suballocation (fp32)
    float* embW = wf;                      // 64*128      = 8192
    float* embB = embW + 8192;             // 128
    float* eW1  = embB + 128;              // 3*257*128   = 98688
    float* eB1  = eW1 + 3 * 257 * HID;     // 384
    float* eW2  = eB1 + 3 * HID;           // 3*128*128   = 49152
    float* eB2  = eW2 + 3 * HID * HID;     // 384
    float* nW1  = eB2 + 3 * HID;           // 3*256*128   = 98304
    float* nB1  = nW1 + 3 * 2 * HID * HID; // 384
    float* nW2  = nB1 + 3 * HID;           // 49152
    float* nB2  = nW2 + 3 * HID * HID;     // 384
    float* pW1  = nB2 + 3 * HID;           // 49152
    float* pB1  = pW1 + 3 * HID * HID;     // 384
    float* pW2  = pB1 + 3 * HID;           // 384
    float* pB2  = pW2 + 3 * HID;           // 3 (+pad)
    float* wend = pB2 + 4;

    int* src32 = (int*)wend;               // 640,000
    int* dst32 = src32 + N_EDGES;          // 640,000
    int* flags = dst32 + N_EDGES;          // 2
    // total ws use ≈ 69.2 MB

    detect_kernel<<<1, 256, 0, stream>>>(embW_raw, eidx_raw, flags);

    cvt_idx_kernel<<<(2 * N_EDGES + 255) / 256, 256, 0, stream>>>(eidx_raw, src32, 2 * N_EDGES, flags);

    cvt_f_kernel<<<(8192 + 255) / 256, 256, 0, stream>>>(embW_raw, embW, 8192, flags);
    cvt_f_kernel<<<1, 128, 0, stream>>>(embB_raw, embB, 128, flags);
    cvt_f_kernel<<<(3 * 257 * HID + 255) / 256, 256, 0, stream>>>(eW1_raw, eW1, 3 * 257 * HID, flags);
    cvt_f_kernel<<<2, 256, 0, stream>>>(eB1_raw, eB1, 3 * HID, flags);
    cvt_f_kernel<<<(3 * HID * HID + 255) / 256, 256, 0, stream>>>(eW2_raw, eW2, 3 * HID * HID, flags);
    cvt_f_kernel<<<2, 256, 0, stream>>>(eB2_raw, eB2, 3 * HID, flags);
    cvt_f_kernel<<<(3 * 2 * HID * HID + 255) / 256, 256, 0, stream>>>(nW1_raw, nW1, 3 * 2 * HID * HID, flags);
    cvt_f_kernel<<<2, 256, 0, stream>>>(nB1_raw, nB1, 3 * HID, flags);
    cvt_f_kernel<<<(3 * HID * HID + 255) / 256, 256, 0, stream>>>(nW2_raw, nW2, 3 * HID * HID, flags);
    cvt_f_kernel<<<2, 256, 0, stream>>>(nB2_raw, nB2, 3 * HID, flags);
    cvt_f_kernel<<<(3 * HID * HID + 255) / 256, 256, 0, stream>>>(pW1_raw, pW1, 3 * HID * HID, flags);
    cvt_f_kernel<<<2, 256, 0, stream>>>(pB1_raw, pB1, 3 * HID, flags);
    cvt_f_kernel<<<2, 256, 0, stream>>>(pW2_raw, pW2, 3 * HID, flags);
    cvt_f_kernel<<<1, 64, 0, stream>>>(pB2_raw, pB2, 3, flags);

    hipMemsetAsync(deg, 0, (size_t)N_NODES * sizeof(float), stream);
    deg_kernel<<<(N_EDGES + 255) / 256, 256, 0, stream>>>(dst32, deg);
    posinit_kernel<<<(N_NODES * 3 + 255) / 256, 256, 0, stream>>>(pos_raw, posf, flags);
    embed_kernel<<<N_NODES, 64, 0, stream>>>(x_raw, embW, embB, h0, flags);

    float* hin = h0;
    float* hout = h1;
    for (int l = 0; l < N_LAYERS; ++l) {
        // agg and pd are contiguous -> single memset
        hipMemsetAsync(agg, 0, ((size_t)N_NODES * HID + (size_t)N_NODES * 3) * sizeof(float), stream);
        edge_kernel<<<N_EDGES, 64, 0, stream>>>(
            src32, dst32, hin, posf,
            eW1 + (size_t)l * 257 * HID, eB1 + (size_t)l * HID,
            eW2 + (size_t)l * HID * HID, eB2 + (size_t)l * HID,
            pW1 + (size_t)l * HID * HID, pB1 + (size_t)l * HID,
            pW2 + (size_t)l * HID,       pB2 + (size_t)l,
            agg, pd);
        node_kernel<<<N_NODES, 64, 0, stream>>>(
            hin, agg,
            nW1 + (size_t)l * 2 * HID * HID, nB1 + (size_t)l * HID,
            nW2 + (size_t)l * HID * HID,     nB2 + (size_t)l * HID,
            hout, posf, pd, deg);
        float* tmp = hin; hin = hout; hout = tmp;
    }

    out_kernel<<<(N_NODES * HID + 255) / 256, 256, 0, stream>>>(hin, posf, d_out, flags);
}

// Round 3
// 3002.172 us; speedup vs baseline: 9.4344x; 9.4344x over previous
//
#include <hip/hip_runtime.h>
#include <hip/hip_bf16.h>

#define N_NODES 40000
#define N_EDGES 640000
#define IN_CH 64
#define HID 128
#define N_LAYERS 3

typedef unsigned short u16;
typedef unsigned int u32;

typedef __attribute__((ext_vector_type(8))) __bf16 bf16x8;
typedef __attribute__((ext_vector_type(4))) float float4v;

__device__ __forceinline__ float bf2f(u16 u) {
    union { u32 i; float f; } v; v.i = ((u32)u) << 16; return v.f;
}
__device__ __forceinline__ u16 f2bf(float f) {
    union { float f; u32 i; } v; v.f = f;
    u32 i = v.i;
    u32 r = (i + 0x7fffu + ((i >> 16) & 1u)) >> 16;
    return (u16)r;
}
__device__ __forceinline__ float silu_f(float x) {
    return x / (1.0f + expf(-x));
}

// ---------------- dtype detection ----------------
__global__ void detect_kernel(const void* __restrict__ w_raw,
                              const void* __restrict__ eidx_raw,
                              int* __restrict__ flags) {
    __shared__ int s_big, s_hi;
    if (threadIdx.x == 0) { s_big = 0; s_hi = 0; }
    __syncthreads();
    const u16* w16 = (const u16*)w_raw;
    for (int i = threadIdx.x; i < 8192; i += blockDim.x) {
        float v = bf2f(w16[i]);
        if (!(fabsf(v) <= 1.0f)) s_big = 1;   // catches NaN too
    }
    const u32* e32 = (const u32*)eidx_raw;
    for (int i = threadIdx.x; i < 256; i += blockDim.x) {
        if (e32[2 * i + 1] != 0u) s_hi = 1;
    }
    __syncthreads();
    if (threadIdx.x == 0) {
        flags[0] = s_big ? 0 : 1;   // 1 => floats are bf16
        flags[1] = s_hi ? 0 : 1;    // 1 => edge_index int64
    }
}

// ---------------- conversions ----------------
__global__ void cvt_f_kernel(const void* __restrict__ in, float* __restrict__ out,
                             int n, const int* __restrict__ flags) {
    int i = blockIdx.x * blockDim.x + threadIdx.x;
    if (i >= n) return;
    out[i] = flags[0] ? bf2f(((const u16*)in)[i]) : ((const float*)in)[i];
}

__global__ void cvt_idx_kernel(const void* __restrict__ in, int* __restrict__ out,
                               int n, const int* __restrict__ flags) {
    int i = blockIdx.x * blockDim.x + threadIdx.x;
    if (i >= n) return;
    out[i] = flags[1] ? (int)(((const long long*)in)[i]) : ((const int*)in)[i];
}

// transpose + cvt to bf16: out[l][n][k] = in[l][k][n]; n in [0,128), k in [0,2^kshift)
__global__ void tcvt_kernel(const void* __restrict__ in, u16* __restrict__ out,
                            int count, int kshift, int inLS, int outLS,
                            const int* __restrict__ flags) {
    int l = blockIdx.y;
    int i = blockIdx.x * blockDim.x + threadIdx.x;
    if (i >= count) return;
    int n = i >> kshift, k = i & ((1 << kshift) - 1);
    int si = inLS * l + k * HID + n;
    float v = flags[0] ? bf2f(((const u16*)in)[si]) : ((const float*)in)[si];
    out[(size_t)outLS * l + i] = f2bf(v);
}

// W1 row 256 (the d2 row), fp32: out[l*128+n] = W1[l][256][n]
__global__ void w1row_kernel(const void* __restrict__ in, float* __restrict__ out,
                             const int* __restrict__ flags) {
    int i = blockIdx.x * blockDim.x + threadIdx.x;
    if (i >= 384) return;
    int l = i >> 7, n = i & 127;
    int si = l * (257 * 128) + 256 * 128 + n;
    out[i] = flags[0] ? bf2f(((const u16*)in)[si]) : ((const float*)in)[si];
}

// ---------------- degree ----------------
__global__ void deg_kernel(const int* __restrict__ dst, float* __restrict__ deg) {
    int i = blockIdx.x * blockDim.x + threadIdx.x;
    if (i < N_EDGES) atomicAdd(&deg[dst[i]], 1.0f);
}

// ---------------- pos init -> f32 ----------------
__global__ void posinit_kernel(const void* __restrict__ pos_raw, float* __restrict__ posf,
                               const int* __restrict__ flags) {
    int i = blockIdx.x * blockDim.x + threadIdx.x;
    if (i < N_NODES * 3)
        posf[i] = flags[0] ? bf2f(((const u16*)pos_raw)[i]) : ((const float*)pos_raw)[i];
}

// ---------------- embedding: h = x @ W + b ----------------
__global__ __launch_bounds__(64) void embed_kernel(
    const void* __restrict__ x_raw, const float* __restrict__ W, const float* __restrict__ b,
    float* __restrict__ h, const int* __restrict__ flags)
{
    __shared__ float s_x[IN_CH];
    const int n = blockIdx.x;
    const int t = threadIdx.x;
    const int isbf = flags[0];
    s_x[t] = isbf ? bf2f(((const u16*)x_raw)[n * IN_CH + t])
                  : ((const float*)x_raw)[n * IN_CH + t];
    __syncthreads();
    const int o = 2 * t;
    float a0 = b[o], a1 = b[o + 1];
#pragma unroll 8
    for (int i = 0; i < IN_CH; ++i) {
        float xi = s_x[i];
        float2 w = *(const float2*)(W + i * HID + o);
        a0 = fmaf(xi, w.x, a0);
        a1 = fmaf(xi, w.y, a1);
    }
    h[(size_t)n * HID + o] = a0;
    h[(size_t)n * HID + o + 1] = a1;
}

// ================= MFMA edge kernel =================
// 64 edges / block, 256 threads (4 waves). Wave w handles edge rows [16w,16w+16),
// all 128 output cols as 8 16x16 tiles. Weights pre-transposed to [n][k] bf16,
// staged into LDS in 64-k chunks. fp32 accumulators, d2+bias folded into init.
#define TILE_E 64
#define EIN_STRIDE 272   // u16; 64 rows x 272 = 17408 u16 (also holds t1+m later)
#define ACT_STRIDE 136   // u16
#define W_STRIDE 72      // u16 (64 k + 8 pad)

__global__ __launch_bounds__(256, 2) void edge_mfma_kernel(
    const int* __restrict__ src, const int* __restrict__ dst,
    const float* __restrict__ h, const float* __restrict__ posf,
    const u16* __restrict__ W1t, const float* __restrict__ W1r256, const float* __restrict__ b1,
    const u16* __restrict__ W2t, const float* __restrict__ b2,
    const u16* __restrict__ pW1t, const float* __restrict__ pb1,
    const float* __restrict__ pW2, const float* __restrict__ pb2,
    float* __restrict__ agg, float* __restrict__ pd)
{
    __shared__ u16 s_big[TILE_E * EIN_STRIDE];   // e_in; later t1 ([0,8704)) + m ([8704,17408))
    __shared__ u16 s_w[128 * W_STRIDE];          // weight chunk [n=0..127][k=0..63]
    __shared__ float s_d2[TILE_E];
    __shared__ float s_rel[TILE_E * 3];
    __shared__ int s_dstn[TILE_E];

    const int t = threadIdx.x;
    const int e0 = blockIdx.x * TILE_E;
    const int wv = t >> 6, lane = t & 63, quad = lane >> 4, li = lane & 15;
    const int rowA = wv * 16 + li;        // A-frag row (edge in tile)
    const int rowC = wv * 16 + quad * 4;  // C-frag row base

    // ---- gather phase ----
    if (t < TILE_E) {
        int e = e0 + t;
        int sN = src[e], dN = dst[e];
        s_dstn[t] = dN;
        float r0 = posf[dN * 3 + 0] - posf[sN * 3 + 0];
        float r1 = posf[dN * 3 + 1] - posf[sN * 3 + 1];
        float r2 = posf[dN * 3 + 2] - posf[sN * 3 + 2];
        s_rel[t * 3 + 0] = r0; s_rel[t * 3 + 1] = r1; s_rel[t * 3 + 2] = r2;
        s_d2[t] = r0 * r0 + r1 * r1 + r2 * r2;
    }
    {   // h gather: 4 threads per edge, 32 floats each from h[dst] and h[src]
        int el = t >> 2, part = t & 3;
        int e = e0 + el;
        int dN = dst[e], sN = src[e];
        const float* hd = h + (size_t)dN * HID + part * 32;
        const float* hs = h + (size_t)sN * HID + part * 32;
        u16* rowp = s_big + el * EIN_STRIDE + part * 32;
#pragma unroll
        for (int j = 0; j < 8; ++j) {
            float4 v = *(const float4*)(hd + j * 4);
            *(u32*)(rowp + j * 4)     = (u32)f2bf(v.x) | ((u32)f2bf(v.y) << 16);
            *(u32*)(rowp + j * 4 + 2) = (u32)f2bf(v.z) | ((u32)f2bf(v.w) << 16);
        }
        rowp += HID;
#pragma unroll
        for (int j = 0; j < 8; ++j) {
            float4 v = *(const float4*)(hs + j * 4);
            *(u32*)(rowp + j * 4)     = (u32)f2bf(v.x) | ((u32)f2bf(v.y) << 16);
            *(u32*)(rowp + j * 4 + 2) = (u32)f2bf(v.z) | ((u32)f2bf(v.w) << 16);
        }
    }
    // stage W1 chunk 0 (128 rows x 32 u32)
    {
        const u32* g = (const u32*)W1t;  // row stride 128 u32 (256 bf16)
        u32* sw = (u32*)s_w;
        for (int i = t; i < 4096; i += 256) {
            int n = i >> 5, kk = i & 31;
            sw[n * 36 + kk] = g[n * 128 + kk];
        }
    }
    __syncthreads();

    // ---- layer 1: [257] -> [128] ----
    float4v acc[8];
#pragma unroll
    for (int c = 0; c < 8; ++c) {
        int col = c * 16 + li;
        float bias = b1[col];
        float w2 = W1r256[col];
#pragma unroll
        for (int r = 0; r < 4; ++r) acc[c][r] = bias + s_d2[rowC + r] * w2;
    }
#pragma unroll
    for (int p = 0; p < 4; ++p) {
        if (p) {
            __syncthreads();
            const u32* g = (const u32*)W1t;
            u32* sw = (u32*)s_w;
            for (int i = t; i < 4096; i += 256) {
                int n = i >> 5, kk = i & 31;
                sw[n * 36 + kk] = g[n * 128 + p * 32 + kk];
            }
            __syncthreads();
        }
#pragma unroll
        for (int kk2 = 0; kk2 < 2; ++kk2) {
            const bf16x8 av = *(const bf16x8*)(s_big + rowA * EIN_STRIDE + p * 64 + kk2 * 32 + quad * 8);
#pragma unroll
            for (int c = 0; c < 8; ++c) {
                const bf16x8 bv = *(const bf16x8*)(s_w + (c * 16 + li) * W_STRIDE + kk2 * 32 + quad * 8);
                acc[c] = __builtin_amdgcn_mfma_f32_16x16x32_bf16(av, bv, acc[c], 0, 0, 0);
            }
        }
    }

    // ---- t1 = silu(acc); write to LDS (overlays dead e_in); stage W2 chunk 0 ----
    __syncthreads();
    u16* s_t1 = s_big;
    u16* s_m  = s_big + TILE_E * ACT_STRIDE;
#pragma unroll
    for (int c = 0; c < 8; ++c) {
        int col = c * 16 + li;
#pragma unroll
        for (int r = 0; r < 4; ++r)
            s_t1[(rowC + r) * ACT_STRIDE + col] = f2bf(silu_f(acc[c][r]));
    }
    {
        const u32* g = (const u32*)W2t;  // row stride 64 u32
        u32* sw = (u32*)s_w;
        for (int i = t; i < 4096; i += 256) {
            int n = i >> 5, kk = i & 31;
            sw[n * 36 + kk] = g[n * 64 + kk];
        }
    }
    __syncthreads();

    // ---- layer 2: [128] -> [128] -> m ----
#pragma unroll
    for (int c = 0; c < 8; ++c) {
        float bias = b2[c * 16 + li];
#pragma unroll
        for (int r = 0; r < 4; ++r) acc[c][r] = bias;
    }
#pragma unroll
    for (int p = 0; p < 2; ++p) {
        if (p) {
            __syncthreads();
            const u32* g = (const u32*)W2t;
            u32* sw = (u32*)s_w;
            for (int i = t; i < 4096; i += 256) {
                int n = i >> 5, kk = i & 31;
                sw[n * 36 + kk] = g[n * 64 + 32 + kk];
            }
            __syncthreads();
        }
#pragma unroll
        for (int kk2 = 0; kk2 < 2; ++kk2) {
            const bf16x8 av = *(const bf16x8*)(s_t1 + rowA * ACT_STRIDE + p * 64 + kk2 * 32 + quad * 8);
#pragma unroll
            for (int c = 0; c < 8; ++c) {
                const bf16x8 bv = *(const bf16x8*)(s_w + (c * 16 + li) * W_STRIDE + kk2 * 32 + quad * 8);
                acc[c] = __builtin_amdgcn_mfma_f32_16x16x32_bf16(av, bv, acc[c], 0, 0, 0);
            }
        }
    }

    // ---- m epilogue: atomics into agg (fp32), write m to LDS (bf16) ----
#pragma unroll
    for (int c = 0; c < 8; ++c) {
        int col = c * 16 + li;
#pragma unroll
        for (int r = 0; r < 4; ++r) {
            float m = silu_f(acc[c][r]);
            int row = rowC + r;
            atomicAdd(&agg[(size_t)s_dstn[row] * HID + col], m);
            s_m[row * ACT_STRIDE + col] = f2bf(m);
        }
    }
    __syncthreads();
    // stage pW1 chunk 0
    {
        const u32* g = (const u32*)pW1t;
        u32* sw = (u32*)s_w;
        for (int i = t; i < 4096; i += 256) {
            int n = i >> 5, kk = i & 31;
            sw[n * 36 + kk] = g[n * 64 + kk];
        }
    }
    __syncthreads();

    // ---- pos MLP: t2 = silu(m @ pW1 + pb1); w = t2 . pW2 + pb2 ----
#pragma unroll
    for (int c = 0; c < 8; ++c) {
        float bias = pb1[c * 16 + li];
#pragma unroll
        for (int r = 0; r < 4; ++r) acc[c][r] = bias;
    }
#pragma unroll
    for (int p = 0; p < 2; ++p) {
        if (p) {
            __syncthreads();
            const u32* g = (const u32*)pW1t;
            u32* sw = (u32*)s_w;
            for (int i = t; i < 4096; i += 256) {
                int n = i >> 5, kk = i & 31;
                sw[n * 36 + kk] = g[n * 64 + 32 + kk];
            }
            __syncthreads();
        }
#pragma unroll
        for (int kk2 = 0; kk2 < 2; ++kk2) {
            const bf16x8 av = *(const bf16x8*)(s_m + rowA * ACT_STRIDE + p * 64 + kk2 * 32 + quad * 8);
#pragma unroll
            for (int c = 0; c < 8; ++c) {
                const bf16x8 bv = *(const bf16x8*)(s_w + (c * 16 + li) * W_STRIDE + kk2 * 32 + quad * 8);
                acc[c] = __builtin_amdgcn_mfma_f32_16x16x32_bf16(av, bv, acc[c], 0, 0, 0);
            }
        }
    }
    float part[4] = {0.f, 0.f, 0.f, 0.f};
#pragma unroll
    for (int c = 0; c < 8; ++c) {
        float pw = pW2[c * 16 + li];
#pragma unroll
        for (int r = 0; r < 4; ++r) part[r] += silu_f(acc[c][r]) * pw;
    }
#pragma unroll
    for (int r = 0; r < 4; ++r) {
        part[r] += __shfl_xor(part[r], 1, 64);
        part[r] += __shfl_xor(part[r], 2, 64);
        part[r] += __shfl_xor(part[r], 4, 64);
        part[r] += __shfl_xor(part[r], 8, 64);
    }
    if (li == 0) {
        float pb2v = pb2[0];
#pragma unroll
        for (int r = 0; r < 4; ++r) {
            int row = rowC + r;
            float w = part[r] + pb2v;
            int dN = s_dstn[row];
            atomicAdd(&pd[(size_t)dN * 3 + 0], s_rel[row * 3 + 0] * w);
            atomicAdd(&pd[(size_t)dN * 3 + 1], s_rel[row * 3 + 1] * w);
            atomicAdd(&pd[(size_t)dN * 3 + 2], s_rel[row * 3 + 2] * w);
        }
    }
}

// ---------------- node kernel: one wave per node ----------------
__global__ __launch_bounds__(64) void node_kernel(
    const float* __restrict__ h_in, const float* __restrict__ agg,
    const float* __restrict__ W1, const float* __restrict__ b1,
    const float* __restrict__ W2, const float* __restrict__ b2,
    float* __restrict__ h_out,
    float* __restrict__ posf, const float* __restrict__ pd, const float* __restrict__ deg)
{
    __shared__ float s_in[2 * HID];
    __shared__ float s_t1[HID];
    const int n = blockIdx.x;
    const int t = threadIdx.x;
    const int o = 2 * t;
    const float2 ha = *(const float2*)(h_in + (size_t)n * HID + o);
    const float2 ag = *(const float2*)(agg + (size_t)n * HID + o);
    s_in[o] = ha.x; s_in[o + 1] = ha.y;
    s_in[HID + o] = ag.x; s_in[HID + o + 1] = ag.y;
    __syncthreads();

    float a0 = b1[o], a1 = b1[o + 1];
#pragma unroll 4
    for (int i = 0; i < 2 * HID; ++i) {
        float xi = s_in[i];
        float2 w = *(const float2*)(W1 + (size_t)i * HID + o);
        a0 = fmaf(xi, w.x, a0);
        a1 = fmaf(xi, w.y, a1);
    }
    s_t1[o] = silu_f(a0);
    s_t1[o + 1] = silu_f(a1);
    __syncthreads();

    a0 = b2[o]; a1 = b2[o + 1];
#pragma unroll 4
    for (int i = 0; i < HID; ++i) {
        float ti = s_t1[i];
        float2 w = *(const float2*)(W2 + (size_t)i * HID + o);
        a0 = fmaf(ti, w.x, a0);
        a1 = fmaf(ti, w.y, a1);
    }
    h_out[(size_t)n * HID + o] = a0;
    h_out[(size_t)n * HID + o + 1] = a1;

    if (t < 3) {
        float dg = deg[n];
        dg = dg < 1.0f ? 1.0f : dg;
        posf[n * 3 + t] += pd[n * 3 + t] / dg;
    }
}

// ---------------- output: f32 -> (bf16 | f32) per flag ----------------
__global__ void out_kernel(const float* __restrict__ h, const float* __restrict__ posf,
                           void* __restrict__ out, const int* __restrict__ flags)
{
    int i = blockIdx.x * blockDim.x + threadIdx.x;
    const int isbf = flags[0];
    if (i < N_NODES * HID) {
        if (isbf) ((u16*)out)[i] = f2bf(h[i]);
        else      ((float*)out)[i] = h[i];
    }
    if (i < N_NODES * 3) {
        if (isbf) ((u16*)out)[N_NODES * HID + i] = f2bf(posf[i]);
        else      ((float*)out)[N_NODES * HID + i] = posf[i];
    }
}

extern "C" void kernel_launch(void* const* d_in, const int* in_sizes, int n_in,
                              void* d_out, int out_size, void* d_ws, size_t ws_size,
                              hipStream_t stream) {
    (void)in_sizes; (void)n_in; (void)out_size; (void)ws_size;

    const void* eidx_raw = d_in[0];
    const void* x_raw    = d_in[1];
    const void* pos_raw  = d_in[2];
    const void* embW_raw = d_in[3];
    const void* embB_raw = d_in[4];
    const void* eW1_raw  = d_in[5];
    const void* eB1_raw  = d_in[6];
    const void* eW2_raw  = d_in[7];
    const void* eB2_raw  = d_in[8];
    const void* nW1_raw  = d_in[9];
    const void* nB1_raw  = d_in[10];
    const void* nW2_raw  = d_in[11];
    const void* nB2_raw  = d_in[12];
    const void* pW1_raw  = d_in[13];
    const void* pB1_raw  = d_in[14];
    const void* pW2_raw  = d_in[15];
    const void* pB2_raw  = d_in[16];

    float* ws   = (float*)d_ws;
    float* h0   = ws;
    float* h1   = h0 + (size_t)N_NODES * HID;
    float* posf = h1 + (size_t)N_NODES * HID;
    float* agg  = posf + (size_t)N_NODES * 3;
    float* pd   = agg + (size_t)N_NODES * HID;
    float* deg  = pd + (size_t)N_NODES * 3;
    float* fw   = deg + N_NODES;          // fp32 weight region

    float* embW   = fw;                    // 8192
    float* embB   = embW + 8192;           // 128
    float* nW1    = embB + 128;            // 98304
    float* nB1    = nW1 + 3 * 2 * HID * HID;
    float* nW2    = nB1 + 3 * HID;         // 49152
    float* nB2    = nW2 + 3 * HID * HID;
    float* eB1f   = nB2 + 3 * HID;         // 384
    float* eB2f   = eB1f + 3 * HID;
    float* pB1f   = eB2f + 3 * HID;
    float* pB2f   = pB1f + 3 * HID;        // 3 (+1 pad)
    float* pW2f   = pB2f + 4;              // 384
    float* W1r256 = pW2f + 3 * HID;        // 384
    float* fend   = W1r256 + 3 * HID;

    u16* W1t  = (u16*)fend;                // 3*128*256 = 98304 u16
    u16* W2t  = W1t + 3 * 128 * 256;       // 3*128*128 = 49152
    u16* pW1t = W2t + 3 * 128 * 128;       // 49152
    int* src32 = (int*)(pW1t + 3 * 128 * 128);
    int* dst32 = src32 + N_EDGES;
    int* flags = dst32 + N_EDGES;
    // total ws ≈ 68.8 MB (previous round used 69.2 MB successfully)

    detect_kernel<<<1, 256, 0, stream>>>(embW_raw, eidx_raw, flags);
    cvt_idx_kernel<<<(2 * N_EDGES + 255) / 256, 256, 0, stream>>>(eidx_raw, src32, 2 * N_EDGES, flags);

    cvt_f_kernel<<<32, 256, 0, stream>>>(embW_raw, embW, 8192, flags);
    cvt_f_kernel<<<1, 128, 0, stream>>>(embB_raw, embB, 128, flags);
    cvt_f_kernel<<<384, 256, 0, stream>>>(nW1_raw, nW1, 3 * 2 * HID * HID, flags);
    cvt_f_kernel<<<2, 256, 0, stream>>>(nB1_raw, nB1, 3 * HID, flags);
    cvt_f_kernel<<<192, 256, 0, stream>>>(nW2_raw, nW2, 3 * HID * HID, flags);
    cvt_f_kernel<<<2, 256, 0, stream>>>(nB2_raw, nB2, 3 * HID, flags);
    cvt_f_kernel<<<2, 256, 0, stream>>>(eB1_raw, eB1f, 3 * HID, flags);
    cvt_f_kernel<<<2, 256, 0, stream>>>(eB2_raw, eB2f, 3 * HID, flags);
    cvt_f_kernel<<<2, 256, 0, stream>>>(pB1_raw, pB1f, 3 * HID, flags);
    cvt_f_kernel<<<1, 64, 0, stream>>>(pB2_raw, pB2f, 3, flags);
    cvt_f_kernel<<<2, 256, 0, stream>>>(pW2_raw, pW2f, 3 * HID, flags);
    w1row_kernel<<<2, 256, 0, stream>>>(eW1_raw, W1r256, flags);

    // transposed bf16 weights: [l][n][k]
    tcvt_kernel<<<dim3(128, 3), 256, 0, stream>>>(eW1_raw, W1t, 128 * 256, 8, 257 * 128, 128 * 256, flags);
    tcvt_kernel<<<dim3(64, 3), 256, 0, stream>>>(eW2_raw, W2t, 128 * 128, 7, 128 * 128, 128 * 128, flags);
    tcvt_kernel<<<dim3(64, 3), 256, 0, stream>>>(pW1_raw, pW1t, 128 * 128, 7, 128 * 128, 128 * 128, flags);

    hipMemsetAsync(deg, 0, (size_t)N_NODES * sizeof(float), stream);
    deg_kernel<<<(N_EDGES + 255) / 256, 256, 0, stream>>>(dst32, deg);
    posinit_kernel<<<(N_NODES * 3 + 255) / 256, 256, 0, stream>>>(pos_raw, posf, flags);
    embed_kernel<<<N_NODES, 64, 0, stream>>>(x_raw, embW, embB, h0, flags);

    float* hin = h0;
    float* hout = h1;
    for (int l = 0; l < N_LAYERS; ++l) {
        hipMemsetAsync(agg, 0, ((size_t)N_NODES * HID + (size_t)N_NODES * 3) * sizeof(float), stream);
        edge_mfma_kernel<<<N_EDGES / TILE_E, 256, 0, stream>>>(
            src32, dst32, hin, posf,
            W1t + (size_t)l * 128 * 256, W1r256 + l * HID, eB1f + l * HID,
            W2t + (size_t)l * 128 * 128, eB2f + l * HID,
            pW1t + (size_t)l * 128 * 128, pB1f + l * HID,
            pW2f + l * HID, pB2f + l,
            agg, pd);
        node_kernel<<<N_NODES, 64, 0, stream>>>(
            hin, agg,
            nW1 + (size_t)l * 2 * HID * HID, nB1 + l * HID,
            nW2 + (size_t)l * HID * HID,     nB2 + l * HID,
            hout, posf, pd, deg);
        float* tmp = hin; hin = hout; hout = tmp;
    }

    out_kernel<<<(N_NODES * HID + 255) / 256, 256, 0, stream>>>(hin, posf, d_out, flags);
}

// Round 4
// 1593.461 us; speedup vs baseline: 17.7750x; 1.8841x over previous
//
#include <hip/hip_runtime.h>
#include <hip/hip_bf16.h>

#define N_NODES 40000
#define N_EDGES 640000
#define IN_CH 64
#define HID 128
#define N_LAYERS 3

typedef unsigned short u16;
typedef unsigned int u32;

typedef __attribute__((ext_vector_type(8))) __bf16 bf16x8;
typedef __attribute__((ext_vector_type(4))) float float4v;

__device__ __forceinline__ float bf2f(u16 u) {
    union { u32 i; float f; } v; v.i = ((u32)u) << 16; return v.f;
}
__device__ __forceinline__ u16 f2bf(float f) {
    union { float f; u32 i; } v; v.f = f;
    u32 i = v.i;
    u32 r = (i + 0x7fffu + ((i >> 16) & 1u)) >> 16;
    return (u16)r;
}
__device__ __forceinline__ float silu_f(float x) {
    return x / (1.0f + __expf(-x));
}

// ---------------- dtype detection ----------------
__global__ void detect_kernel(const void* __restrict__ w_raw,
                              const void* __restrict__ eidx_raw,
                              int* __restrict__ flags) {
    __shared__ int s_big, s_hi;
    if (threadIdx.x == 0) { s_big = 0; s_hi = 0; }
    __syncthreads();
    const u16* w16 = (const u16*)w_raw;
    for (int i = threadIdx.x; i < 8192; i += blockDim.x) {
        float v = bf2f(w16[i]);
        if (!(fabsf(v) <= 1.0f)) s_big = 1;   // catches NaN too
    }
    const u32* e32 = (const u32*)eidx_raw;
    for (int i = threadIdx.x; i < 256; i += blockDim.x) {
        if (e32[2 * i + 1] != 0u) s_hi = 1;
    }
    __syncthreads();
    if (threadIdx.x == 0) {
        flags[0] = s_big ? 0 : 1;   // 1 => floats are bf16
        flags[1] = s_hi ? 0 : 1;    // 1 => edge_index int64
    }
}

// ---------------- conversions ----------------
__global__ void cvt_f_kernel(const void* __restrict__ in, float* __restrict__ out,
                             int n, const int* __restrict__ flags) {
    int i = blockIdx.x * blockDim.x + threadIdx.x;
    if (i >= n) return;
    out[i] = flags[0] ? bf2f(((const u16*)in)[i]) : ((const float*)in)[i];
}

__global__ void cvt_idx_kernel(const void* __restrict__ in, int* __restrict__ out,
                               int n, const int* __restrict__ flags) {
    int i = blockIdx.x * blockDim.x + threadIdx.x;
    if (i >= n) return;
    out[i] = flags[1] ? (int)(((const long long*)in)[i]) : ((const int*)in)[i];
}

// transpose + cvt to bf16: out[l][n][k] = in[l][k][n]; n in [0,128), k in [0,2^kshift)
__global__ void tcvt_kernel(const void* __restrict__ in, u16* __restrict__ out,
                            int count, int kshift, int inLS, int outLS,
                            const int* __restrict__ flags) {
    int l = blockIdx.y;
    int i = blockIdx.x * blockDim.x + threadIdx.x;
    if (i >= count) return;
    int n = i >> kshift, k = i & ((1 << kshift) - 1);
    int si = inLS * l + k * HID + n;
    float v = flags[0] ? bf2f(((const u16*)in)[si]) : ((const float*)in)[si];
    out[(size_t)outLS * l + i] = f2bf(v);
}

// W1 row 256 (the d2 row), fp32
__global__ void w1row_kernel(const void* __restrict__ in, float* __restrict__ out,
                             const int* __restrict__ flags) {
    int i = blockIdx.x * blockDim.x + threadIdx.x;
    if (i >= 384) return;
    int l = i >> 7, n = i & 127;
    int si = l * (257 * 128) + 256 * 128 + n;
    out[i] = flags[0] ? bf2f(((const u16*)in)[si]) : ((const float*)in)[si];
}

// ---------------- counting sort by dst ----------------
__global__ void cnt_kernel(const int* __restrict__ dst, int* __restrict__ cnt) {
    int e = blockIdx.x * blockDim.x + threadIdx.x;
    if (e < N_EDGES) atomicAdd(&cnt[dst[e]], 1);
}

__global__ __launch_bounds__(1024) void scan_kernel(const int* __restrict__ cnt,
                                                    int* __restrict__ offs) {
    __shared__ int s_part[1024];
    const int t = threadIdx.x;
    const int base = t * 40;
    int sum = 0;
    for (int j = 0; j < 40; ++j) {
        int idx = base + j;
        sum += (idx < N_NODES) ? cnt[idx] : 0;
    }
    s_part[t] = sum;
    __syncthreads();
    for (int d = 1; d < 1024; d <<= 1) {
        int v = (t >= d) ? s_part[t - d] : 0;
        __syncthreads();
        s_part[t] += v;
        __syncthreads();
    }
    int run = (t == 0) ? 0 : s_part[t - 1];
    for (int j = 0; j < 40; ++j) {
        int idx = base + j;
        if (idx < N_NODES) { offs[idx] = run; run += cnt[idx]; }
    }
    if (t == 1023) offs[N_NODES] = run;
}

__global__ void scatter_kernel(const int* __restrict__ src, const int* __restrict__ dst,
                               const int* __restrict__ offs, int* __restrict__ cur,
                               int* __restrict__ ssrc, int* __restrict__ sdst) {
    int e = blockIdx.x * blockDim.x + threadIdx.x;
    if (e >= N_EDGES) return;
    int n = dst[e];
    int p = offs[n] + atomicAdd(&cur[n], 1);
    ssrc[p] = src[e];
    sdst[p] = n;
}

// ---------------- pos init -> f32 ----------------
__global__ void posinit_kernel(const void* __restrict__ pos_raw, float* __restrict__ posf,
                               const int* __restrict__ flags) {
    int i = blockIdx.x * blockDim.x + threadIdx.x;
    if (i < N_NODES * 3)
        posf[i] = flags[0] ? bf2f(((const u16*)pos_raw)[i]) : ((const float*)pos_raw)[i];
}

// ---------------- embedding: h = x @ W + b (output bf16) ----------------
__global__ __launch_bounds__(64) void embed_kernel(
    const void* __restrict__ x_raw, const float* __restrict__ W, const float* __restrict__ b,
    u16* __restrict__ h, const int* __restrict__ flags)
{
    __shared__ float s_x[IN_CH];
    const int n = blockIdx.x;
    const int t = threadIdx.x;
    const int isbf = flags[0];
    s_x[t] = isbf ? bf2f(((const u16*)x_raw)[n * IN_CH + t])
                  : ((const float*)x_raw)[n * IN_CH + t];
    __syncthreads();
    const int o = 2 * t;
    float a0 = b[o], a1 = b[o + 1];
#pragma unroll 8
    for (int i = 0; i < IN_CH; ++i) {
        float xi = s_x[i];
        float2 w = *(const float2*)(W + i * HID + o);
        a0 = fmaf(xi, w.x, a0);
        a1 = fmaf(xi, w.y, a1);
    }
    *(u32*)(h + (size_t)n * HID + o) = (u32)f2bf(a0) | ((u32)f2bf(a1) << 16);
}

// ================= MFMA edge kernel (sorted edges) =================
#define TILE_E 64
#define EIN_STRIDE 280   // u16: 256 data + 24 pad; 560B row (16B aligned, 2-way banks)
#define ACT_STRIDE 136   // u16: 128 data + 8 pad; 272B row
#define W_STRIDE 72      // u16: 64 k + 8 pad; 144B row

__global__ __launch_bounds__(256, 2) void edge_mfma_kernel(
    const int* __restrict__ ssrc, const int* __restrict__ sdst,
    const u16* __restrict__ h, const float* __restrict__ posf,
    const u16* __restrict__ W1t, const float* __restrict__ W1r256, const float* __restrict__ b1,
    const u16* __restrict__ W2t, const float* __restrict__ b2,
    const u16* __restrict__ pW1t, const float* __restrict__ pb1,
    const float* __restrict__ pW2, const float* __restrict__ pb2,
    float* __restrict__ agg, float* __restrict__ pd)
{
    __shared__ u16 s_big[TILE_E * EIN_STRIDE];   // e_in; later t1 [0,8704) + m [8704,17408)
    __shared__ u16 s_w[128 * W_STRIDE];
    __shared__ float s_d2[TILE_E];               // d2; later per-row w
    __shared__ float s_rel[TILE_E * 3];
    __shared__ int s_dstn[TILE_E];

    const int t = threadIdx.x;
    const int e0 = blockIdx.x * TILE_E;
    const int wv = t >> 6, lane = t & 63, quad = lane >> 4, li = lane & 15;
    const int rowA = wv * 16 + li;
    const int rowC = wv * 16 + quad * 4;

    // ---- gather ----
    if (t < TILE_E) {
        int e = e0 + t;
        int sN = ssrc[e], dN = sdst[e];
        s_dstn[t] = dN;
        float r0 = posf[dN * 3 + 0] - posf[sN * 3 + 0];
        float r1 = posf[dN * 3 + 1] - posf[sN * 3 + 1];
        float r2 = posf[dN * 3 + 2] - posf[sN * 3 + 2];
        s_rel[t * 3 + 0] = r0; s_rel[t * 3 + 1] = r1; s_rel[t * 3 + 2] = r2;
        s_d2[t] = r0 * r0 + r1 * r1 + r2 * r2;
    }
    {   // h rows (bf16): 4 threads/edge, 64 B each from h[dst] and h[src]
        int el = t >> 2, part = t & 3;
        int e = e0 + el;
        int dN = sdst[e], sN = ssrc[e];
        const u32* hd = (const u32*)(h + (size_t)dN * HID) + part * 16;
        const u32* hs = (const u32*)(h + (size_t)sN * HID) + part * 16;
        u32* rowp = (u32*)s_big + el * (EIN_STRIDE / 2) + part * 16;
#pragma unroll
        for (int j = 0; j < 4; ++j) *(uint4*)(rowp + j * 4) = *(const uint4*)(hd + j * 4);
        rowp += 64;  // +128 u16 = h_j half
#pragma unroll
        for (int j = 0; j < 4; ++j) *(uint4*)(rowp + j * 4) = *(const uint4*)(hs + j * 4);
    }
    // stage W1 chunk 0
    {
        const u32* g = (const u32*)W1t;  // row: 128 u32
        u32* sw = (u32*)s_w;
        for (int i = t; i < 4096; i += 256) {
            int n = i >> 5, kk = i & 31;
            sw[n * 36 + kk] = g[n * 128 + kk];
        }
    }
    __syncthreads();

    // ---- layer 1: [257] -> [128] ----
    float4v acc[8];
#pragma unroll
    for (int c = 0; c < 8; ++c) {
        int col = c * 16 + li;
        float bias = b1[col];
        float w2 = W1r256[col];
#pragma unroll
        for (int r = 0; r < 4; ++r) acc[c][r] = bias + s_d2[rowC + r] * w2;
    }
#pragma unroll
    for (int p = 0; p < 4; ++p) {
        if (p) {
            __syncthreads();
            const u32* g = (const u32*)W1t;
            u32* sw = (u32*)s_w;
            for (int i = t; i < 4096; i += 256) {
                int n = i >> 5, kk = i & 31;
                sw[n * 36 + kk] = g[n * 128 + p * 32 + kk];
            }
            __syncthreads();
        }
#pragma unroll
        for (int kk2 = 0; kk2 < 2; ++kk2) {
            const bf16x8 av = *(const bf16x8*)(s_big + rowA * EIN_STRIDE + p * 64 + kk2 * 32 + quad * 8);
#pragma unroll
            for (int c = 0; c < 8; ++c) {
                const bf16x8 bv = *(const bf16x8*)(s_w + (c * 16 + li) * W_STRIDE + kk2 * 32 + quad * 8);
                acc[c] = __builtin_amdgcn_mfma_f32_16x16x32_bf16(av, bv, acc[c], 0, 0, 0);
            }
        }
    }

    // ---- t1 = silu(acc) -> LDS; stage W2 chunk 0 ----
    __syncthreads();
    u16* s_t1 = s_big;
    u16* s_m  = s_big + TILE_E * ACT_STRIDE;
#pragma unroll
    for (int c = 0; c < 8; ++c) {
        int col = c * 16 + li;
#pragma unroll
        for (int r = 0; r < 4; ++r)
            s_t1[(rowC + r) * ACT_STRIDE + col] = f2bf(silu_f(acc[c][r]));
    }
    {
        const u32* g = (const u32*)W2t;  // row: 64 u32
        u32* sw = (u32*)s_w;
        for (int i = t; i < 4096; i += 256) {
            int n = i >> 5, kk = i & 31;
            sw[n * 36 + kk] = g[n * 64 + kk];
        }
    }
    __syncthreads();

    // ---- layer 2: [128] -> [128] -> m ----
#pragma unroll
    for (int c = 0; c < 8; ++c) {
        float bias = b2[c * 16 + li];
#pragma unroll
        for (int r = 0; r < 4; ++r) acc[c][r] = bias;
    }
#pragma unroll
    for (int p = 0; p < 2; ++p) {
        if (p) {
            __syncthreads();
            const u32* g = (const u32*)W2t;
            u32* sw = (u32*)s_w;
            for (int i = t; i < 4096; i += 256) {
                int n = i >> 5, kk = i & 31;
                sw[n * 36 + kk] = g[n * 64 + 32 + kk];
            }
            __syncthreads();
        }
#pragma unroll
        for (int kk2 = 0; kk2 < 2; ++kk2) {
            const bf16x8 av = *(const bf16x8*)(s_t1 + rowA * ACT_STRIDE + p * 64 + kk2 * 32 + quad * 8);
#pragma unroll
            for (int c = 0; c < 8; ++c) {
                const bf16x8 bv = *(const bf16x8*)(s_w + (c * 16 + li) * W_STRIDE + kk2 * 32 + quad * 8);
                acc[c] = __builtin_amdgcn_mfma_f32_16x16x32_bf16(av, bv, acc[c], 0, 0, 0);
            }
        }
    }

    // ---- m -> LDS (bf16) ----
#pragma unroll
    for (int c = 0; c < 8; ++c) {
        int col = c * 16 + li;
#pragma unroll
        for (int r = 0; r < 4; ++r)
            s_m[(rowC + r) * ACT_STRIDE + col] = f2bf(silu_f(acc[c][r]));
    }
    __syncthreads();

    // ---- stage pW1 chunk 0 + segmented agg reduction (sorted dst runs) ----
    {
        const u32* g = (const u32*)pW1t;
        u32* sw = (u32*)s_w;
        for (int i = t; i < 4096; i += 256) {
            int n = i >> 5, kk = i & 31;
            sw[n * 36 + kk] = g[n * 64 + kk];
        }
    }
    {
        int col = t & 127, r0 = (t >> 7) * 32;
        float run = 0.f;
        int cur = s_dstn[r0];
        for (int r = r0; r < r0 + 32; ++r) {
            int dn = s_dstn[r];
            if (dn != cur) {
                atomicAdd(&agg[(size_t)cur * HID + col], run);
                run = 0.f; cur = dn;
            }
            run += bf2f(s_m[r * ACT_STRIDE + col]);
        }
        atomicAdd(&agg[(size_t)cur * HID + col], run);
    }
    __syncthreads();

    // ---- pos MLP ----
#pragma unroll
    for (int c = 0; c < 8; ++c) {
        float bias = pb1[c * 16 + li];
#pragma unroll
        for (int r = 0; r < 4; ++r) acc[c][r] = bias;
    }
#pragma unroll
    for (int p = 0; p < 2; ++p) {
        if (p) {
            __syncthreads();
            const u32* g = (const u32*)pW1t;
            u32* sw = (u32*)s_w;
            for (int i = t; i < 4096; i += 256) {
                int n = i >> 5, kk = i & 31;
                sw[n * 36 + kk] = g[n * 64 + 32 + kk];
            }
            __syncthreads();
        }
#pragma unroll
        for (int kk2 = 0; kk2 < 2; ++kk2) {
            const bf16x8 av = *(const bf16x8*)(s_m + rowA * ACT_STRIDE + p * 64 + kk2 * 32 + quad * 8);
#pragma unroll
            for (int c = 0; c < 8; ++c) {
                const bf16x8 bv = *(const bf16x8*)(s_w + (c * 16 + li) * W_STRIDE + kk2 * 32 + quad * 8);
                acc[c] = __builtin_amdgcn_mfma_f32_16x16x32_bf16(av, bv, acc[c], 0, 0, 0);
            }
        }
    }
    float part[4] = {0.f, 0.f, 0.f, 0.f};
#pragma unroll
    for (int c = 0; c < 8; ++c) {
        float pw = pW2[c * 16 + li];
#pragma unroll
        for (int r = 0; r < 4; ++r) part[r] += silu_f(acc[c][r]) * pw;
    }
#pragma unroll
    for (int r = 0; r < 4; ++r) {
        part[r] += __shfl_xor(part[r], 1, 64);
        part[r] += __shfl_xor(part[r], 2, 64);
        part[r] += __shfl_xor(part[r], 4, 64);
        part[r] += __shfl_xor(part[r], 8, 64);
    }
    __syncthreads();   // s_d2 reuse as w storage
    if (li == 0) {
        float pb2v = pb2[0];
#pragma unroll
        for (int r = 0; r < 4; ++r) s_d2[rowC + r] = part[r] + pb2v;
    }
    __syncthreads();
    // segmented pd reduction: 6 threads (3 axes x 2 halves)
    if (t < 6) {
        int a = t % 3, r0 = (t / 3) * 32;
        float run = 0.f;
        int cur = s_dstn[r0];
        for (int r = r0; r < r0 + 32; ++r) {
            int dn = s_dstn[r];
            if (dn != cur) {
                atomicAdd(&pd[(size_t)cur * 3 + a], run);
                run = 0.f; cur = dn;
            }
            run += s_rel[r * 3 + a] * s_d2[r];
        }
        atomicAdd(&pd[(size_t)cur * 3 + a], run);
    }
}

// ================= MFMA node kernel =================
#define A_STRIDE 264   // u16: 256 + 8 pad; 528B row

__global__ __launch_bounds__(256, 2) void node_mfma_kernel(
    const u16* __restrict__ h_in, const float* __restrict__ agg,
    const u16* __restrict__ W1t, const float* __restrict__ b1,
    const u16* __restrict__ W2t, const float* __restrict__ b2,
    u16* __restrict__ h_out,
    float* __restrict__ posf, const float* __restrict__ pd, const int* __restrict__ cnt)
{
    __shared__ u16 s_a[64 * A_STRIDE];   // A rows; later t1 in [0, 64*ACT_STRIDE)
    __shared__ u16 s_w[128 * W_STRIDE];

    const int t = threadIdx.x;
    const int n0 = blockIdx.x * 64;
    const int wv = t >> 6, lane = t & 63, quad = lane >> 4, li = lane & 15;
    const int rowA = wv * 16 + li;
    const int rowC = wv * 16 + quad * 4;

    // ---- load A: [h bf16 | f2bf(agg)] ----
    {
        int nl = t >> 2, part = t & 3;
        const u32* hp = (const u32*)(h_in + (size_t)(n0 + nl) * HID) + part * 16;
        u32* rowp = (u32*)s_a + nl * (A_STRIDE / 2) + part * 16;
#pragma unroll
        for (int j = 0; j < 4; ++j) *(uint4*)(rowp + j * 4) = *(const uint4*)(hp + j * 4);
        const float* ap = agg + (size_t)(n0 + nl) * HID + part * 32;
        rowp += 64;
#pragma unroll
        for (int j = 0; j < 16; ++j) {
            float2 v = *(const float2*)(ap + j * 2);
            rowp[j] = (u32)f2bf(v.x) | ((u32)f2bf(v.y) << 16);
        }
    }
    {
        const u32* g = (const u32*)W1t;  // row: 128 u32 (256 bf16)
        u32* sw = (u32*)s_w;
        for (int i = t; i < 4096; i += 256) {
            int n = i >> 5, kk = i & 31;
            sw[n * 36 + kk] = g[n * 128 + kk];
        }
    }
    __syncthreads();

    // ---- layer 1: [256] -> [128], silu ----
    float4v acc[8];
#pragma unroll
    for (int c = 0; c < 8; ++c) {
        float bias = b1[c * 16 + li];
#pragma unroll
        for (int r = 0; r < 4; ++r) acc[c][r] = bias;
    }
#pragma unroll
    for (int p = 0; p < 4; ++p) {
        if (p) {
            __syncthreads();
            const u32* g = (const u32*)W1t;
            u32* sw = (u32*)s_w;
            for (int i = t; i < 4096; i += 256) {
                int n = i >> 5, kk = i & 31;
                sw[n * 36 + kk] = g[n * 128 + p * 32 + kk];
            }
            __syncthreads();
        }
#pragma unroll
        for (int kk2 = 0; kk2 < 2; ++kk2) {
            const bf16x8 av = *(const bf16x8*)(s_a + rowA * A_STRIDE + p * 64 + kk2 * 32 + quad * 8);
#pragma unroll
            for (int c = 0; c < 8; ++c) {
                const bf16x8 bv = *(const bf16x8*)(s_w + (c * 16 + li) * W_STRIDE + kk2 * 32 + quad * 8);
                acc[c] = __builtin_amdgcn_mfma_f32_16x16x32_bf16(av, bv, acc[c], 0, 0, 0);
            }
        }
    }

    __syncthreads();
    u16* s_t1 = s_a;
#pragma unroll
    for (int c = 0; c < 8; ++c) {
        int col = c * 16 + li;
#pragma unroll
        for (int r = 0; r < 4; ++r)
            s_t1[(rowC + r) * ACT_STRIDE + col] = f2bf(silu_f(acc[c][r]));
    }
    {
        const u32* g = (const u32*)W2t;
        u32* sw = (u32*)s_w;
        for (int i = t; i < 4096; i += 256) {
            int n = i >> 5, kk = i & 31;
            sw[n * 36 + kk] = g[n * 64 + kk];
        }
    }
    __syncthreads();

    // ---- layer 2: [128] -> [128] ----
#pragma unroll
    for (int c = 0; c < 8; ++c) {
        float bias = b2[c * 16 + li];
#pragma unroll
        for (int r = 0; r < 4; ++r) acc[c][r] = bias;
    }
#pragma unroll
    for (int p = 0; p < 2; ++p) {
        if (p) {
            __syncthreads();
            const u32* g = (const u32*)W2t;
            u32* sw = (u32*)s_w;
            for (int i = t; i < 4096; i += 256) {
                int n = i >> 5, kk = i & 31;
                sw[n * 36 + kk] = g[n * 64 + 32 + kk];
            }
            __syncthreads();
        }
#pragma unroll
        for (int kk2 = 0; kk2 < 2; ++kk2) {
            const bf16x8 av = *(const bf16x8*)(s_t1 + rowA * ACT_STRIDE + p * 64 + kk2 * 32 + quad * 8);
#pragma unroll
            for (int c = 0; c < 8; ++c) {
                const bf16x8 bv = *(const bf16x8*)(s_w + (c * 16 + li) * W_STRIDE + kk2 * 32 + quad * 8);
                acc[c] = __builtin_amdgcn_mfma_f32_16x16x32_bf16(av, bv, acc[c], 0, 0, 0);
            }
        }
    }

    // ---- epilogue: h_out bf16 + pos update ----
#pragma unroll
    for (int c = 0; c < 8; ++c) {
        int col = c * 16 + li;
#pragma unroll
        for (int r = 0; r < 4; ++r)
            h_out[(size_t)(n0 + rowC + r) * HID + col] = f2bf(acc[c][r]);
    }
    if (t < 192) {
        int nl = t / 3, a = t % 3;
        int n = n0 + nl;
        float dg = (float)cnt[n];
        dg = dg < 1.0f ? 1.0f : dg;
        posf[n * 3 + a] += pd[n * 3 + a] / dg;
    }
}

// ---------------- output ----------------
__global__ void out_kernel(const u16* __restrict__ h, const float* __restrict__ posf,
                           void* __restrict__ out, const int* __restrict__ flags)
{
    int i = blockIdx.x * blockDim.x + threadIdx.x;
    const int isbf = flags[0];
    if (i < N_NODES * HID) {
        if (isbf) ((u16*)out)[i] = h[i];
        else      ((float*)out)[i] = bf2f(h[i]);
    }
    if (i < N_NODES * 3) {
        if (isbf) ((u16*)out)[N_NODES * HID + i] = f2bf(posf[i]);
        else      ((float*)out)[N_NODES * HID + i] = posf[i];
    }
}

extern "C" void kernel_launch(void* const* d_in, const int* in_sizes, int n_in,
                              void* d_out, int out_size, void* d_ws, size_t ws_size,
                              hipStream_t stream) {
    (void)in_sizes; (void)n_in; (void)out_size; (void)ws_size;

    const void* eidx_raw = d_in[0];
    const void* x_raw    = d_in[1];
    const void* pos_raw  = d_in[2];
    const void* embW_raw = d_in[3];
    const void* embB_raw = d_in[4];
    const void* eW1_raw  = d_in[5];
    const void* eB1_raw  = d_in[6];
    const void* eW2_raw  = d_in[7];
    const void* eB2_raw  = d_in[8];
    const void* nW1_raw  = d_in[9];
    const void* nB1_raw  = d_in[10];
    const void* nW2_raw  = d_in[11];
    const void* nB2_raw  = d_in[12];
    const void* pW1_raw  = d_in[13];
    const void* pB1_raw  = d_in[14];
    const void* pW2_raw  = d_in[15];
    const void* pB2_raw  = d_in[16];

    float* ws   = (float*)d_ws;
    float* posf = ws;                           //   120,000
    float* agg  = posf + (size_t)N_NODES * 3;   // 5,120,000
    float* pd   = agg + (size_t)N_NODES * HID;  //   120,000 (contiguous w/ agg)
    float* fw   = pd + (size_t)N_NODES * 3;

    float* embW   = fw;                     // 8192
    float* embB   = embW + 8192;            // 128
    float* eB1f   = embB + 128;             // 384
    float* eB2f   = eB1f + 3 * HID;
    float* pB1f   = eB2f + 3 * HID;
    float* pB2f   = pB1f + 3 * HID;         // 3 (+1 pad)
    float* pW2f   = pB2f + 4;               // 384
    float* W1r256 = pW2f + 3 * HID;         // 384
    float* nB1f   = W1r256 + 3 * HID;       // 384
    float* nB2f   = nB1f + 3 * HID;         // 384
    float* fend   = nB2f + 3 * HID;

    u16* W1t  = (u16*)fend;                 // 3*128*256
    u16* W2t  = W1t + 3 * 128 * 256;        // 3*128*128
    u16* pW1t = W2t + 3 * 128 * 128;
    u16* nW1t = pW1t + 3 * 128 * 128;       // 3*128*256
    u16* nW2t = nW1t + 3 * 128 * 256;       // 3*128*128
    u16* h0   = nW2t + 3 * 128 * 128;       // N*128 bf16
    u16* h1   = h0 + (size_t)N_NODES * HID;
    int* src32 = (int*)(h1 + (size_t)N_NODES * HID);
    int* dst32 = src32 + N_EDGES;
    int* ssrc  = dst32 + N_EDGES;
    int* sdst  = ssrc + N_EDGES;
    int* cnt   = sdst + N_EDGES;            // 40000
    int* cur   = cnt + N_NODES;             // 40000 (contiguous w/ cnt for memset)
    int* offs  = cur + N_NODES;             // 40001
    int* flags = offs + N_NODES + 4;
    // total ws ≈ 56 MB

    detect_kernel<<<1, 256, 0, stream>>>(embW_raw, eidx_raw, flags);
    cvt_idx_kernel<<<(2 * N_EDGES + 255) / 256, 256, 0, stream>>>(eidx_raw, src32, 2 * N_EDGES, flags);

    cvt_f_kernel<<<32, 256, 0, stream>>>(embW_raw, embW, 8192, flags);
    cvt_f_kernel<<<1, 128, 0, stream>>>(embB_raw, embB, 128, flags);
    cvt_f_kernel<<<2, 256, 0, stream>>>(eB1_raw, eB1f, 3 * HID, flags);
    cvt_f_kernel<<<2, 256, 0, stream>>>(eB2_raw, eB2f, 3 * HID, flags);
    cvt_f_kernel<<<2, 256, 0, stream>>>(pB1_raw, pB1f, 3 * HID, flags);
    cvt_f_kernel<<<1, 64, 0, stream>>>(pB2_raw, pB2f, 3, flags);
    cvt_f_kernel<<<2, 256, 0, stream>>>(pW2_raw, pW2f, 3 * HID, flags);
    cvt_f_kernel<<<2, 256, 0, stream>>>(nB1_raw, nB1f, 3 * HID, flags);
    cvt_f_kernel<<<2, 256, 0, stream>>>(nB2_raw, nB2f, 3 * HID, flags);
    w1row_kernel<<<2, 256, 0, stream>>>(eW1_raw, W1r256, flags);

    tcvt_kernel<<<dim3(128, 3), 256, 0, stream>>>(eW1_raw, W1t, 128 * 256, 8, 257 * 128, 128 * 256, flags);
    tcvt_kernel<<<dim3(64, 3), 256, 0, stream>>>(eW2_raw, W2t, 128 * 128, 7, 128 * 128, 128 * 128, flags);
    tcvt_kernel<<<dim3(64, 3), 256, 0, stream>>>(pW1_raw, pW1t, 128 * 128, 7, 128 * 128, 128 * 128, flags);
    tcvt_kernel<<<dim3(128, 3), 256, 0, stream>>>(nW1_raw, nW1t, 128 * 256, 8, 2 * HID * HID, 128 * 256, flags);
    tcvt_kernel<<<dim3(64, 3), 256, 0, stream>>>(nW2_raw, nW2t, 128 * 128, 7, 128 * 128, 128 * 128, flags);

    // counting sort by dst
    hipMemsetAsync(cnt, 0, 2 * (size_t)N_NODES * sizeof(int), stream);  // cnt + cur
    cnt_kernel<<<(N_EDGES + 255) / 256, 256, 0, stream>>>(dst32, cnt);
    scan_kernel<<<1, 1024, 0, stream>>>(cnt, offs);
    scatter_kernel<<<(N_EDGES + 255) / 256, 256, 0, stream>>>(src32, dst32, offs, cur, ssrc, sdst);

    posinit_kernel<<<(N_NODES * 3 + 255) / 256, 256, 0, stream>>>(pos_raw, posf, flags);
    embed_kernel<<<N_NODES, 64, 0, stream>>>(x_raw, embW, embB, h0, flags);

    u16* hin = h0;
    u16* hout = h1;
    for (int l = 0; l < N_LAYERS; ++l) {
        hipMemsetAsync(agg, 0, ((size_t)N_NODES * HID + (size_t)N_NODES * 3) * sizeof(float), stream);
        edge_mfma_kernel<<<N_EDGES / TILE_E, 256, 0, stream>>>(
            ssrc, sdst, hin, posf,
            W1t + (size_t)l * 128 * 256, W1r256 + l * HID, eB1f + l * HID,
            W2t + (size_t)l * 128 * 128, eB2f + l * HID,
            pW1t + (size_t)l * 128 * 128, pB1f + l * HID,
            pW2f + l * HID, pB2f + l,
            agg, pd);
        node_mfma_kernel<<<N_NODES / 64, 256, 0, stream>>>(
            hin, agg,
            nW1t + (size_t)l * 128 * 256, nB1f + l * HID,
            nW2t + (size_t)l * 128 * 128, nB2f + l * HID,
            hout, posf, pd, cnt);
        u16* tmp = hin; hin = hout; hout = tmp;
    }

    out_kernel<<<(N_NODES * HID + 255) / 256, 256, 0, stream>>>(hin, posf, d_out, flags);
}

// Round 5
// 887.306 us; speedup vs baseline: 31.9210x; 1.7958x over previous
//
#include <hip/hip_runtime.h>
#include <hip/hip_bf16.h>

#define N_NODES 40000
#define N_EDGES 640000
#define IN_CH 64
#define HID 128
#define N_LAYERS 3

typedef unsigned short u16;
typedef unsigned int u32;

typedef __attribute__((ext_vector_type(8))) __bf16 bf16x8;
typedef __attribute__((ext_vector_type(4))) float float4v;

__device__ __forceinline__ float bf2f(u16 u) {
    union { u32 i; float f; } v; v.i = ((u32)u) << 16; return v.f;
}
__device__ __forceinline__ float bflo(u32 p) {   // low bf16 of packed pair
    union { u32 i; float f; } v; v.i = p << 16; return v.f;
}
__device__ __forceinline__ float bfhi(u32 p) {   // high bf16 of packed pair
    union { u32 i; float f; } v; v.i = p & 0xffff0000u; return v.f;
}
__device__ __forceinline__ u16 f2bf(float f) {
    union { float f; u32 i; } v; v.f = f;
    u32 i = v.i;
    u32 r = (i + 0x7fffu + ((i >> 16) & 1u)) >> 16;
    return (u16)r;
}
__device__ __forceinline__ float silu_f(float x) {
    float d = 1.0f + __expf(-x);
#if __has_builtin(__builtin_amdgcn_rcpf)
    return x * __builtin_amdgcn_rcpf(d);
#else
    return __fdividef(x, d);
#endif
}

// ---- wide LDS weight staging: 128 rows x 64-k chunk, W_STRIDE=72 u16 ----
#define W_STRIDE 72
__device__ __forceinline__ void stage_w64(const u16* __restrict__ g, u16* s, int t,
                                          int chunk, int rowstride_u32) {
    const u32* gp = (const u32*)g;
    u32* sp = (u32*)s;
#pragma unroll
    for (int it = 0; it < 4; ++it) {
        int i4 = t + it * 256;
        int n = i4 >> 3, j = i4 & 7;
        *(uint4*)(sp + n * 36 + j * 4) = *(const uint4*)(gp + n * rowstride_u32 + chunk * 32 + j * 4);
    }
}
// ---- 256 rows x 32-k chunk, stride 40 u16 (uv weights) ----
__device__ __forceinline__ void stage_w32_256(const u16* __restrict__ g, u16* s, int t, int chunk) {
    const u32* gp = (const u32*)g;
    u32* sp = (u32*)s;
#pragma unroll
    for (int it = 0; it < 4; ++it) {
        int i4 = t + it * 256;
        int o = i4 >> 2, j = i4 & 3;
        *(uint4*)(sp + o * 20 + j * 4) = *(const uint4*)(gp + o * 64 + chunk * 16 + j * 4);
    }
}

// ---------------- dtype detection ----------------
__global__ void detect_kernel(const void* __restrict__ w_raw,
                              const void* __restrict__ eidx_raw,
                              int* __restrict__ flags) {
    __shared__ int s_big, s_hi;
    if (threadIdx.x == 0) { s_big = 0; s_hi = 0; }
    __syncthreads();
    const u16* w16 = (const u16*)w_raw;
    for (int i = threadIdx.x; i < 8192; i += blockDim.x) {
        float v = bf2f(w16[i]);
        if (!(fabsf(v) <= 1.0f)) s_big = 1;
    }
    const u32* e32 = (const u32*)eidx_raw;
    for (int i = threadIdx.x; i < 256; i += blockDim.x) {
        if (e32[2 * i + 1] != 0u) s_hi = 1;
    }
    __syncthreads();
    if (threadIdx.x == 0) {
        flags[0] = s_big ? 0 : 1;   // 1 => floats are bf16
        flags[1] = s_hi ? 0 : 1;    // 1 => edge_index int64
    }
}

// ---------------- conversions ----------------
__global__ void cvt_f_kernel(const void* __restrict__ in, float* __restrict__ out,
                             int n, const int* __restrict__ flags) {
    int i = blockIdx.x * blockDim.x + threadIdx.x;
    if (i >= n) return;
    out[i] = flags[0] ? bf2f(((const u16*)in)[i]) : ((const float*)in)[i];
}

__global__ void cvt_idx_kernel(const void* __restrict__ in, int* __restrict__ out,
                               int n, const int* __restrict__ flags) {
    int i = blockIdx.x * blockDim.x + threadIdx.x;
    if (i >= n) return;
    out[i] = flags[1] ? (int)(((const long long*)in)[i]) : ((const int*)in)[i];
}

// transpose + cvt to bf16: out[l][n][k] = in[l][k][n]
__global__ void tcvt_kernel(const void* __restrict__ in, u16* __restrict__ out,
                            int count, int kshift, int inLS, int outLS,
                            const int* __restrict__ flags) {
    int l = blockIdx.y;
    int i = blockIdx.x * blockDim.x + threadIdx.x;
    if (i >= count) return;
    int n = i >> kshift, k = i & ((1 << kshift) - 1);
    int si = inLS * l + k * HID + n;
    float v = flags[0] ? bf2f(((const u16*)in)[si]) : ((const float*)in)[si];
    out[(size_t)outLS * l + i] = f2bf(v);
}

// W1ab^T: out[l][o][k], o<128: W1[k][o] (h_i part); o>=128: W1[128+k][o-128] (h_j part)
__global__ void w1ab_kernel(const void* __restrict__ in, u16* __restrict__ out,
                            const int* __restrict__ flags) {
    int l = blockIdx.y;
    int i = blockIdx.x * blockDim.x + threadIdx.x;   // < 32768
    int o = i >> 7, k = i & 127;
    int si = l * (257 * 128) + ((o < 128) ? (k * 128 + o) : ((128 + k) * 128 + (o - 128)));
    float v = flags[0] ? bf2f(((const u16*)in)[si]) : ((const float*)in)[si];
    out[(size_t)l * 32768 + i] = f2bf(v);
}

// W1 row 256 (d2 row), fp32
__global__ void w1row_kernel(const void* __restrict__ in, float* __restrict__ out,
                             const int* __restrict__ flags) {
    int i = blockIdx.x * blockDim.x + threadIdx.x;
    if (i >= 384) return;
    int l = i >> 7, n = i & 127;
    int si = l * (257 * 128) + 256 * 128 + n;
    out[i] = flags[0] ? bf2f(((const u16*)in)[si]) : ((const float*)in)[si];
}

// ---------------- counting sort by dst ----------------
__global__ void cnt_kernel(const int* __restrict__ dst, int* __restrict__ cnt) {
    int e = blockIdx.x * blockDim.x + threadIdx.x;
    if (e < N_EDGES) atomicAdd(&cnt[dst[e]], 1);
}

__global__ __launch_bounds__(1024) void scan_kernel(const int* __restrict__ cnt,
                                                    int* __restrict__ offs) {
    __shared__ int s_part[1024];
    const int t = threadIdx.x;
    const int base = t * 40;
    int sum = 0;
    for (int j = 0; j < 40; ++j) {
        int idx = base + j;
        sum += (idx < N_NODES) ? cnt[idx] : 0;
    }
    s_part[t] = sum;
    __syncthreads();
    for (int d = 1; d < 1024; d <<= 1) {
        int v = (t >= d) ? s_part[t - d] : 0;
        __syncthreads();
        s_part[t] += v;
        __syncthreads();
    }
    int run = (t == 0) ? 0 : s_part[t - 1];
    for (int j = 0; j < 40; ++j) {
        int idx = base + j;
        if (idx < N_NODES) { offs[idx] = run; run += cnt[idx]; }
    }
    if (t == 1023) offs[N_NODES] = run;
}

__global__ void scatter_kernel(const int* __restrict__ src, const int* __restrict__ dst,
                               const int* __restrict__ offs, int* __restrict__ cur,
                               int* __restrict__ ssrc, int* __restrict__ sdst) {
    int e = blockIdx.x * blockDim.x + threadIdx.x;
    if (e >= N_EDGES) return;
    int n = dst[e];
    int p = offs[n] + atomicAdd(&cur[n], 1);
    ssrc[p] = src[e];
    sdst[p] = n;
}

// ---------------- pos init -> f32 ----------------
__global__ void posinit_kernel(const void* __restrict__ pos_raw, float* __restrict__ posf,
                               const int* __restrict__ flags) {
    int i = blockIdx.x * blockDim.x + threadIdx.x;
    if (i < N_NODES * 3)
        posf[i] = flags[0] ? bf2f(((const u16*)pos_raw)[i]) : ((const float*)pos_raw)[i];
}

// ---------------- embedding: h = x @ W + b (output bf16) ----------------
__global__ __launch_bounds__(64) void embed_kernel(
    const void* __restrict__ x_raw, const float* __restrict__ W, const float* __restrict__ b,
    u16* __restrict__ h, const int* __restrict__ flags)
{
    __shared__ float s_x[IN_CH];
    const int n = blockIdx.x;
    const int t = threadIdx.x;
    const int isbf = flags[0];
    s_x[t] = isbf ? bf2f(((const u16*)x_raw)[n * IN_CH + t])
                  : ((const float*)x_raw)[n * IN_CH + t];
    __syncthreads();
    const int o = 2 * t;
    float a0 = b[o], a1 = b[o + 1];
#pragma unroll 8
    for (int i = 0; i < IN_CH; ++i) {
        float xi = s_x[i];
        float2 w = *(const float2*)(W + i * HID + o);
        a0 = fmaf(xi, w.x, a0);
        a1 = fmaf(xi, w.y, a1);
    }
    *(u32*)(h + (size_t)n * HID + o) = (u32)f2bf(a0) | ((u32)f2bf(a1) << 16);
}

#define ACT_STRIDE 136   // u16: 128 + 8 pad

// ================= uv GEMM: uv[n] = [ h@W1a + b1 | h@W1b ]  =================
__global__ __launch_bounds__(256, 4) void uv_kernel(
    const u16* __restrict__ h, const u16* __restrict__ W1abt, const float* __restrict__ b1,
    u16* __restrict__ uv)
{
    __shared__ __align__(16) u16 s_a[64 * ACT_STRIDE];
    __shared__ __align__(16) u16 s_w[256 * 40];

    const int t = threadIdx.x;
    const int n0 = blockIdx.x * 64;
    const int wv = t >> 6, lane = t & 63, quad = lane >> 4, li = lane & 15;
    const int rowA = wv * 16 + li;
    const int rowC = wv * 16 + quad * 4;

    {   // A = h rows (bf16)
        int nl = t >> 2, part = t & 3;
        const uint4* hp = (const uint4*)((const u32*)h + (size_t)(n0 + nl) * 64 + part * 16);
        uint4* ap = (uint4*)((u32*)s_a + nl * (ACT_STRIDE / 2) + part * 16);
#pragma unroll
        for (int j = 0; j < 4; ++j) ap[j] = hp[j];
    }

    float4v acc[16];
#pragma unroll
    for (int ct = 0; ct < 16; ++ct) {
        float bias = (ct < 8) ? b1[ct * 16 + li] : 0.0f;
#pragma unroll
        for (int r = 0; r < 4; ++r) acc[ct][r] = bias;
    }

#pragma unroll
    for (int c = 0; c < 4; ++c) {    // k chunks of 32
        if (c) __syncthreads();
        stage_w32_256(W1abt, s_w, t, c);
        __syncthreads();
        const bf16x8 av = *(const bf16x8*)(s_a + rowA * ACT_STRIDE + c * 32 + quad * 8);
#pragma unroll
        for (int ct = 0; ct < 16; ++ct) {
            const bf16x8 bv = *(const bf16x8*)(s_w + (ct * 16 + li) * 40 + quad * 8);
            acc[ct] = __builtin_amdgcn_mfma_f32_16x16x32_bf16(av, bv, acc[ct], 0, 0, 0);
        }
    }

#pragma unroll
    for (int ct = 0; ct < 16; ++ct) {
        int col = ct * 16 + li;
#pragma unroll
        for (int r = 0; r < 4; ++r)
            uv[(size_t)(n0 + rowC + r) * 256 + col] = f2bf(acc[ct][r]);
    }
}

// ================= edge kernel v2 (no L1 matmul) =================
#define TILE_E 64

__global__ __launch_bounds__(256, 4) void edge_mfma_kernel(
    const int* __restrict__ ssrc, const int* __restrict__ sdst,
    const u16* __restrict__ uv, const float* __restrict__ posf,
    const float* __restrict__ w1c_g,
    const u16* __restrict__ W2t, const float* __restrict__ b2,
    const u16* __restrict__ pW1t, const float* __restrict__ pb1,
    const float* __restrict__ pW2, const float* __restrict__ pb2,
    float* __restrict__ agg, float* __restrict__ pd)
{
    __shared__ __align__(16) u16 s_act[TILE_E * ACT_STRIDE];   // t1, then m
    __shared__ __align__(16) u16 s_w[128 * W_STRIDE];
    __shared__ float s_w1c[128];
    __shared__ float s_d2[TILE_E];     // d2; later per-row pos weight
    __shared__ float s_rel[TILE_E * 3];
    __shared__ int s_dstn[TILE_E], s_srcn[TILE_E];

    const int t = threadIdx.x;
    const int e0 = blockIdx.x * TILE_E;
    const int wv = t >> 6, lane = t & 63, quad = lane >> 4, li = lane & 15;
    const int rowA = wv * 16 + li;
    const int rowC = wv * 16 + quad * 4;

    // ---- phase 1: meta + w1c + W2 chunk0 ----
    if (t < TILE_E) {
        int e = e0 + t;
        int sN = ssrc[e], dN = sdst[e];
        s_dstn[t] = dN; s_srcn[t] = sN;
        float r0 = posf[dN * 3 + 0] - posf[sN * 3 + 0];
        float r1 = posf[dN * 3 + 1] - posf[sN * 3 + 1];
        float r2 = posf[dN * 3 + 2] - posf[sN * 3 + 2];
        s_rel[t * 3 + 0] = r0; s_rel[t * 3 + 1] = r1; s_rel[t * 3 + 2] = r2;
        s_d2[t] = r0 * r0 + r1 * r1 + r2 * r2;
    }
    if (t < 128) s_w1c[t] = w1c_g[t];
    stage_w64(W2t, s_w, t, 0, 64);
    __syncthreads();

    // ---- phase 2: t1 = silu(u[dst] + v[src] + d2*w1c) ----
    {
        int el = t >> 2, part = t & 3;
        int dN = s_dstn[el], sN = s_srcn[el];
        const uint4* up = (const uint4*)((const u32*)uv + (size_t)dN * 128 + part * 16);
        const uint4* vp = (const uint4*)((const u32*)uv + (size_t)sN * 128 + 64 + part * 16);
        float d2 = s_d2[el];
        u32* outp = (u32*)s_act + el * (ACT_STRIDE / 2) + part * 16;
        const float* wc = s_w1c + part * 32;
#pragma unroll
        for (int q4 = 0; q4 < 4; ++q4) {
            uint4 uu = up[q4];
            uint4 vv = vp[q4];
            u32 res[4];
#pragma unroll
            for (int j = 0; j < 4; ++j) {
                u32 ua = ((const u32*)&uu)[j], va = ((const u32*)&vv)[j];
                int col = q4 * 8 + j * 2;
                float x0 = fmaf(d2, wc[col],     bflo(ua) + bflo(va));
                float x1 = fmaf(d2, wc[col + 1], bfhi(ua) + bfhi(va));
                res[j] = (u32)f2bf(silu_f(x0)) | ((u32)f2bf(silu_f(x1)) << 16);
            }
            *(uint4*)(outp + q4 * 4) = *(uint4*)res;
        }
    }
    __syncthreads();

    // ---- L2 matmul: m_pre = t1 @ W2 + b2 ----
    float4v acc[8];
#pragma unroll
    for (int c = 0; c < 8; ++c) {
        float bias = b2[c * 16 + li];
#pragma unroll
        for (int r = 0; r < 4; ++r) acc[c][r] = bias;
    }
#pragma unroll
    for (int p = 0; p < 2; ++p) {
        if (p) {
            __syncthreads();
            stage_w64(W2t, s_w, t, 1, 64);
            __syncthreads();
        }
#pragma unroll
        for (int kk2 = 0; kk2 < 2; ++kk2) {
            const bf16x8 av = *(const bf16x8*)(s_act + rowA * ACT_STRIDE + p * 64 + kk2 * 32 + quad * 8);
#pragma unroll
            for (int c = 0; c < 8; ++c) {
                const bf16x8 bv = *(const bf16x8*)(s_w + (c * 16 + li) * W_STRIDE + kk2 * 32 + quad * 8);
                acc[c] = __builtin_amdgcn_mfma_f32_16x16x32_bf16(av, bv, acc[c], 0, 0, 0);
            }
        }
    }
    __syncthreads();   // all waves done reading t1 + s_w

    // ---- m -> s_act (overwrite); stage pW1 chunk0 ----
#pragma unroll
    for (int c = 0; c < 8; ++c) {
        int col = c * 16 + li;
#pragma unroll
        for (int r = 0; r < 4; ++r)
            s_act[(rowC + r) * ACT_STRIDE + col] = f2bf(silu_f(acc[c][r]));
    }
    stage_w64(pW1t, s_w, t, 0, 64);
    __syncthreads();

    // ---- agg segmented reduction (4 row-groups x 64 col-pairs) ----
    {
        int c32 = t & 63, grp = t >> 6;
        int r0 = grp * 16;
        float run0 = 0.f, run1 = 0.f;
        int cur = s_dstn[r0];
        for (int r = r0; r < r0 + 16; ++r) {
            int dn = s_dstn[r];
            if (dn != cur) {
                atomicAdd(&agg[(size_t)cur * HID + 2 * c32], run0);
                atomicAdd(&agg[(size_t)cur * HID + 2 * c32 + 1], run1);
                run0 = run1 = 0.f; cur = dn;
            }
            u32 mm = *((const u32*)s_act + r * (ACT_STRIDE / 2) + c32);
            run0 += bflo(mm);
            run1 += bfhi(mm);
        }
        atomicAdd(&agg[(size_t)cur * HID + 2 * c32], run0);
        atomicAdd(&agg[(size_t)cur * HID + 2 * c32 + 1], run1);
    }

    // ---- pos MLP matmul: t2_pre = m @ pW1 + pb1 ----
#pragma unroll
    for (int c = 0; c < 8; ++c) {
        float bias = pb1[c * 16 + li];
#pragma unroll
        for (int r = 0; r < 4; ++r) acc[c][r] = bias;
    }
#pragma unroll
    for (int p = 0; p < 2; ++p) {
        if (p) {
            __syncthreads();
            stage_w64(pW1t, s_w, t, 1, 64);
            __syncthreads();
        }
#pragma unroll
        for (int kk2 = 0; kk2 < 2; ++kk2) {
            const bf16x8 av = *(const bf16x8*)(s_act + rowA * ACT_STRIDE + p * 64 + kk2 * 32 + quad * 8);
#pragma unroll
            for (int c = 0; c < 8; ++c) {
                const bf16x8 bv = *(const bf16x8*)(s_w + (c * 16 + li) * W_STRIDE + kk2 * 32 + quad * 8);
                acc[c] = __builtin_amdgcn_mfma_f32_16x16x32_bf16(av, bv, acc[c], 0, 0, 0);
            }
        }
    }
    float part[4] = {0.f, 0.f, 0.f, 0.f};
#pragma unroll
    for (int c = 0; c < 8; ++c) {
        float pw = pW2[c * 16 + li];
#pragma unroll
        for (int r = 0; r < 4; ++r) part[r] += silu_f(acc[c][r]) * pw;
    }
#pragma unroll
    for (int r = 0; r < 4; ++r) {
        part[r] += __shfl_xor(part[r], 1, 64);
        part[r] += __shfl_xor(part[r], 2, 64);
        part[r] += __shfl_xor(part[r], 4, 64);
        part[r] += __shfl_xor(part[r], 8, 64);
    }
    __syncthreads();     // s_d2 done as d2; reuse for per-row w
    if (li == 0) {
        float pb2v = pb2[0];
#pragma unroll
        for (int r = 0; r < 4; ++r) s_d2[rowC + r] = part[r] + pb2v;
    }
    __syncthreads();
    if (t < 12) {   // 3 axes x 4 row-groups
        int a = t % 3, grp = t / 3;
        int r0 = grp * 16;
        float run = 0.f;
        int cur = s_dstn[r0];
        for (int r = r0; r < r0 + 16; ++r) {
            int dn = s_dstn[r];
            if (dn != cur) {
                atomicAdd(&pd[(size_t)cur * 3 + a], run);
                run = 0.f; cur = dn;
            }
            run += s_rel[r * 3 + a] * s_d2[r];
        }
        atomicAdd(&pd[(size_t)cur * 3 + a], run);
    }
}

// ================= MFMA node kernel =================
#define A_STRIDE 264

__global__ __launch_bounds__(256, 3) void node_mfma_kernel(
    const u16* __restrict__ h_in, const float* __restrict__ agg,
    const u16* __restrict__ W1t, const float* __restrict__ b1,
    const u16* __restrict__ W2t, const float* __restrict__ b2,
    u16* __restrict__ h_out,
    float* __restrict__ posf, const float* __restrict__ pd, const int* __restrict__ cnt)
{
    __shared__ __align__(16) u16 s_a[64 * A_STRIDE];
    __shared__ __align__(16) u16 s_w[128 * W_STRIDE];

    const int t = threadIdx.x;
    const int n0 = blockIdx.x * 64;
    const int wv = t >> 6, lane = t & 63, quad = lane >> 4, li = lane & 15;
    const int rowA = wv * 16 + li;
    const int rowC = wv * 16 + quad * 4;

    {   // A = [h bf16 | f2bf(agg)]
        int nl = t >> 2, part = t & 3;
        const uint4* hp = (const uint4*)((const u32*)h_in + (size_t)(n0 + nl) * 64 + part * 16);
        u32* rowp = (u32*)s_a + nl * (A_STRIDE / 2) + part * 16;
#pragma unroll
        for (int j = 0; j < 4; ++j) *(uint4*)(rowp + j * 4) = hp[j];
        const float* ap = agg + (size_t)(n0 + nl) * HID + part * 32;
        rowp += 64;
#pragma unroll
        for (int j = 0; j < 16; ++j) {
            float2 v = *(const float2*)(ap + j * 2);
            rowp[j] = (u32)f2bf(v.x) | ((u32)f2bf(v.y) << 16);
        }
    }
    stage_w64(W1t, s_w, t, 0, 128);
    __syncthreads();

    float4v acc[8];
#pragma unroll
    for (int c = 0; c < 8; ++c) {
        float bias = b1[c * 16 + li];
#pragma unroll
        for (int r = 0; r < 4; ++r) acc[c][r] = bias;
    }
#pragma unroll
    for (int p = 0; p < 4; ++p) {
        if (p) {
            __syncthreads();
            stage_w64(W1t, s_w, t, p, 128);
            __syncthreads();
        }
#pragma unroll
        for (int kk2 = 0; kk2 < 2; ++kk2) {
            const bf16x8 av = *(const bf16x8*)(s_a + rowA * A_STRIDE + p * 64 + kk2 * 32 + quad * 8);
#pragma unroll
            for (int c = 0; c < 8; ++c) {
                const bf16x8 bv = *(const bf16x8*)(s_w + (c * 16 + li) * W_STRIDE + kk2 * 32 + quad * 8);
                acc[c] = __builtin_amdgcn_mfma_f32_16x16x32_bf16(av, bv, acc[c], 0, 0, 0);
            }
        }
    }

    __syncthreads();
    u16* s_t1 = s_a;
#pragma unroll
    for (int c = 0; c < 8; ++c) {
        int col = c * 16 + li;
#pragma unroll
        for (int r = 0; r < 4; ++r)
            s_t1[(rowC + r) * ACT_STRIDE + col] = f2bf(silu_f(acc[c][r]));
    }
    stage_w64(W2t, s_w, t, 0, 64);
    __syncthreads();

#pragma unroll
    for (int c = 0; c < 8; ++c) {
        float bias = b2[c * 16 + li];
#pragma unroll
        for (int r = 0; r < 4; ++r) acc[c][r] = bias;
    }
#pragma unroll
    for (int p = 0; p < 2; ++p) {
        if (p) {
            __syncthreads();
            stage_w64(W2t, s_w, t, 1, 64);
            __syncthreads();
        }
#pragma unroll
        for (int kk2 = 0; kk2 < 2; ++kk2) {
            const bf16x8 av = *(const bf16x8*)(s_t1 + rowA * ACT_STRIDE + p * 64 + kk2 * 32 + quad * 8);
#pragma unroll
            for (int c = 0; c < 8; ++c) {
                const bf16x8 bv = *(const bf16x8*)(s_w + (c * 16 + li) * W_STRIDE + kk2 * 32 + quad * 8);
                acc[c] = __builtin_amdgcn_mfma_f32_16x16x32_bf16(av, bv, acc[c], 0, 0, 0);
            }
        }
    }

#pragma unroll
    for (int c = 0; c < 8; ++c) {
        int col = c * 16 + li;
#pragma unroll
        for (int r = 0; r < 4; ++r)
            h_out[(size_t)(n0 + rowC + r) * HID + col] = f2bf(acc[c][r]);
    }
    if (t < 192) {
        int nl = t / 3, a = t % 3;
        int n = n0 + nl;
        float dg = (float)cnt[n];
        dg = dg < 1.0f ? 1.0f : dg;
        posf[n * 3 + a] += pd[n * 3 + a] / dg;
    }
}

// ---------------- output ----------------
__global__ void out_kernel(const u16* __restrict__ h, const float* __restrict__ posf,
                           void* __restrict__ out, const int* __restrict__ flags)
{
    int i = blockIdx.x * blockDim.x + threadIdx.x;
    const int isbf = flags[0];
    if (i < N_NODES * HID) {
        if (isbf) ((u16*)out)[i] = h[i];
        else      ((float*)out)[i] = bf2f(h[i]);
    }
    if (i < N_NODES * 3) {
        if (isbf) ((u16*)out)[N_NODES * HID + i] = f2bf(posf[i]);
        else      ((float*)out)[N_NODES * HID + i] = posf[i];
    }
}

extern "C" void kernel_launch(void* const* d_in, const int* in_sizes, int n_in,
                              void* d_out, int out_size, void* d_ws, size_t ws_size,
                              hipStream_t stream) {
    (void)in_sizes; (void)n_in; (void)out_size; (void)ws_size;

    const void* eidx_raw = d_in[0];
    const void* x_raw    = d_in[1];
    const void* pos_raw  = d_in[2];
    const void* embW_raw = d_in[3];
    const void* embB_raw = d_in[4];
    const void* eW1_raw  = d_in[5];
    const void* eB1_raw  = d_in[6];
    const void* eW2_raw  = d_in[7];
    const void* eB2_raw  = d_in[8];
    const void* nW1_raw  = d_in[9];
    const void* nB1_raw  = d_in[10];
    const void* nW2_raw  = d_in[11];
    const void* nB2_raw  = d_in[12];
    const void* pW1_raw  = d_in[13];
    const void* pB1_raw  = d_in[14];
    const void* pW2_raw  = d_in[15];
    const void* pB2_raw  = d_in[16];

    float* ws   = (float*)d_ws;
    float* posf = ws;                            //   120,000
    float* agg  = posf + (size_t)N_NODES * 3;    // 5,120,000
    float* pd   = agg + (size_t)N_NODES * HID;   //   120,000 (contiguous w/ agg)
    float* embW = pd + (size_t)N_NODES * 3;      // 8,192
    float* embB = embW + 8192;                   // 128
    float* eB1f = embB + 128;                    // 384
    float* eB2f = eB1f + 384;
    float* pB1f = eB2f + 384;
    float* pB2f = pB1f + 384;                    // 4
    float* pW2f = pB2f + 4;                      // 384
    float* W1r  = pW2f + 384;                    // 384
    float* nB1f = W1r + 384;
    float* nB2f = nB1f + 384;
    float* fend = nB2f + 384;

    u16* W1abt = (u16*)fend;                     // 3*256*128 = 98,304
    u16* W2t   = W1abt + 3 * 256 * 128;          // 49,152
    u16* pW1t  = W2t + 3 * 128 * 128;            // 49,152
    u16* nW1t  = pW1t + 3 * 128 * 128;           // 98,304
    u16* nW2t  = nW1t + 3 * 128 * 256;           // 49,152
    u16* h0    = nW2t + 3 * 128 * 128;           // 5,120,000
    u16* h1    = h0 + (size_t)N_NODES * HID;     // 5,120,000
    u16* uvb   = h1 + (size_t)N_NODES * HID;     // 10,240,000
    int* ssrc  = (int*)(uvb + (size_t)N_NODES * 256);
    int* sdst  = ssrc + N_EDGES;
    int* cnt   = sdst + N_EDGES;                 // 40,000
    int* cur   = cnt + N_NODES;                  // 40,000
    int* offs  = cur + N_NODES;                  // 40,001
    int* flags = offs + N_NODES + 3;
    // src32/dst32 live inside uvb (dead until uv_kernel runs, after sort)
    int* src32 = (int*)uvb;
    int* dst32 = src32 + N_EDGES;
    // total ws ≈ 68.8 MB (round-1's 69.2 MB layout passed)

    detect_kernel<<<1, 256, 0, stream>>>(embW_raw, eidx_raw, flags);
    cvt_idx_kernel<<<(2 * N_EDGES + 255) / 256, 256, 0, stream>>>(eidx_raw, src32, 2 * N_EDGES, flags);

    cvt_f_kernel<<<32, 256, 0, stream>>>(embW_raw, embW, 8192, flags);
    cvt_f_kernel<<<1, 128, 0, stream>>>(embB_raw, embB, 128, flags);
    cvt_f_kernel<<<2, 256, 0, stream>>>(eB1_raw, eB1f, 3 * HID, flags);
    cvt_f_kernel<<<2, 256, 0, stream>>>(eB2_raw, eB2f, 3 * HID, flags);
    cvt_f_kernel<<<2, 256, 0, stream>>>(pB1_raw, pB1f, 3 * HID, flags);
    cvt_f_kernel<<<1, 64, 0, stream>>>(pB2_raw, pB2f, 3, flags);
    cvt_f_kernel<<<2, 256, 0, stream>>>(pW2_raw, pW2f, 3 * HID, flags);
    cvt_f_kernel<<<2, 256, 0, stream>>>(nB1_raw, nB1f, 3 * HID, flags);
    cvt_f_kernel<<<2, 256, 0, stream>>>(nB2_raw, nB2f, 3 * HID, flags);
    w1row_kernel<<<2, 256, 0, stream>>>(eW1_raw, W1r, flags);

    w1ab_kernel<<<dim3(128, 3), 256, 0, stream>>>(eW1_raw, W1abt, flags);
    tcvt_kernel<<<dim3(64, 3), 256, 0, stream>>>(eW2_raw, W2t, 128 * 128, 7, 128 * 128, 128 * 128, flags);
    tcvt_kernel<<<dim3(64, 3), 256, 0, stream>>>(pW1_raw, pW1t, 128 * 128, 7, 128 * 128, 128 * 128, flags);
    tcvt_kernel<<<dim3(128, 3), 256, 0, stream>>>(nW1_raw, nW1t, 128 * 256, 8, 2 * HID * HID, 128 * 256, flags);
    tcvt_kernel<<<dim3(64, 3), 256, 0, stream>>>(nW2_raw, nW2t, 128 * 128, 7, 128 * 128, 128 * 128, flags);

    hipMemsetAsync(cnt, 0, 2 * (size_t)N_NODES * sizeof(int), stream);
    cnt_kernel<<<(N_EDGES + 255) / 256, 256, 0, stream>>>(dst32, cnt);
    scan_kernel<<<1, 1024, 0, stream>>>(cnt, offs);
    scatter_kernel<<<(N_EDGES + 255) / 256, 256, 0, stream>>>(src32, dst32, offs, cur, ssrc, sdst);

    posinit_kernel<<<(N_NODES * 3 + 255) / 256, 256, 0, stream>>>(pos_raw, posf, flags);
    embed_kernel<<<N_NODES, 64, 0, stream>>>(x_raw, embW, embB, h0, flags);

    u16* hin = h0;
    u16* hout = h1;
    for (int l = 0; l < N_LAYERS; ++l) {
        uv_kernel<<<N_NODES / 64, 256, 0, stream>>>(hin, W1abt + (size_t)l * 32768, eB1f + l * HID, uvb);
        hipMemsetAsync(agg, 0, ((size_t)N_NODES * HID + (size_t)N_NODES * 3) * sizeof(float), stream);
        edge_mfma_kernel<<<N_EDGES / TILE_E, 256, 0, stream>>>(
            ssrc, sdst, uvb, posf,
            W1r + l * HID,
            W2t + (size_t)l * 128 * 128, eB2f + l * HID,
            pW1t + (size_t)l * 128 * 128, pB1f + l * HID,
            pW2f + l * HID, pB2f + l,
            agg, pd);
        node_mfma_kernel<<<N_NODES / 64, 256, 0, stream>>>(
            hin, agg,
            nW1t + (size_t)l * 128 * 256, nB1f + l * HID,
            nW2t + (size_t)l * 128 * 128, nB2f + l * HID,
            hout, posf, pd, cnt);
        u16* tmp = hin; hin = hout; hout = tmp;
    }

    out_kernel<<<(N_NODES * HID + 255) / 256, 256, 0, stream>>>(hin, posf, d_out, flags);
}

// Round 6
// 832.684 us; speedup vs baseline: 34.0150x; 1.0656x over previous
//
#include <hip/hip_runtime.h>
#include <hip/hip_bf16.h>

#define N_NODES 40000
#define N_EDGES 640000
#define IN_CH 64
#define HID 128
#define N_LAYERS 3

typedef unsigned short u16;
typedef unsigned int u32;

typedef __attribute__((ext_vector_type(8))) __bf16 bf16x8;
typedef __attribute__((ext_vector_type(4))) float float4v;

__device__ __forceinline__ float bf2f(u16 u) {
    union { u32 i; float f; } v; v.i = ((u32)u) << 16; return v.f;
}
__device__ __forceinline__ float bflo(u32 p) {
    union { u32 i; float f; } v; v.i = p << 16; return v.f;
}
__device__ __forceinline__ float bfhi(u32 p) {
    union { u32 i; float f; } v; v.i = p & 0xffff0000u; return v.f;
}
__device__ __forceinline__ u16 f2bf(float f) {
    union { float f; u32 i; } v; v.f = f;
    u32 i = v.i;
    u32 r = (i + 0x7fffu + ((i >> 16) & 1u)) >> 16;
    return (u16)r;
}
#if __has_builtin(__builtin_amdgcn_cvt_pk_bf16_f32)
typedef __attribute__((ext_vector_type(2))) __bf16 bf16x2_t;
__device__ __forceinline__ u32 pk2bf(float a, float b) {
    bf16x2_t p = __builtin_amdgcn_cvt_pk_bf16_f32(a, b);
    union { bf16x2_t v; u32 u; } c; c.v = p; return c.u;
}
#else
__device__ __forceinline__ u32 pk2bf(float a, float b) {
    return (u32)f2bf(a) | ((u32)f2bf(b) << 16);
}
#endif
__device__ __forceinline__ float silu_f(float x) {
    float d = 1.0f + __expf(-x);
#if __has_builtin(__builtin_amdgcn_rcpf)
    return x * __builtin_amdgcn_rcpf(d);
#else
    return __fdividef(x, d);
#endif
}

// ---- LDS weight staging: 128 rows x 64-k chunk ----
#define W_STRIDE 72
__device__ __forceinline__ void stage_w64(const u16* __restrict__ g, u16* s, int t,
                                          int chunk, int rowstride_u32) {
    const u32* gp = (const u32*)g;
    u32* sp = (u32*)s;
#pragma unroll
    for (int it = 0; it < 4; ++it) {
        int i4 = t + it * 256;
        int n = i4 >> 3, j = i4 & 7;
        *(uint4*)(sp + n * 36 + j * 4) = *(const uint4*)(gp + n * rowstride_u32 + chunk * 32 + j * 4);
    }
}

// ---------------- dtype detection ----------------
__global__ void detect_kernel(const void* __restrict__ w_raw,
                              const void* __restrict__ eidx_raw,
                              int* __restrict__ flags) {
    __shared__ int s_big, s_hi;
    if (threadIdx.x == 0) { s_big = 0; s_hi = 0; }
    __syncthreads();
    const u16* w16 = (const u16*)w_raw;
    for (int i = threadIdx.x; i < 8192; i += blockDim.x) {
        float v = bf2f(w16[i]);
        if (!(fabsf(v) <= 1.0f)) s_big = 1;
    }
    const u32* e32 = (const u32*)eidx_raw;
    for (int i = threadIdx.x; i < 256; i += blockDim.x) {
        if (e32[2 * i + 1] != 0u) s_hi = 1;
    }
    __syncthreads();
    if (threadIdx.x == 0) {
        flags[0] = s_big ? 0 : 1;   // 1 => floats are bf16
        flags[1] = s_hi ? 0 : 1;    // 1 => edge_index int64
    }
}

// ---------------- fused small fp32 conversions ----------------
__global__ void small_cvt_kernel(
    const void* __restrict__ embB_raw, const void* __restrict__ eB1_raw,
    const void* __restrict__ eB2_raw, const void* __restrict__ pB1_raw,
    const void* __restrict__ pB2_raw, const void* __restrict__ pW2_raw,
    const void* __restrict__ eW1_raw, const void* __restrict__ nB1_raw,
    const void* __restrict__ nB2_raw,
    float* __restrict__ dstf, const int* __restrict__ flags)
{
    int i = blockIdx.x * blockDim.x + threadIdx.x;
    if (i >= 2820) return;
    const void* src; int si;
    if (i < 128)       { src = embB_raw; si = i; }
    else if (i < 512)  { src = eB1_raw;  si = i - 128; }
    else if (i < 896)  { src = eB2_raw;  si = i - 512; }
    else if (i < 1280) { src = pB1_raw;  si = i - 896; }
    else if (i < 1284) { src = pB2_raw;  si = i - 1280; if (si >= 3) { dstf[i] = 0.f; return; } }
    else if (i < 1668) { src = pW2_raw;  si = i - 1284; }
    else if (i < 2052) { int j = i - 1668; src = eW1_raw; si = (j >> 7) * 32896 + 32768 + (j & 127); }
    else if (i < 2436) { src = nB1_raw;  si = i - 2052; }
    else               { src = nB2_raw;  si = i - 2436; }
    dstf[i] = flags[0] ? bf2f(((const u16*)src)[si]) : ((const float*)src)[si];
}

// ---------------- fused weight transpose+cvt to bf16 [n][k] ----------------
__global__ void wcvt_kernel(
    const void* __restrict__ eW1_raw, const void* __restrict__ eW2_raw,
    const void* __restrict__ pW1_raw, const void* __restrict__ nW1_raw,
    const void* __restrict__ nW2_raw, const void* __restrict__ embW_raw,
    u16* __restrict__ W1abt, u16* __restrict__ W2t, u16* __restrict__ pW1t,
    u16* __restrict__ nW1t, u16* __restrict__ nW2t, u16* __restrict__ embWt,
    const int* __restrict__ flags)
{
    int z = blockIdx.z, l = blockIdx.y;
    int i = blockIdx.x * blockDim.x + threadIdx.x;
    const void* src; u16* dst; int si, di;
    if (z == 0) {           // edge W1 [257][128] -> [o<128: h_i | o>=128: h_j][k]
        if (i >= 32768) return;
        int o = i >> 7, k = i & 127;
        si = l * 32896 + ((o < 128) ? (k * 128 + o) : ((128 + k) * 128 + (o - 128)));
        src = eW1_raw; dst = W1abt; di = l * 32768 + i;
    } else if (z == 1) {
        if (i >= 16384) return;
        int n = i >> 7, k = i & 127;
        si = l * 16384 + k * 128 + n; src = eW2_raw; dst = W2t; di = l * 16384 + i;
    } else if (z == 2) {
        if (i >= 16384) return;
        int n = i >> 7, k = i & 127;
        si = l * 16384 + k * 128 + n; src = pW1_raw; dst = pW1t; di = l * 16384 + i;
    } else if (z == 3) {
        if (i >= 32768) return;
        int n = i >> 8, k = i & 255;
        si = l * 32768 + k * 128 + n; src = nW1_raw; dst = nW1t; di = l * 32768 + i;
    } else if (z == 4) {
        if (i >= 16384) return;
        int n = i >> 7, k = i & 127;
        si = l * 16384 + k * 128 + n; src = nW2_raw; dst = nW2t; di = l * 16384 + i;
    } else {                // emb W [64][128] -> [128][64]
        if (l != 0 || i >= 8192) return;
        int n = i >> 6, k = i & 63;
        si = k * 128 + n; src = embW_raw; dst = embWt; di = i;
    }
    float v = flags[0] ? bf2f(((const u16*)src)[si]) : ((const float*)src)[si];
    dst[di] = f2bf(v);
}

// ---------------- counting sort by dst (reads raw edge_index) ----------------
__global__ void cnt_kernel(const void* __restrict__ eidx, int* __restrict__ cnt,
                           const int* __restrict__ flags) {
    int e = blockIdx.x * blockDim.x + threadIdx.x;
    if (e >= N_EDGES) return;
    int dn = flags[1] ? (int)((const long long*)eidx)[N_EDGES + e]
                      : ((const int*)eidx)[N_EDGES + e];
    atomicAdd(&cnt[dn], 1);
}

__global__ __launch_bounds__(1024) void scan_kernel(const int* __restrict__ cnt,
                                                    int* __restrict__ offs) {
    __shared__ int s_part[1024];
    const int t = threadIdx.x;
    const int base = t * 40;
    int sum = 0;
    for (int j = 0; j < 40; ++j) {
        int idx = base + j;
        sum += (idx < N_NODES) ? cnt[idx] : 0;
    }
    s_part[t] = sum;
    __syncthreads();
    for (int d = 1; d < 1024; d <<= 1) {
        int v = (t >= d) ? s_part[t - d] : 0;
        __syncthreads();
        s_part[t] += v;
        __syncthreads();
    }
    int run = (t == 0) ? 0 : s_part[t - 1];
    for (int j = 0; j < 40; ++j) {
        int idx = base + j;
        if (idx < N_NODES) { offs[idx] = run; run += cnt[idx]; }
    }
    if (t == 1023) offs[N_NODES] = run;
}

__global__ void scatter_kernel(const void* __restrict__ eidx,
                               const int* __restrict__ offs, int* __restrict__ cur,
                               int* __restrict__ ssrc, int* __restrict__ sdst,
                               const int* __restrict__ flags) {
    int e = blockIdx.x * blockDim.x + threadIdx.x;
    if (e >= N_EDGES) return;
    int sn, dn;
    if (flags[1]) {
        sn = (int)((const long long*)eidx)[e];
        dn = (int)((const long long*)eidx)[N_EDGES + e];
    } else {
        sn = ((const int*)eidx)[e];
        dn = ((const int*)eidx)[N_EDGES + e];
    }
    int p = offs[dn] + atomicAdd(&cur[dn], 1);
    ssrc[p] = sn;
    sdst[p] = dn;
}

// ---------------- pos init -> f32 ----------------
__global__ void posinit_kernel(const void* __restrict__ pos_raw, float* __restrict__ posf,
                               const int* __restrict__ flags) {
    int i = blockIdx.x * blockDim.x + threadIdx.x;
    if (i < N_NODES * 3)
        posf[i] = flags[0] ? bf2f(((const u16*)pos_raw)[i]) : ((const float*)pos_raw)[i];
}

#define ACT_STRIDE 136

// ================= fused embed + uv(layer0) =================
__global__ __launch_bounds__(256, 3) void embed_uv_kernel(
    const void* __restrict__ x_raw, const u16* __restrict__ embWt, const float* __restrict__ embB,
    const u16* __restrict__ W1abt, const float* __restrict__ b1,
    u16* __restrict__ h, u16* __restrict__ uv, const int* __restrict__ flags)
{
    __shared__ __align__(16) u16 s_x[64 * 72];
    __shared__ __align__(16) u16 s_h[64 * ACT_STRIDE];
    __shared__ __align__(16) u16 s_w[128 * W_STRIDE];

    const int t = threadIdx.x;
    const int n0 = blockIdx.x * 64;
    const int wv = t >> 6, lane = t & 63, quad = lane >> 4, li = lane & 15;
    const int rowA = wv * 16 + li;
    const int rowC = wv * 16 + quad * 4;

    {   // load x rows -> bf16 LDS
        int el = t >> 2, part = t & 3;
        u32* op = (u32*)s_x + el * 36 + part * 8;
        if (flags[0]) {
            const u32* xp = (const u32*)x_raw + (size_t)(n0 + el) * 32 + part * 8;
            *(uint4*)(op)     = *(const uint4*)(xp);
            *(uint4*)(op + 4) = *(const uint4*)(xp + 4);
        } else {
            const float* xp = (const float*)x_raw + (size_t)(n0 + el) * 64 + part * 16;
#pragma unroll
            for (int j = 0; j < 8; ++j) op[j] = pk2bf(xp[2 * j], xp[2 * j + 1]);
        }
    }
    stage_w64(embWt, s_w, t, 0, 32);
    __syncthreads();

    // h = x @ embW + b  (K=64)
    float4v acc[8];
#pragma unroll
    for (int c = 0; c < 8; ++c) {
        float bias = embB[c * 16 + li];
#pragma unroll
        for (int r = 0; r < 4; ++r) acc[c][r] = bias;
    }
#pragma unroll
    for (int kk2 = 0; kk2 < 2; ++kk2) {
        const bf16x8 av = *(const bf16x8*)(s_x + rowA * 72 + kk2 * 32 + quad * 8);
#pragma unroll
        for (int c = 0; c < 8; ++c) {
            const bf16x8 bv = *(const bf16x8*)(s_w + (c * 16 + li) * W_STRIDE + kk2 * 32 + quad * 8);
            acc[c] = __builtin_amdgcn_mfma_f32_16x16x32_bf16(av, bv, acc[c], 0, 0, 0);
        }
    }
    // write h (global + LDS), pair stores
#pragma unroll
    for (int c = 0; c < 8; ++c) {
        int col = c * 16 + li;
#pragma unroll
        for (int r = 0; r < 4; ++r) {
            float v = acc[c][r];
            float vo = __shfl_xor(v, 1, 64);
            if (!(li & 1)) {
                u32 pkd = pk2bf(v, vo);
                *(u32*)(s_h + (rowC + r) * ACT_STRIDE + col) = pkd;
                *(u32*)(h + (size_t)(n0 + rowC + r) * HID + col) = pkd;
            }
        }
    }

    // uv = [h@W1a + b1 | h@W1b]
    float4v a2[16];
#pragma unroll
    for (int ct = 0; ct < 16; ++ct) {
        float bias = (ct < 8) ? b1[ct * 16 + li] : 0.0f;
#pragma unroll
        for (int r = 0; r < 4; ++r) a2[ct][r] = bias;
    }
#pragma unroll
    for (int half = 0; half < 2; ++half) {
#pragma unroll
        for (int chunk = 0; chunk < 2; ++chunk) {
            __syncthreads();
            stage_w64(W1abt + half * 16384, s_w, t, chunk, 64);
            __syncthreads();
#pragma unroll
            for (int kk2 = 0; kk2 < 2; ++kk2) {
                const bf16x8 av = *(const bf16x8*)(s_h + rowA * ACT_STRIDE + chunk * 64 + kk2 * 32 + quad * 8);
#pragma unroll
                for (int c = 0; c < 8; ++c) {
                    const bf16x8 bv = *(const bf16x8*)(s_w + (c * 16 + li) * W_STRIDE + kk2 * 32 + quad * 8);
                    a2[half * 8 + c] = __builtin_amdgcn_mfma_f32_16x16x32_bf16(av, bv, a2[half * 8 + c], 0, 0, 0);
                }
            }
        }
    }
#pragma unroll
    for (int ct = 0; ct < 16; ++ct) {
        int col = (ct >> 3) * 128 + (ct & 7) * 16 + li;
#pragma unroll
        for (int r = 0; r < 4; ++r) {
            float v = a2[ct][r];
            float vo = __shfl_xor(v, 1, 64);
            if (!(li & 1))
                *(u32*)(uv + (size_t)(n0 + rowC + r) * 256 + col) = pk2bf(v, vo);
        }
    }
}

// ================= edge kernel =================
#define TILE_E 64

__global__ __launch_bounds__(256, 4) void edge_mfma_kernel(
    const int* __restrict__ ssrc, const int* __restrict__ sdst,
    const u16* __restrict__ uv, const float* __restrict__ posf,
    const float* __restrict__ w1c_g,
    const u16* __restrict__ W2t, const float* __restrict__ b2,
    const u16* __restrict__ pW1t, const float* __restrict__ pb1,
    const float* __restrict__ pW2, const float* __restrict__ pb2,
    float* __restrict__ agg, float* __restrict__ pd)
{
    __shared__ __align__(16) u16 s_act[TILE_E * ACT_STRIDE];
    __shared__ __align__(16) u16 s_w[128 * W_STRIDE];
    __shared__ float s_w1c[128];
    __shared__ float s_d2[TILE_E];
    __shared__ float s_rel[TILE_E * 3];
    __shared__ int s_dstn[TILE_E], s_srcn[TILE_E];

    const int t = threadIdx.x;
    const int e0 = blockIdx.x * TILE_E;
    const int wv = t >> 6, lane = t & 63, quad = lane >> 4, li = lane & 15;
    const int rowA = wv * 16 + li;
    const int rowC = wv * 16 + quad * 4;

    if (t < TILE_E) {
        int e = e0 + t;
        int sN = ssrc[e], dN = sdst[e];
        s_dstn[t] = dN; s_srcn[t] = sN;
        float r0 = posf[dN * 3 + 0] - posf[sN * 3 + 0];
        float r1 = posf[dN * 3 + 1] - posf[sN * 3 + 1];
        float r2 = posf[dN * 3 + 2] - posf[sN * 3 + 2];
        s_rel[t * 3 + 0] = r0; s_rel[t * 3 + 1] = r1; s_rel[t * 3 + 2] = r2;
        s_d2[t] = r0 * r0 + r1 * r1 + r2 * r2;
    }
    if (t < 128) s_w1c[t] = w1c_g[t];
    stage_w64(W2t, s_w, t, 0, 64);
    __syncthreads();

    // t1 = silu(u[dst] + v[src] + d2*w1c)
    {
        int el = t >> 2, part = t & 3;
        int dN = s_dstn[el], sN = s_srcn[el];
        const uint4* up = (const uint4*)((const u32*)uv + (size_t)dN * 128 + part * 16);
        const uint4* vp = (const uint4*)((const u32*)uv + (size_t)sN * 128 + 64 + part * 16);
        float d2 = s_d2[el];
        u32* outp = (u32*)s_act + el * (ACT_STRIDE / 2) + part * 16;
        const float* wc = s_w1c + part * 32;
#pragma unroll
        for (int q4 = 0; q4 < 4; ++q4) {
            uint4 uu = up[q4];
            uint4 vv = vp[q4];
            u32 res[4];
#pragma unroll
            for (int j = 0; j < 4; ++j) {
                u32 ua = ((const u32*)&uu)[j], va = ((const u32*)&vv)[j];
                int col = q4 * 8 + j * 2;
                float x0 = fmaf(d2, wc[col],     bflo(ua) + bflo(va));
                float x1 = fmaf(d2, wc[col + 1], bfhi(ua) + bfhi(va));
                res[j] = pk2bf(silu_f(x0), silu_f(x1));
            }
            *(uint4*)(outp + q4 * 4) = *(uint4*)res;
        }
    }
    __syncthreads();

    // m_pre = t1 @ W2 + b2
    float4v acc[8];
#pragma unroll
    for (int c = 0; c < 8; ++c) {
        float bias = b2[c * 16 + li];
#pragma unroll
        for (int r = 0; r < 4; ++r) acc[c][r] = bias;
    }
#pragma unroll
    for (int p = 0; p < 2; ++p) {
        if (p) {
            __syncthreads();
            stage_w64(W2t, s_w, t, 1, 64);
            __syncthreads();
        }
#pragma unroll
        for (int kk2 = 0; kk2 < 2; ++kk2) {
            const bf16x8 av = *(const bf16x8*)(s_act + rowA * ACT_STRIDE + p * 64 + kk2 * 32 + quad * 8);
#pragma unroll
            for (int c = 0; c < 8; ++c) {
                const bf16x8 bv = *(const bf16x8*)(s_w + (c * 16 + li) * W_STRIDE + kk2 * 32 + quad * 8);
                acc[c] = __builtin_amdgcn_mfma_f32_16x16x32_bf16(av, bv, acc[c], 0, 0, 0);
            }
        }
    }
    __syncthreads();

    // m -> s_act (pair stores); stage pW1 chunk0
#pragma unroll
    for (int c = 0; c < 8; ++c) {
        int col = c * 16 + li;
#pragma unroll
        for (int r = 0; r < 4; ++r) {
            float m = silu_f(acc[c][r]);
            float mo = __shfl_xor(m, 1, 64);
            if (!(li & 1))
                *(u32*)(s_act + (rowC + r) * ACT_STRIDE + col) = pk2bf(m, mo);
        }
    }
    stage_w64(pW1t, s_w, t, 0, 64);
    __syncthreads();

    // agg segmented reduction
    {
        int c32 = t & 63, grp = t >> 6;
        int r0 = grp * 16;
        float run0 = 0.f, run1 = 0.f;
        int cur = s_dstn[r0];
        for (int r = r0; r < r0 + 16; ++r) {
            int dn = s_dstn[r];
            if (dn != cur) {
                atomicAdd(&agg[(size_t)cur * HID + 2 * c32], run0);
                atomicAdd(&agg[(size_t)cur * HID + 2 * c32 + 1], run1);
                run0 = run1 = 0.f; cur = dn;
            }
            u32 mm = *((const u32*)s_act + r * (ACT_STRIDE / 2) + c32);
            run0 += bflo(mm);
            run1 += bfhi(mm);
        }
        atomicAdd(&agg[(size_t)cur * HID + 2 * c32], run0);
        atomicAdd(&agg[(size_t)cur * HID + 2 * c32 + 1], run1);
    }

    // pos MLP
#pragma unroll
    for (int c = 0; c < 8; ++c) {
        float bias = pb1[c * 16 + li];
#pragma unroll
        for (int r = 0; r < 4; ++r) acc[c][r] = bias;
    }
#pragma unroll
    for (int p = 0; p < 2; ++p) {
        if (p) {
            __syncthreads();
            stage_w64(pW1t, s_w, t, 1, 64);
            __syncthreads();
        }
#pragma unroll
        for (int kk2 = 0; kk2 < 2; ++kk2) {
            const bf16x8 av = *(const bf16x8*)(s_act + rowA * ACT_STRIDE + p * 64 + kk2 * 32 + quad * 8);
#pragma unroll
            for (int c = 0; c < 8; ++c) {
                const bf16x8 bv = *(const bf16x8*)(s_w + (c * 16 + li) * W_STRIDE + kk2 * 32 + quad * 8);
                acc[c] = __builtin_amdgcn_mfma_f32_16x16x32_bf16(av, bv, acc[c], 0, 0, 0);
            }
        }
    }
    float part[4] = {0.f, 0.f, 0.f, 0.f};
#pragma unroll
    for (int c = 0; c < 8; ++c) {
        float pw = pW2[c * 16 + li];
#pragma unroll
        for (int r = 0; r < 4; ++r) part[r] += silu_f(acc[c][r]) * pw;
    }
#pragma unroll
    for (int r = 0; r < 4; ++r) {
        part[r] += __shfl_xor(part[r], 1, 64);
        part[r] += __shfl_xor(part[r], 2, 64);
        part[r] += __shfl_xor(part[r], 4, 64);
        part[r] += __shfl_xor(part[r], 8, 64);
    }
    __syncthreads();
    if (li == 0) {
        float pb2v = pb2[0];
#pragma unroll
        for (int r = 0; r < 4; ++r) s_d2[rowC + r] = part[r] + pb2v;
    }
    __syncthreads();
    if (t < 12) {
        int a = t % 3, grp = t / 3;
        int r0 = grp * 16;
        float run = 0.f;
        int cur = s_dstn[r0];
        for (int r = r0; r < r0 + 16; ++r) {
            int dn = s_dstn[r];
            if (dn != cur) {
                atomicAdd(&pd[(size_t)cur * 3 + a], run);
                run = 0.f; cur = dn;
            }
            run += s_rel[r * 3 + a] * s_d2[r];
        }
        atomicAdd(&pd[(size_t)cur * 3 + a], run);
    }
}

// ================= fused node MLP + uv(next layer) + output =================
#define A_STRIDE 264

__global__ __launch_bounds__(256, 3) void node_uv_kernel(
    const u16* __restrict__ h_in, float* __restrict__ agg,
    const u16* __restrict__ W1t, const float* __restrict__ b1,
    const u16* __restrict__ W2t, const float* __restrict__ b2,
    const u16* __restrict__ W1abt_nx, const float* __restrict__ b1_nx,
    u16* __restrict__ h_out, u16* __restrict__ uv,
    float* __restrict__ posf, float* __restrict__ pd, const int* __restrict__ cnt,
    void* __restrict__ outp, const int* __restrict__ flags, int do_out)
{
    __shared__ __align__(16) u16 s_a[64 * A_STRIDE];
    __shared__ __align__(16) u16 s_w[128 * W_STRIDE];

    const int t = threadIdx.x;
    const int n0 = blockIdx.x * 64;
    const int wv = t >> 6, lane = t & 63, quad = lane >> 4, li = lane & 15;
    const int rowA = wv * 16 + li;
    const int rowC = wv * 16 + quad * 4;

    {   // A = [h | bf16(agg)]; zero agg after read
        int nl = t >> 2, part = t & 3;
        const uint4* hp = (const uint4*)((const u32*)h_in + (size_t)(n0 + nl) * 64 + part * 16);
        u32* rowp = (u32*)s_a + nl * (A_STRIDE / 2) + part * 16;
#pragma unroll
        for (int j = 0; j < 4; ++j) *(uint4*)(rowp + j * 4) = hp[j];
        float* ap = agg + (size_t)(n0 + nl) * HID + part * 32;
        rowp += 64;
#pragma unroll
        for (int j = 0; j < 16; ++j) {
            float2 v = *(const float2*)(ap + j * 2);
            rowp[j] = pk2bf(v.x, v.y);
        }
        float4 z = {0.f, 0.f, 0.f, 0.f};
#pragma unroll
        for (int j = 0; j < 8; ++j) *(float4*)(ap + j * 4) = z;
    }
    stage_w64(W1t, s_w, t, 0, 128);
    __syncthreads();

    float4v acc[8];
#pragma unroll
    for (int c = 0; c < 8; ++c) {
        float bias = b1[c * 16 + li];
#pragma unroll
        for (int r = 0; r < 4; ++r) acc[c][r] = bias;
    }
#pragma unroll
    for (int p = 0; p < 4; ++p) {
        if (p) {
            __syncthreads();
            stage_w64(W1t, s_w, t, p, 128);
            __syncthreads();
        }
#pragma unroll
        for (int kk2 = 0; kk2 < 2; ++kk2) {
            const bf16x8 av = *(const bf16x8*)(s_a + rowA * A_STRIDE + p * 64 + kk2 * 32 + quad * 8);
#pragma unroll
            for (int c = 0; c < 8; ++c) {
                const bf16x8 bv = *(const bf16x8*)(s_w + (c * 16 + li) * W_STRIDE + kk2 * 32 + quad * 8);
                acc[c] = __builtin_amdgcn_mfma_f32_16x16x32_bf16(av, bv, acc[c], 0, 0, 0);
            }
        }
    }

    __syncthreads();
    u16* s_t1 = s_a;   // overlay
#pragma unroll
    for (int c = 0; c < 8; ++c) {
        int col = c * 16 + li;
#pragma unroll
        for (int r = 0; r < 4; ++r) {
            float v = silu_f(acc[c][r]);
            float vo = __shfl_xor(v, 1, 64);
            if (!(li & 1))
                *(u32*)(s_t1 + (rowC + r) * ACT_STRIDE + col) = pk2bf(v, vo);
        }
    }
    stage_w64(W2t, s_w, t, 0, 64);
    __syncthreads();

#pragma unroll
    for (int c = 0; c < 8; ++c) {
        float bias = b2[c * 16 + li];
#pragma unroll
        for (int r = 0; r < 4; ++r) acc[c][r] = bias;
    }
#pragma unroll
    for (int p = 0; p < 2; ++p) {
        if (p) {
            __syncthreads();
            stage_w64(W2t, s_w, t, 1, 64);
            __syncthreads();
        }
#pragma unroll
        for (int kk2 = 0; kk2 < 2; ++kk2) {
            const bf16x8 av = *(const bf16x8*)(s_t1 + rowA * ACT_STRIDE + p * 64 + kk2 * 32 + quad * 8);
#pragma unroll
            for (int c = 0; c < 8; ++c) {
                const bf16x8 bv = *(const bf16x8*)(s_w + (c * 16 + li) * W_STRIDE + kk2 * 32 + quad * 8);
                acc[c] = __builtin_amdgcn_mfma_f32_16x16x32_bf16(av, bv, acc[c], 0, 0, 0);
            }
        }
    }

    // epilogue: h
    if (do_out) {
        if (flags[0]) {
#pragma unroll
            for (int c = 0; c < 8; ++c) {
                int col = c * 16 + li;
#pragma unroll
                for (int r = 0; r < 4; ++r) {
                    float v = acc[c][r];
                    float vo = __shfl_xor(v, 1, 64);
                    if (!(li & 1))
                        *(u32*)((u16*)outp + (size_t)(n0 + rowC + r) * HID + col) = pk2bf(v, vo);
                }
            }
        } else {
#pragma unroll
            for (int c = 0; c < 8; ++c) {
                int col = c * 16 + li;
#pragma unroll
                for (int r = 0; r < 4; ++r)
                    ((float*)outp)[(size_t)(n0 + rowC + r) * HID + col] = acc[c][r];
            }
        }
    } else {
#pragma unroll
        for (int c = 0; c < 8; ++c) {
            int col = c * 16 + li;
#pragma unroll
            for (int r = 0; r < 4; ++r) {
                float v = acc[c][r];
                float vo = __shfl_xor(v, 1, 64);
                if (!(li & 1)) {
                    u32 pkd = pk2bf(v, vo);
                    *(u32*)(s_t1 + (rowC + r) * ACT_STRIDE + col) = pkd;
                    *(u32*)(h_out + (size_t)(n0 + rowC + r) * HID + col) = pkd;
                }
            }
        }
    }

    // pos update + pd zero (+ pos out)
    if (t < 192) {
        int nl = t / 3, a = t % 3;
        int n = n0 + nl;
        float dg = (float)cnt[n];
        dg = dg < 1.0f ? 1.0f : dg;
        float np = posf[n * 3 + a] + pd[n * 3 + a] / dg;
        posf[n * 3 + a] = np;
        pd[n * 3 + a] = 0.f;
        if (do_out) {
            if (flags[0]) ((u16*)outp)[(size_t)N_NODES * HID + n * 3 + a] = f2bf(np);
            else          ((float*)outp)[(size_t)N_NODES * HID + n * 3 + a] = np;
        }
    }

    if (do_out) return;

    // uv for next layer
    float4v a2[16];
#pragma unroll
    for (int ct = 0; ct < 16; ++ct) {
        float bias = (ct < 8) ? b1_nx[ct * 16 + li] : 0.0f;
#pragma unroll
        for (int r = 0; r < 4; ++r) a2[ct][r] = bias;
    }
#pragma unroll
    for (int half = 0; half < 2; ++half) {
#pragma unroll
        for (int chunk = 0; chunk < 2; ++chunk) {
            __syncthreads();
            stage_w64(W1abt_nx + half * 16384, s_w, t, chunk, 64);
            __syncthreads();
#pragma unroll
            for (int kk2 = 0; kk2 < 2; ++kk2) {
                const bf16x8 av = *(const bf16x8*)(s_t1 + rowA * ACT_STRIDE + chunk * 64 + kk2 * 32 + quad * 8);
#pragma unroll
                for (int c = 0; c < 8; ++c) {
                    const bf16x8 bv = *(const bf16x8*)(s_w + (c * 16 + li) * W_STRIDE + kk2 * 32 + quad * 8);
                    a2[half * 8 + c] = __builtin_amdgcn_mfma_f32_16x16x32_bf16(av, bv, a2[half * 8 + c], 0, 0, 0);
                }
            }
        }
    }
#pragma unroll
    for (int ct = 0; ct < 16; ++ct) {
        int col = (ct >> 3) * 128 + (ct & 7) * 16 + li;
#pragma unroll
        for (int r = 0; r < 4; ++r) {
            float v = a2[ct][r];
            float vo = __shfl_xor(v, 1, 64);
            if (!(li & 1))
                *(u32*)(uv + (size_t)(n0 + rowC + r) * 256 + col) = pk2bf(v, vo);
        }
    }
}

extern "C" void kernel_launch(void* const* d_in, const int* in_sizes, int n_in,
                              void* d_out, int out_size, void* d_ws, size_t ws_size,
                              hipStream_t stream) {
    (void)in_sizes; (void)n_in; (void)out_size; (void)ws_size;

    const void* eidx_raw = d_in[0];
    const void* x_raw    = d_in[1];
    const void* pos_raw  = d_in[2];
    const void* embW_raw = d_in[3];
    const void* embB_raw = d_in[4];
    const void* eW1_raw  = d_in[5];
    const void* eB1_raw  = d_in[6];
    const void* eW2_raw  = d_in[7];
    const void* eB2_raw  = d_in[8];
    const void* nW1_raw  = d_in[9];
    const void* nB1_raw  = d_in[10];
    const void* nW2_raw  = d_in[11];
    const void* nB2_raw  = d_in[12];
    const void* pW1_raw  = d_in[13];
    const void* pB1_raw  = d_in[14];
    const void* pW2_raw  = d_in[15];
    const void* pB2_raw  = d_in[16];

    float* ws   = (float*)d_ws;
    float* posf = ws;                            //   120,000
    float* agg  = posf + (size_t)N_NODES * 3;    // 5,120,000
    float* pd   = agg + (size_t)N_NODES * HID;   //   120,000 (contiguous w/ agg)
    float* smallf = pd + (size_t)N_NODES * 3;    //     2,820
    float* embB = smallf;                        // [0,128)
    float* eB1f = smallf + 128;                  // [128,512)
    float* eB2f = smallf + 512;
    float* pB1f = smallf + 896;
    float* pB2f = smallf + 1280;
    float* pW2f = smallf + 1284;
    float* W1r  = smallf + 1668;
    float* nB1f = smallf + 2052;
    float* nB2f = smallf + 2436;

    u16* W1abt = (u16*)(smallf + 2820);          // 98,304
    u16* W2t   = W1abt + 3 * 256 * 128;          // 49,152
    u16* pW1t  = W2t + 3 * 128 * 128;            // 49,152
    u16* nW1t  = pW1t + 3 * 128 * 128;           // 98,304
    u16* nW2t  = nW1t + 3 * 128 * 256;           // 49,152
    u16* embWt = nW2t + 3 * 128 * 128;           //  8,192
    u16* h0    = embWt + 8192;                   // 5,120,000
    u16* h1    = h0 + (size_t)N_NODES * HID;     // 5,120,000
    u16* uvb   = h1 + (size_t)N_NODES * HID;     // 10,240,000
    int* ssrc  = (int*)(uvb + (size_t)N_NODES * 256);
    int* sdst  = ssrc + N_EDGES;
    int* cnt   = sdst + N_EDGES;                 // 40,000
    int* cur   = cnt + N_NODES;                  // 40,000 (contiguous for memset)
    int* offs  = cur + N_NODES;                  // 40,001
    int* flags = offs + N_NODES + 3;
    // total ws ≈ 68.7 MB

    detect_kernel<<<1, 256, 0, stream>>>(embW_raw, eidx_raw, flags);
    small_cvt_kernel<<<12, 256, 0, stream>>>(embB_raw, eB1_raw, eB2_raw, pB1_raw, pB2_raw,
                                             pW2_raw, eW1_raw, nB1_raw, nB2_raw, smallf, flags);
    wcvt_kernel<<<dim3(128, 3, 6), 256, 0, stream>>>(
        eW1_raw, eW2_raw, pW1_raw, nW1_raw, nW2_raw, embW_raw,
        W1abt, W2t, pW1t, nW1t, nW2t, embWt, flags);

    hipMemsetAsync(cnt, 0, 2 * (size_t)N_NODES * sizeof(int), stream);
    cnt_kernel<<<(N_EDGES + 255) / 256, 256, 0, stream>>>(eidx_raw, cnt, flags);
    scan_kernel<<<1, 1024, 0, stream>>>(cnt, offs);
    scatter_kernel<<<(N_EDGES + 255) / 256, 256, 0, stream>>>(eidx_raw, offs, cur, ssrc, sdst, flags);

    posinit_kernel<<<(N_NODES * 3 + 255) / 256, 256, 0, stream>>>(pos_raw, posf, flags);
    hipMemsetAsync(agg, 0, ((size_t)N_NODES * HID + (size_t)N_NODES * 3) * sizeof(float), stream);

    embed_uv_kernel<<<N_NODES / 64, 256, 0, stream>>>(x_raw, embWt, embB, W1abt, eB1f, h0, uvb, flags);

    u16* hin = h0;
    u16* hout = h1;
    for (int l = 0; l < N_LAYERS; ++l) {
        int last = (l == N_LAYERS - 1);
        edge_mfma_kernel<<<N_EDGES / TILE_E, 256, 0, stream>>>(
            ssrc, sdst, uvb, posf,
            W1r + l * HID,
            W2t + (size_t)l * 128 * 128, eB2f + l * HID,
            pW1t + (size_t)l * 128 * 128, pB1f + l * HID,
            pW2f + l * HID, pB2f + l,
            agg, pd);
        node_uv_kernel<<<N_NODES / 64, 256, 0, stream>>>(
            hin, agg,
            nW1t + (size_t)l * 128 * 256, nB1f + l * HID,
            nW2t + (size_t)l * 128 * 128, nB2f + l * HID,
            W1abt + (size_t)(last ? 0 : (l + 1)) * 32768, eB1f + (last ? 0 : (l + 1)) * HID,
            hout, uvb,
            posf, pd, cnt,
            d_out, flags, last ? 1 : 0);
        u16* tmp = hin; hin = hout; hout = tmp;
    }
}

// Round 8
// 782.626 us; speedup vs baseline: 36.1906x; 1.0640x over previous
//
#include <hip/hip_runtime.h>
#include <hip/hip_bf16.h>

#define N_NODES 40000
#define N_EDGES 640000
#define IN_CH 64
#define HID 128
#define N_LAYERS 3

typedef unsigned short u16;
typedef unsigned int u32;

typedef __attribute__((ext_vector_type(8))) __bf16 bf16x8;
typedef __attribute__((ext_vector_type(4))) float float4v;

__device__ __forceinline__ float bf2f(u16 u) {
    union { u32 i; float f; } v; v.i = ((u32)u) << 16; return v.f;
}
__device__ __forceinline__ float bflo(u32 p) {
    union { u32 i; float f; } v; v.i = p << 16; return v.f;
}
__device__ __forceinline__ float bfhi(u32 p) {
    union { u32 i; float f; } v; v.i = p & 0xffff0000u; return v.f;
}
__device__ __forceinline__ u16 f2bf(float f) {
    union { float f; u32 i; } v; v.f = f;
    u32 i = v.i;
    u32 r = (i + 0x7fffu + ((i >> 16) & 1u)) >> 16;
    return (u16)r;
}
#if __has_builtin(__builtin_amdgcn_cvt_pk_bf16_f32)
typedef __attribute__((ext_vector_type(2))) __bf16 bf16x2_t;
__device__ __forceinline__ u32 pk2bf(float a, float b) {
    bf16x2_t p = __builtin_amdgcn_cvt_pk_bf16_f32(a, b);
    union { bf16x2_t v; u32 u; } c; c.v = p; return c.u;
}
#else
__device__ __forceinline__ u32 pk2bf(float a, float b) {
    return (u32)f2bf(a) | ((u32)f2bf(b) << 16);
}
#endif
__device__ __forceinline__ float silu_f(float x) {
    float d = 1.0f + __expf(-x);
#if __has_builtin(__builtin_amdgcn_rcpf)
    return x * __builtin_amdgcn_rcpf(d);
#else
    return __fdividef(x, d);
#endif
}

// ---- LDS weight staging: 128 rows x 64-k chunk ----
#define W_STRIDE 72
__device__ __forceinline__ void stage_w64(const u16* __restrict__ g, u16* s, int t,
                                          int chunk, int rowstride_u32) {
    const u32* gp = (const u32*)g;
    u32* sp = (u32*)s;
#pragma unroll
    for (int it = 0; it < 4; ++it) {
        int i4 = t + it * 256;
        int n = i4 >> 3, j = i4 & 7;
        *(uint4*)(sp + n * 36 + j * 4) = *(const uint4*)(gp + n * rowstride_u32 + chunk * 32 + j * 4);
    }
}

// ---------------- dtype detection ----------------
__global__ void detect_kernel(const void* __restrict__ w_raw,
                              const void* __restrict__ eidx_raw,
                              int* __restrict__ flags) {
    __shared__ int s_big, s_hi;
    if (threadIdx.x == 0) { s_big = 0; s_hi = 0; }
    __syncthreads();
    const u16* w16 = (const u16*)w_raw;
    for (int i = threadIdx.x; i < 8192; i += blockDim.x) {
        float v = bf2f(w16[i]);
        if (!(fabsf(v) <= 1.0f)) s_big = 1;
    }
    const u32* e32 = (const u32*)eidx_raw;
    for (int i = threadIdx.x; i < 256; i += blockDim.x) {
        if (e32[2 * i + 1] != 0u) s_hi = 1;
    }
    __syncthreads();
    if (threadIdx.x == 0) {
        flags[0] = s_big ? 0 : 1;   // 1 => floats are bf16
        flags[1] = s_hi ? 0 : 1;    // 1 => edge_index int64
    }
}

// ---------------- fused small fp32 conversions ----------------
__global__ void small_cvt_kernel(
    const void* __restrict__ embB_raw, const void* __restrict__ eB1_raw,
    const void* __restrict__ eB2_raw, const void* __restrict__ pB1_raw,
    const void* __restrict__ pB2_raw, const void* __restrict__ pW2_raw,
    const void* __restrict__ eW1_raw, const void* __restrict__ nB1_raw,
    const void* __restrict__ nB2_raw,
    float* __restrict__ dstf, const int* __restrict__ flags)
{
    int i = blockIdx.x * blockDim.x + threadIdx.x;
    if (i >= 2820) return;
    const void* src; int si;
    if (i < 128)       { src = embB_raw; si = i; }
    else if (i < 512)  { src = eB1_raw;  si = i - 128; }
    else if (i < 896)  { src = eB2_raw;  si = i - 512; }
    else if (i < 1280) { src = pB1_raw;  si = i - 896; }
    else if (i < 1284) { src = pB2_raw;  si = i - 1280; if (si >= 3) { dstf[i] = 0.f; return; } }
    else if (i < 1668) { src = pW2_raw;  si = i - 1284; }
    else if (i < 2052) { int j = i - 1668; src = eW1_raw; si = (j >> 7) * 32896 + 32768 + (j & 127); }
    else if (i < 2436) { src = nB1_raw;  si = i - 2052; }
    else               { src = nB2_raw;  si = i - 2436; }
    dstf[i] = flags[0] ? bf2f(((const u16*)src)[si]) : ((const float*)src)[si];
}

// ---------------- fused weight transpose+cvt to bf16 [n][k] ----------------
__global__ void wcvt_kernel(
    const void* __restrict__ eW1_raw, const void* __restrict__ eW2_raw,
    const void* __restrict__ pW1_raw, const void* __restrict__ nW1_raw,
    const void* __restrict__ nW2_raw, const void* __restrict__ embW_raw,
    u16* __restrict__ W1abt, u16* __restrict__ W2t, u16* __restrict__ pW1t,
    u16* __restrict__ nW1t, u16* __restrict__ nW2t, u16* __restrict__ embWt,
    const int* __restrict__ flags)
{
    int z = blockIdx.z, l = blockIdx.y;
    int i = blockIdx.x * blockDim.x + threadIdx.x;
    const void* src; u16* dst; int si, di;
    if (z == 0) {           // edge W1 [257][128] -> [o<128: h_i | o>=128: h_j][k]
        if (i >= 32768) return;
        int o = i >> 7, k = i & 127;
        si = l * 32896 + ((o < 128) ? (k * 128 + o) : ((128 + k) * 128 + (o - 128)));
        src = eW1_raw; dst = W1abt; di = l * 32768 + i;
    } else if (z == 1) {
        if (i >= 16384) return;
        int n = i >> 7, k = i & 127;
        si = l * 16384 + k * 128 + n; src = eW2_raw; dst = W2t; di = l * 16384 + i;
    } else if (z == 2) {
        if (i >= 16384) return;
        int n = i >> 7, k = i & 127;
        si = l * 16384 + k * 128 + n; src = pW1_raw; dst = pW1t; di = l * 16384 + i;
    } else if (z == 3) {
        if (i >= 32768) return;
        int n = i >> 8, k = i & 255;
        si = l * 32768 + k * 128 + n; src = nW1_raw; dst = nW1t; di = l * 32768 + i;
    } else if (z == 4) {
        if (i >= 16384) return;
        int n = i >> 7, k = i & 127;
        si = l * 16384 + k * 128 + n; src = nW2_raw; dst = nW2t; di = l * 16384 + i;
    } else {                // emb W [64][128] -> [128][64]
        if (l != 0 || i >= 8192) return;
        int n = i >> 6, k = i & 63;
        si = k * 128 + n; src = embW_raw; dst = embWt; di = i;
    }
    float v = flags[0] ? bf2f(((const u16*)src)[si]) : ((const float*)src)[si];
    dst[di] = f2bf(v);
}

// ---------------- counting sort by dst (reads raw edge_index) ----------------
__global__ void cnt_kernel(const void* __restrict__ eidx, int* __restrict__ cnt,
                           const int* __restrict__ flags) {
    int e = blockIdx.x * blockDim.x + threadIdx.x;
    if (e >= N_EDGES) return;
    int dn = flags[1] ? (int)((const long long*)eidx)[N_EDGES + e]
                      : ((const int*)eidx)[N_EDGES + e];
    atomicAdd(&cnt[dn], 1);
}

__global__ __launch_bounds__(1024) void scan_kernel(const int* __restrict__ cnt,
                                                    int* __restrict__ offs) {
    __shared__ int s_part[1024];
    const int t = threadIdx.x;
    const int base = t * 40;
    int sum = 0;
    for (int j = 0; j < 40; ++j) {
        int idx = base + j;
        sum += (idx < N_NODES) ? cnt[idx] : 0;
    }
    s_part[t] = sum;
    __syncthreads();
    for (int d = 1; d < 1024; d <<= 1) {
        int v = (t >= d) ? s_part[t - d] : 0;
        __syncthreads();
        s_part[t] += v;
        __syncthreads();
    }
    int run = (t == 0) ? 0 : s_part[t - 1];
    for (int j = 0; j < 40; ++j) {
        int idx = base + j;
        if (idx < N_NODES) { offs[idx] = run; run += cnt[idx]; }
    }
    if (t == 1023) offs[N_NODES] = run;
}

__global__ void scatter_kernel(const void* __restrict__ eidx,
                               const int* __restrict__ offs, int* __restrict__ cur,
                               int* __restrict__ ssrc, int* __restrict__ sdst,
                               const int* __restrict__ flags) {
    int e = blockIdx.x * blockDim.x + threadIdx.x;
    if (e >= N_EDGES) return;
    int sn, dn;
    if (flags[1]) {
        sn = (int)((const long long*)eidx)[e];
        dn = (int)((const long long*)eidx)[N_EDGES + e];
    } else {
        sn = ((const int*)eidx)[e];
        dn = ((const int*)eidx)[N_EDGES + e];
    }
    int p = offs[dn] + atomicAdd(&cur[dn], 1);
    ssrc[p] = sn;
    sdst[p] = dn;
}

// ---------------- pos init -> f32 ----------------
__global__ void posinit_kernel(const void* __restrict__ pos_raw, float* __restrict__ posf,
                               const int* __restrict__ flags) {
    int i = blockIdx.x * blockDim.x + threadIdx.x;
    if (i < N_NODES * 3)
        posf[i] = flags[0] ? bf2f(((const u16*)pos_raw)[i]) : ((const float*)pos_raw)[i];
}

#define ACT_STRIDE 136

// ================= fused embed + uv(layer0) =================
__global__ __launch_bounds__(256, 3) void embed_uv_kernel(
    const void* __restrict__ x_raw, const u16* __restrict__ embWt, const float* __restrict__ embB,
    const u16* __restrict__ W1abt, const float* __restrict__ b1,
    u16* __restrict__ h, u16* __restrict__ uv, const int* __restrict__ flags)
{
    __shared__ __align__(16) u16 s_x[64 * 72];
    __shared__ __align__(16) u16 s_h[64 * ACT_STRIDE];
    __shared__ __align__(16) u16 s_w[128 * W_STRIDE];

    const int t = threadIdx.x;
    const int n0 = blockIdx.x * 64;
    const int wv = t >> 6, lane = t & 63, quad = lane >> 4, li = lane & 15;
    const int rowA = wv * 16 + li;
    const int rowC = wv * 16 + quad * 4;

    {   // load x rows -> bf16 LDS
        int el = t >> 2, pt4 = t & 3;
        u32* op = (u32*)s_x + el * 36 + pt4 * 8;
        if (flags[0]) {
            const u32* xp = (const u32*)x_raw + (size_t)(n0 + el) * 32 + pt4 * 8;
            *(uint4*)(op)     = *(const uint4*)(xp);
            *(uint4*)(op + 4) = *(const uint4*)(xp + 4);
        } else {
            const float* xp = (const float*)x_raw + (size_t)(n0 + el) * 64 + pt4 * 16;
#pragma unroll
            for (int j = 0; j < 8; ++j) op[j] = pk2bf(xp[2 * j], xp[2 * j + 1]);
        }
    }
    stage_w64(embWt, s_w, t, 0, 32);
    __syncthreads();

    // h = x @ embW + b  (K=64)
    float4v acc[8];
#pragma unroll
    for (int c = 0; c < 8; ++c) {
        float bias = embB[c * 16 + li];
#pragma unroll
        for (int r = 0; r < 4; ++r) acc[c][r] = bias;
    }
#pragma unroll
    for (int kk2 = 0; kk2 < 2; ++kk2) {
        const bf16x8 av = *(const bf16x8*)(s_x + rowA * 72 + kk2 * 32 + quad * 8);
#pragma unroll
        for (int c = 0; c < 8; ++c) {
            const bf16x8 bv = *(const bf16x8*)(s_w + (c * 16 + li) * W_STRIDE + kk2 * 32 + quad * 8);
            acc[c] = __builtin_amdgcn_mfma_f32_16x16x32_bf16(av, bv, acc[c], 0, 0, 0);
        }
    }
    // write h (global + LDS), pair stores
#pragma unroll
    for (int c = 0; c < 8; ++c) {
        int col = c * 16 + li;
#pragma unroll
        for (int r = 0; r < 4; ++r) {
            float v = acc[c][r];
            float vo = __shfl_xor(v, 1, 64);
            if (!(li & 1)) {
                u32 pkd = pk2bf(v, vo);
                *(u32*)(s_h + (rowC + r) * ACT_STRIDE + col) = pkd;
                *(u32*)(h + (size_t)(n0 + rowC + r) * HID + col) = pkd;
            }
        }
    }

    // uv = [h@W1a + b1 | h@W1b]
    float4v a2[16];
#pragma unroll
    for (int ct = 0; ct < 16; ++ct) {
        float bias = (ct < 8) ? b1[ct * 16 + li] : 0.0f;
#pragma unroll
        for (int r = 0; r < 4; ++r) a2[ct][r] = bias;
    }
#pragma unroll
    for (int half = 0; half < 2; ++half) {
#pragma unroll
        for (int chunk = 0; chunk < 2; ++chunk) {
            __syncthreads();
            stage_w64(W1abt + half * 16384, s_w, t, chunk, 64);
            __syncthreads();
#pragma unroll
            for (int kk2 = 0; kk2 < 2; ++kk2) {
                const bf16x8 av = *(const bf16x8*)(s_h + rowA * ACT_STRIDE + chunk * 64 + kk2 * 32 + quad * 8);
#pragma unroll
                for (int c = 0; c < 8; ++c) {
                    const bf16x8 bv = *(const bf16x8*)(s_w + (c * 16 + li) * W_STRIDE + kk2 * 32 + quad * 8);
                    a2[half * 8 + c] = __builtin_amdgcn_mfma_f32_16x16x32_bf16(av, bv, a2[half * 8 + c], 0, 0, 0);
                }
            }
        }
    }
#pragma unroll
    for (int ct = 0; ct < 16; ++ct) {
        int col = (ct >> 3) * 128 + (ct & 7) * 16 + li;
#pragma unroll
        for (int r = 0; r < 4; ++r) {
            float v = a2[ct][r];
            float vo = __shfl_xor(v, 1, 64);
            if (!(li & 1))
                *(u32*)(uv + (size_t)(n0 + rowC + r) * 256 + col) = pk2bf(v, vo);
        }
    }
}

// ================= edge kernel =================
#define TILE_E 64

__global__ __launch_bounds__(256, 4) void edge_mfma_kernel(
    const int* __restrict__ ssrc, const int* __restrict__ sdst,
    const u16* __restrict__ uv, const float* __restrict__ posf,
    const float* __restrict__ w1c_g,
    const u16* __restrict__ W2t, const float* __restrict__ b2,
    const u16* __restrict__ pW1t, const float* __restrict__ pb1,
    const float* __restrict__ pW2, const float* __restrict__ pb2,
    float* __restrict__ agg, float* __restrict__ pd)
{
    __shared__ __align__(16) u16 s_act[TILE_E * ACT_STRIDE];
    __shared__ __align__(16) u16 s_w[128 * W_STRIDE];
    __shared__ float s_w1c[128];
    __shared__ float s_d2[TILE_E];
    __shared__ float s_rel[TILE_E * 3];
    __shared__ int s_dstn[TILE_E];

    const int t = threadIdx.x;
    const int e0 = blockIdx.x * TILE_E;
    const int wv = t >> 6, lane = t & 63, quad = lane >> 4, li = lane & 15;
    const int rowA = wv * 16 + li;
    const int rowC = wv * 16 + quad * 4;

    // ---- hoisted uv gather: issue loads before any barrier ----
    {
        const int el = t >> 2, pt4 = t & 3;
        int eg = e0 + el;
        int dNg = sdst[eg], sNg = ssrc[eg];
        const uint4* up = (const uint4*)((const u32*)uv + (size_t)dNg * 128 + pt4 * 16);
        const uint4* vp = (const uint4*)((const u32*)uv + (size_t)sNg * 128 + 64 + pt4 * 16);
        uint4 uu[4], vv[4];
#pragma unroll
        for (int q4 = 0; q4 < 4; ++q4) { uu[q4] = up[q4]; vv[q4] = vp[q4]; }

        // ---- meta phase (overlaps the loads above) ----
        if (t < TILE_E) {
            int e = e0 + t;
            int sN = ssrc[e], dN = sdst[e];
            s_dstn[t] = dN;
            float r0 = posf[dN * 3 + 0] - posf[sN * 3 + 0];
            float r1 = posf[dN * 3 + 1] - posf[sN * 3 + 1];
            float r2 = posf[dN * 3 + 2] - posf[sN * 3 + 2];
            s_rel[t * 3 + 0] = r0; s_rel[t * 3 + 1] = r1; s_rel[t * 3 + 2] = r2;
            s_d2[t] = r0 * r0 + r1 * r1 + r2 * r2;
        }
        if (t < 128) s_w1c[t] = w1c_g[t];
        stage_w64(W2t, s_w, t, 0, 64);
        __syncthreads();

        // ---- t1 = silu(u[dst] + v[src] + d2*w1c) ----
        float d2 = s_d2[el];
        u32* outp = (u32*)s_act + el * (ACT_STRIDE / 2) + pt4 * 16;
        const float* wc = s_w1c + pt4 * 32;
#pragma unroll
        for (int q4 = 0; q4 < 4; ++q4) {
            u32 res[4];
#pragma unroll
            for (int j = 0; j < 4; ++j) {
                u32 ua = ((const u32*)&uu[q4])[j], va = ((const u32*)&vv[q4])[j];
                int col = q4 * 8 + j * 2;
                float x0 = fmaf(d2, wc[col],     bflo(ua) + bflo(va));
                float x1 = fmaf(d2, wc[col + 1], bfhi(ua) + bfhi(va));
                res[j] = pk2bf(silu_f(x0), silu_f(x1));
            }
            *(uint4*)(outp + q4 * 4) = *(uint4*)res;
        }
    }
    __syncthreads();

    // m_pre = t1 @ W2 + b2
    float4v acc[8];
#pragma unroll
    for (int c = 0; c < 8; ++c) {
        float bias = b2[c * 16 + li];
#pragma unroll
        for (int r = 0; r < 4; ++r) acc[c][r] = bias;
    }
#pragma unroll
    for (int p = 0; p < 2; ++p) {
        if (p) {
            __syncthreads();
            stage_w64(W2t, s_w, t, 1, 64);
            __syncthreads();
        }
#pragma unroll
        for (int kk2 = 0; kk2 < 2; ++kk2) {
            const bf16x8 av = *(const bf16x8*)(s_act + rowA * ACT_STRIDE + p * 64 + kk2 * 32 + quad * 8);
#pragma unroll
            for (int c = 0; c < 8; ++c) {
                const bf16x8 bv = *(const bf16x8*)(s_w + (c * 16 + li) * W_STRIDE + kk2 * 32 + quad * 8);
                acc[c] = __builtin_amdgcn_mfma_f32_16x16x32_bf16(av, bv, acc[c], 0, 0, 0);
            }
        }
    }
    __syncthreads();

    // m -> s_act (scalar LDS stores: pair-store via shfl REGRESSED here, r6 postmortem)
#pragma unroll
    for (int c = 0; c < 8; ++c) {
        int col = c * 16 + li;
#pragma unroll
        for (int r = 0; r < 4; ++r)
            s_act[(rowC + r) * ACT_STRIDE + col] = f2bf(silu_f(acc[c][r]));
    }
    stage_w64(pW1t, s_w, t, 0, 64);
    __syncthreads();

    // agg segmented reduction
    {
        int c32 = t & 63, grp = t >> 6;
        int r0 = grp * 16;
        float run0 = 0.f, run1 = 0.f;
        int cur = s_dstn[r0];
        for (int r = r0; r < r0 + 16; ++r) {
            int dn = s_dstn[r];
            if (dn != cur) {
                atomicAdd(&agg[(size_t)cur * HID + 2 * c32], run0);
                atomicAdd(&agg[(size_t)cur * HID + 2 * c32 + 1], run1);
                run0 = run1 = 0.f; cur = dn;
            }
            u32 mm = *((const u32*)s_act + r * (ACT_STRIDE / 2) + c32);
            run0 += bflo(mm);
            run1 += bfhi(mm);
        }
        atomicAdd(&agg[(size_t)cur * HID + 2 * c32], run0);
        atomicAdd(&agg[(size_t)cur * HID + 2 * c32 + 1], run1);
    }

    // pos MLP
#pragma unroll
    for (int c = 0; c < 8; ++c) {
        float bias = pb1[c * 16 + li];
#pragma unroll
        for (int r = 0; r < 4; ++r) acc[c][r] = bias;
    }
#pragma unroll
    for (int p = 0; p < 2; ++p) {
        if (p) {
            __syncthreads();
            stage_w64(pW1t, s_w, t, 1, 64);
            __syncthreads();
        }
#pragma unroll
        for (int kk2 = 0; kk2 < 2; ++kk2) {
            const bf16x8 av = *(const bf16x8*)(s_act + rowA * ACT_STRIDE + p * 64 + kk2 * 32 + quad * 8);
#pragma unroll
            for (int c = 0; c < 8; ++c) {
                const bf16x8 bv = *(const bf16x8*)(s_w + (c * 16 + li) * W_STRIDE + kk2 * 32 + quad * 8);
                acc[c] = __builtin_amdgcn_mfma_f32_16x16x32_bf16(av, bv, acc[c], 0, 0, 0);
            }
        }
    }
    float part[4] = {0.f, 0.f, 0.f, 0.f};
#pragma unroll
    for (int c = 0; c < 8; ++c) {
        float pw = pW2[c * 16 + li];
#pragma unroll
        for (int r = 0; r < 4; ++r) part[r] += silu_f(acc[c][r]) * pw;
    }
#pragma unroll
    for (int r = 0; r < 4; ++r) {
        part[r] += __shfl_xor(part[r], 1, 64);
        part[r] += __shfl_xor(part[r], 2, 64);
        part[r] += __shfl_xor(part[r], 4, 64);
        part[r] += __shfl_xor(part[r], 8, 64);
    }
    __syncthreads();
    if (li == 0) {
        float pb2v = pb2[0];
#pragma unroll
        for (int r = 0; r < 4; ++r) s_d2[rowC + r] = part[r] + pb2v;
    }
    __syncthreads();
    if (t < 12) {
        int a = t % 3, grp = t / 3;
        int r0 = grp * 16;
        float run = 0.f;
        int cur = s_dstn[r0];
        for (int r = r0; r < r0 + 16; ++r) {
            int dn = s_dstn[r];
            if (dn != cur) {
                atomicAdd(&pd[(size_t)cur * 3 + a], run);
                run = 0.f; cur = dn;
            }
            run += s_rel[r * 3 + a] * s_d2[r];
        }
        atomicAdd(&pd[(size_t)cur * 3 + a], run);
    }
}

// ================= fused node MLP + uv(next layer) + output =================
#define A_STRIDE 264

__global__ __launch_bounds__(256, 3) void node_uv_kernel(
    const u16* __restrict__ h_in, float* __restrict__ agg,
    const u16* __restrict__ W1t, const float* __restrict__ b1,
    const u16* __restrict__ W2t, const float* __restrict__ b2,
    const u16* __restrict__ W1abt_nx, const float* __restrict__ b1_nx,
    u16* __restrict__ h_out, u16* __restrict__ uv,
    float* __restrict__ posf, float* __restrict__ pd, const int* __restrict__ cnt,
    void* __restrict__ outp, const int* __restrict__ flags, int do_out)
{
    __shared__ __align__(16) u16 s_a[64 * A_STRIDE];
    __shared__ __align__(16) u16 s_w[128 * W_STRIDE];

    const int t = threadIdx.x;
    const int n0 = blockIdx.x * 64;
    const int wv = t >> 6, lane = t & 63, quad = lane >> 4, li = lane & 15;
    const int rowA = wv * 16 + li;
    const int rowC = wv * 16 + quad * 4;

    {   // A = [h | bf16(agg)]; zero agg after read
        int nl = t >> 2, pt4 = t & 3;
        const uint4* hp = (const uint4*)((const u32*)h_in + (size_t)(n0 + nl) * 64 + pt4 * 16);
        u32* rowp = (u32*)s_a + nl * (A_STRIDE / 2) + pt4 * 16;
#pragma unroll
        for (int j = 0; j < 4; ++j) *(uint4*)(rowp + j * 4) = hp[j];
        float* ap = agg + (size_t)(n0 + nl) * HID + pt4 * 32;
        rowp += 64;
#pragma unroll
        for (int j = 0; j < 16; ++j) {
            float2 v = *(const float2*)(ap + j * 2);
            rowp[j] = pk2bf(v.x, v.y);
        }
        float4 z = {0.f, 0.f, 0.f, 0.f};
#pragma unroll
        for (int j = 0; j < 8; ++j) *(float4*)(ap + j * 4) = z;
    }
    stage_w64(W1t, s_w, t, 0, 128);
    __syncthreads();

    float4v acc[8];
#pragma unroll
    for (int c = 0; c < 8; ++c) {
        float bias = b1[c * 16 + li];
#pragma unroll
        for (int r = 0; r < 4; ++r) acc[c][r] = bias;
    }
#pragma unroll
    for (int p = 0; p < 4; ++p) {
        if (p) {
            __syncthreads();
            stage_w64(W1t, s_w, t, p, 128);
            __syncthreads();
        }
#pragma unroll
        for (int kk2 = 0; kk2 < 2; ++kk2) {
            const bf16x8 av = *(const bf16x8*)(s_a + rowA * A_STRIDE + p * 64 + kk2 * 32 + quad * 8);
#pragma unroll
            for (int c = 0; c < 8; ++c) {
                const bf16x8 bv = *(const bf16x8*)(s_w + (c * 16 + li) * W_STRIDE + kk2 * 32 + quad * 8);
                acc[c] = __builtin_amdgcn_mfma_f32_16x16x32_bf16(av, bv, acc[c], 0, 0, 0);
            }
        }
    }

    __syncthreads();
    u16* s_t1 = s_a;   // overlay
#pragma unroll
    for (int c = 0; c < 8; ++c) {
        int col = c * 16 + li;
#pragma unroll
        for (int r = 0; r < 4; ++r) {
            float v = silu_f(acc[c][r]);
            float vo = __shfl_xor(v, 1, 64);
            if (!(li & 1))
                *(u32*)(s_t1 + (rowC + r) * ACT_STRIDE + col) = pk2bf(v, vo);
        }
    }
    stage_w64(W2t, s_w, t, 0, 64);
    __syncthreads();

#pragma unroll
    for (int c = 0; c < 8; ++c) {
        float bias = b2[c * 16 + li];
#pragma unroll
        for (int r = 0; r < 4; ++r) acc[c][r] = bias;
    }
#pragma unroll
    for (int p = 0; p < 2; ++p) {
        if (p) {
            __syncthreads();
            stage_w64(W2t, s_w, t, 1, 64);
            __syncthreads();
        }
#pragma unroll
        for (int kk2 = 0; kk2 < 2; ++kk2) {
            const bf16x8 av = *(const bf16x8*)(s_t1 + rowA * ACT_STRIDE + p * 64 + kk2 * 32 + quad * 8);
#pragma unroll
            for (int c = 0; c < 8; ++c) {
                const bf16x8 bv = *(const bf16x8*)(s_w + (c * 16 + li) * W_STRIDE + kk2 * 32 + quad * 8);
                acc[c] = __builtin_amdgcn_mfma_f32_16x16x32_bf16(av, bv, acc[c], 0, 0, 0);
            }
        }
    }

    // epilogue: h
    if (do_out) {
        if (flags[0]) {
#pragma unroll
            for (int c = 0; c < 8; ++c) {
                int col = c * 16 + li;
#pragma unroll
                for (int r = 0; r < 4; ++r) {
                    float v = acc[c][r];
                    float vo = __shfl_xor(v, 1, 64);
                    if (!(li & 1))
                        *(u32*)((u16*)outp + (size_t)(n0 + rowC + r) * HID + col) = pk2bf(v, vo);
                }
            }
        } else {
#pragma unroll
            for (int c = 0; c < 8; ++c) {
                int col = c * 16 + li;
#pragma unroll
                for (int r = 0; r < 4; ++r)
                    ((float*)outp)[(size_t)(n0 + rowC + r) * HID + col] = acc[c][r];
            }
        }
    } else {
#pragma unroll
        for (int c = 0; c < 8; ++c) {
            int col = c * 16 + li;
#pragma unroll
            for (int r = 0; r < 4; ++r) {
                float v = acc[c][r];
                float vo = __shfl_xor(v, 1, 64);
                if (!(li & 1)) {
                    u32 pkd = pk2bf(v, vo);
                    *(u32*)(s_t1 + (rowC + r) * ACT_STRIDE + col) = pkd;
                    *(u32*)(h_out + (size_t)(n0 + rowC + r) * HID + col) = pkd;
                }
            }
        }
    }

    // pos update + pd zero (+ pos out)
    if (t < 192) {
        int nl = t / 3, a = t % 3;
        int n = n0 + nl;
        float dg = (float)cnt[n];
        dg = dg < 1.0f ? 1.0f : dg;
        float np = posf[n * 3 + a] + pd[n * 3 + a] / dg;
        posf[n * 3 + a] = np;
        pd[n * 3 + a] = 0.f;
        if (do_out) {
            if (flags[0]) ((u16*)outp)[(size_t)N_NODES * HID + n * 3 + a] = f2bf(np);
            else          ((float*)outp)[(size_t)N_NODES * HID + n * 3 + a] = np;
        }
    }

    if (do_out) return;

    // uv for next layer
    float4v a2[16];
#pragma unroll
    for (int ct = 0; ct < 16; ++ct) {
        float bias = (ct < 8) ? b1_nx[ct * 16 + li] : 0.0f;
#pragma unroll
        for (int r = 0; r < 4; ++r) a2[ct][r] = bias;
    }
#pragma unroll
    for (int half = 0; half < 2; ++half) {
#pragma unroll
        for (int chunk = 0; chunk < 2; ++chunk) {
            __syncthreads();
            stage_w64(W1abt_nx + half * 16384, s_w, t, chunk, 64);
            __syncthreads();
#pragma unroll
            for (int kk2 = 0; kk2 < 2; ++kk2) {
                const bf16x8 av = *(const bf16x8*)(s_t1 + rowA * ACT_STRIDE + chunk * 64 + kk2 * 32 + quad * 8);
#pragma unroll
                for (int c = 0; c < 8; ++c) {
                    const bf16x8 bv = *(const bf16x8*)(s_w + (c * 16 + li) * W_STRIDE + kk2 * 32 + quad * 8);
                    a2[half * 8 + c] = __builtin_amdgcn_mfma_f32_16x16x32_bf16(av, bv, a2[half * 8 + c], 0, 0, 0);
                }
            }
        }
    }
#pragma unroll
    for (int ct = 0; ct < 16; ++ct) {
        int col = (ct >> 3) * 128 + (ct & 7) * 16 + li;
#pragma unroll
        for (int r = 0; r < 4; ++r) {
            float v = a2[ct][r];
            float vo = __shfl_xor(v, 1, 64);
            if (!(li & 1))
                *(u32*)(uv + (size_t)(n0 + rowC + r) * 256 + col) = pk2bf(v, vo);
        }
    }
}

extern "C" void kernel_launch(void* const* d_in, const int* in_sizes, int n_in,
                              void* d_out, int out_size, void* d_ws, size_t ws_size,
                              hipStream_t stream) {
    (void)in_sizes; (void)n_in; (void)out_size; (void)ws_size;

    const void* eidx_raw = d_in[0];
    const void* x_raw    = d_in[1];
    const void* pos_raw  = d_in[2];
    const void* embW_raw = d_in[3];
    const void* embB_raw = d_in[4];
    const void* eW1_raw  = d_in[5];
    const void* eB1_raw  = d_in[6];
    const void* eW2_raw  = d_in[7];
    const void* eB2_raw  = d_in[8];
    const void* nW1_raw  = d_in[9];
    const void* nB1_raw  = d_in[10];
    const void* nW2_raw  = d_in[11];
    const void* nB2_raw  = d_in[12];
    const void* pW1_raw  = d_in[13];
    const void* pB1_raw  = d_in[14];
    const void* pW2_raw  = d_in[15];
    const void* pB2_raw  = d_in[16];

    float* ws   = (float*)d_ws;
    float* posf = ws;                            //   120,000
    float* agg  = posf + (size_t)N_NODES * 3;    // 5,120,000
    float* pd   = agg + (size_t)N_NODES * HID;   //   120,000 (contiguous w/ agg)
    float* smallf = pd + (size_t)N_NODES * 3;    //     2,820
    float* embB = smallf;                        // [0,128)
    float* eB1f = smallf + 128;                  // [128,512)
    float* eB2f = smallf + 512;
    float* pB1f = smallf + 896;
    float* pB2f = smallf + 1280;
    float* pW2f = smallf + 1284;
    float* W1r  = smallf + 1668;
    float* nB1f = smallf + 2052;
    float* nB2f = smallf + 2436;

    u16* W1abt = (u16*)(smallf + 2820);          // 98,304
    u16* W2t   = W1abt + 3 * 256 * 128;          // 49,152
    u16* pW1t  = W2t + 3 * 128 * 128;            // 49,152
    u16* nW1t  = pW1t + 3 * 128 * 128;           // 98,304
    u16* nW2t  = nW1t + 3 * 128 * 256;           // 49,152
    u16* embWt = nW2t + 3 * 128 * 128;           //  8,192
    u16* h0    = embWt + 8192;                   // 5,120,000
    u16* h1    = h0 + (size_t)N_NODES * HID;     // 5,120,000
    u16* uvb   = h1 + (size_t)N_NODES * HID;     // 10,240,000
    int* ssrc  = (int*)(uvb + (size_t)N_NODES * 256);
    int* sdst  = ssrc + N_EDGES;
    int* cnt   = sdst + N_EDGES;                 // 40,000
    int* cur   = cnt + N_NODES;                  // 40,000 (contiguous for memset)
    int* offs  = cur + N_NODES;                  // 40,001
    int* flags = offs + N_NODES + 3;
    // total ws ≈ 68.7 MB

    detect_kernel<<<1, 256, 0, stream>>>(embW_raw, eidx_raw, flags);
    small_cvt_kernel<<<12, 256, 0, stream>>>(embB_raw, eB1_raw, eB2_raw, pB1_raw, pB2_raw,
                                             pW2_raw, eW1_raw, nB1_raw, nB2_raw, smallf, flags);
    wcvt_kernel<<<dim3(128, 3, 6), 256, 0, stream>>>(
        eW1_raw, eW2_raw, pW1_raw, nW1_raw, nW2_raw, embW_raw,
        W1abt, W2t, pW1t, nW1t, nW2t, embWt, flags);

    hipMemsetAsync(cnt, 0, 2 * (size_t)N_NODES * sizeof(int), stream);
    cnt_kernel<<<(N_EDGES + 255) / 256, 256, 0, stream>>>(eidx_raw, cnt, flags);
    scan_kernel<<<1, 1024, 0, stream>>>(cnt, offs);
    scatter_kernel<<<(N_EDGES + 255) / 256, 256, 0, stream>>>(eidx_raw, offs, cur, ssrc, sdst, flags);

    posinit_kernel<<<(N_NODES * 3 + 255) / 256, 256, 0, stream>>>(pos_raw, posf, flags);
    hipMemsetAsync(agg, 0, ((size_t)N_NODES * HID + (size_t)N_NODES * 3) * sizeof(float), stream);

    embed_uv_kernel<<<N_NODES / 64, 256, 0, stream>>>(x_raw, embWt, embB, W1abt, eB1f, h0, uvb, flags);

    u16* hin = h0;
    u16* hout = h1;
    for (int l = 0; l < N_LAYERS; ++l) {
        int last = (l == N_LAYERS - 1);
        edge_mfma_kernel<<<N_EDGES / TILE_E, 256, 0, stream>>>(
            ssrc, sdst, uvb, posf,
            W1r + l * HID,
            W2t + (size_t)l * 128 * 128, eB2f + l * HID,
            pW1t + (size_t)l * 128 * 128, pB1f + l * HID,
            pW2f + l * HID, pB2f + l,
            agg, pd);
        node_uv_kernel<<<N_NODES / 64, 256, 0, stream>>>(
            hin, agg,
            nW1t + (size_t)l * 128 * 256, nB1f + l * HID,
            nW2t + (size_t)l * 128 * 128, nB2f + l * HID,
            W1abt + (size_t)(last ? 0 : (l + 1)) * 32768, eB1f + (last ? 0 : (l + 1)) * HID,
            hout, uvb,
            posf, pd, cnt,
            d_out, flags, last ? 1 : 0);
        u16* tmp = hin; hin = hout; hout = tmp;
    }
}

// Round 9
// 768.665 us; speedup vs baseline: 36.8479x; 1.0182x over previous
//
#include <hip/hip_runtime.h>
#include <hip/hip_bf16.h>

#define N_NODES 40000
#define N_EDGES 640000
#define IN_CH 64
#define HID 128
#define N_LAYERS 3

typedef unsigned short u16;
typedef unsigned int u32;

typedef __attribute__((ext_vector_type(8))) __bf16 bf16x8;
typedef __attribute__((ext_vector_type(4))) float float4v;

__device__ __forceinline__ float bf2f(u16 u) {
    union { u32 i; float f; } v; v.i = ((u32)u) << 16; return v.f;
}
__device__ __forceinline__ float bflo(u32 p) {
    union { u32 i; float f; } v; v.i = p << 16; return v.f;
}
__device__ __forceinline__ float bfhi(u32 p) {
    union { u32 i; float f; } v; v.i = p & 0xffff0000u; return v.f;
}
__device__ __forceinline__ u16 f2bf(float f) {
    union { float f; u32 i; } v; v.f = f;
    u32 i = v.i;
    u32 r = (i + 0x7fffu + ((i >> 16) & 1u)) >> 16;
    return (u16)r;
}
#if __has_builtin(__builtin_amdgcn_cvt_pk_bf16_f32)
typedef __attribute__((ext_vector_type(2))) __bf16 bf16x2_t;
__device__ __forceinline__ u32 pk2bf(float a, float b) {
    bf16x2_t p = __builtin_amdgcn_cvt_pk_bf16_f32(a, b);
    union { bf16x2_t v; u32 u; } c; c.v = p; return c.u;
}
#else
__device__ __forceinline__ u32 pk2bf(float a, float b) {
    return (u32)f2bf(a) | ((u32)f2bf(b) << 16);
}
#endif
__device__ __forceinline__ float silu_f(float x) {
    float d = 1.0f + __expf(-x);
#if __has_builtin(__builtin_amdgcn_rcpf)
    return x * __builtin_amdgcn_rcpf(d);
#else
    return __fdividef(x, d);
#endif
}

// ---- LDS weight staging: 128 rows x 64-k chunk ----
#define W_STRIDE 72
__device__ __forceinline__ void stage_w64(const u16* __restrict__ g, u16* s, int t,
                                          int chunk, int rowstride_u32) {
    const u32* gp = (const u32*)g;
    u32* sp = (u32*)s;
#pragma unroll
    for (int it = 0; it < 4; ++it) {
        int i4 = t + it * 256;
        int n = i4 >> 3, j = i4 & 7;
        *(uint4*)(sp + n * 36 + j * 4) = *(const uint4*)(gp + n * rowstride_u32 + chunk * 32 + j * 4);
    }
}

// B-row permutation: storage row r holds canonical output channel (r&15)*8 + (r>>4),
// so MFMA lane li's 8 C-tiles land on canonical cols li*8..li*8+7 (contiguous stores).
__device__ __forceinline__ int permch(int r) { return ((r & 15) << 3) | (r >> 4); }

// ---------------- dtype detection ----------------
__global__ void detect_kernel(const void* __restrict__ w_raw,
                              const void* __restrict__ eidx_raw,
                              int* __restrict__ flags) {
    __shared__ int s_big, s_hi;
    if (threadIdx.x == 0) { s_big = 0; s_hi = 0; }
    __syncthreads();
    const u16* w16 = (const u16*)w_raw;
    for (int i = threadIdx.x; i < 8192; i += blockDim.x) {
        float v = bf2f(w16[i]);
        if (!(fabsf(v) <= 1.0f)) s_big = 1;
    }
    const u32* e32 = (const u32*)eidx_raw;
    for (int i = threadIdx.x; i < 256; i += blockDim.x) {
        if (e32[2 * i + 1] != 0u) s_hi = 1;
    }
    __syncthreads();
    if (threadIdx.x == 0) {
        flags[0] = s_big ? 0 : 1;   // 1 => floats are bf16
        flags[1] = s_hi ? 0 : 1;    // 1 => edge_index int64
    }
}

// ---------------- fused small fp32 conversions ----------------
__global__ void small_cvt_kernel(
    const void* __restrict__ embB_raw, const void* __restrict__ eB1_raw,
    const void* __restrict__ eB2_raw, const void* __restrict__ pB1_raw,
    const void* __restrict__ pB2_raw, const void* __restrict__ pW2_raw,
    const void* __restrict__ eW1_raw, const void* __restrict__ nB1_raw,
    const void* __restrict__ nB2_raw,
    float* __restrict__ dstf, const int* __restrict__ flags)
{
    int i = blockIdx.x * blockDim.x + threadIdx.x;
    if (i >= 2820) return;
    const void* src; int si;
    if (i < 128)       { src = embB_raw; si = i; }
    else if (i < 512)  { src = eB1_raw;  si = i - 128; }
    else if (i < 896)  { src = eB2_raw;  si = i - 512; }
    else if (i < 1280) { src = pB1_raw;  si = i - 896; }
    else if (i < 1284) { src = pB2_raw;  si = i - 1280; if (si >= 3) { dstf[i] = 0.f; return; } }
    else if (i < 1668) { src = pW2_raw;  si = i - 1284; }
    else if (i < 2052) { int j = i - 1668; src = eW1_raw; si = (j >> 7) * 32896 + 32768 + (j & 127); }
    else if (i < 2436) { src = nB1_raw;  si = i - 2052; }
    else               { src = nB2_raw;  si = i - 2436; }
    dstf[i] = flags[0] ? bf2f(((const u16*)src)[si]) : ((const float*)src)[si];
}

// ---------------- fused weight transpose+cvt to bf16 [n][k] ----------------
// Output-storing matmul weights (W1ab, W2, nW1, nW2, embW) get the B-row
// permutation (permch) so their epilogues store contiguous 16B per lane.
// pW1 stays unpermuted (its output is dot-reduced only).
__global__ void wcvt_kernel(
    const void* __restrict__ eW1_raw, const void* __restrict__ eW2_raw,
    const void* __restrict__ pW1_raw, const void* __restrict__ nW1_raw,
    const void* __restrict__ nW2_raw, const void* __restrict__ embW_raw,
    u16* __restrict__ W1abt, u16* __restrict__ W2t, u16* __restrict__ pW1t,
    u16* __restrict__ nW1t, u16* __restrict__ nW2t, u16* __restrict__ embWt,
    const int* __restrict__ flags)
{
    int z = blockIdx.z, l = blockIdx.y;
    int i = blockIdx.x * blockDim.x + threadIdx.x;
    const void* src; u16* dst; int si, di;
    if (z == 0) {           // edge W1 [257][128] -> rows: [o<128: h_i | o>=128: h_j], permuted
        if (i >= 32768) return;
        int o = i >> 7, k = i & 127;
        int ch = permch(o & 127);
        si = l * 32896 + ((o < 128) ? (k * 128 + ch) : ((128 + k) * 128 + ch));
        src = eW1_raw; dst = W1abt; di = l * 32768 + i;
    } else if (z == 1) {    // edge W2, permuted rows
        if (i >= 16384) return;
        int n = i >> 7, k = i & 127;
        si = l * 16384 + k * 128 + permch(n); src = eW2_raw; dst = W2t; di = l * 16384 + i;
    } else if (z == 2) {    // pos W1, NOT permuted
        if (i >= 16384) return;
        int n = i >> 7, k = i & 127;
        si = l * 16384 + k * 128 + n; src = pW1_raw; dst = pW1t; di = l * 16384 + i;
    } else if (z == 3) {    // node W1, permuted rows
        if (i >= 32768) return;
        int n = i >> 8, k = i & 255;
        si = l * 32768 + k * 128 + permch(n); src = nW1_raw; dst = nW1t; di = l * 32768 + i;
    } else if (z == 4) {    // node W2, permuted rows
        if (i >= 16384) return;
        int n = i >> 7, k = i & 127;
        si = l * 16384 + k * 128 + permch(n); src = nW2_raw; dst = nW2t; di = l * 16384 + i;
    } else {                // emb W [64][128] -> [128][64], permuted rows
        if (l != 0 || i >= 8192) return;
        int n = i >> 6, k = i & 63;
        si = k * 128 + permch(n); src = embW_raw; dst = embWt; di = i;
    }
    float v = flags[0] ? bf2f(((const u16*)src)[si]) : ((const float*)src)[si];
    dst[di] = f2bf(v);
}

// ---------------- counting sort by dst (reads raw edge_index) ----------------
__global__ void cnt_kernel(const void* __restrict__ eidx, int* __restrict__ cnt,
                           const int* __restrict__ flags) {
    int e = blockIdx.x * blockDim.x + threadIdx.x;
    if (e >= N_EDGES) return;
    int dn = flags[1] ? (int)((const long long*)eidx)[N_EDGES + e]
                      : ((const int*)eidx)[N_EDGES + e];
    atomicAdd(&cnt[dn], 1);
}

__global__ __launch_bounds__(1024) void scan_kernel(const int* __restrict__ cnt,
                                                    int* __restrict__ offs) {
    __shared__ int s_part[1024];
    const int t = threadIdx.x;
    const int base = t * 40;
    int sum = 0;
    for (int j = 0; j < 40; ++j) {
        int idx = base + j;
        sum += (idx < N_NODES) ? cnt[idx] : 0;
    }
    s_part[t] = sum;
    __syncthreads();
    for (int d = 1; d < 1024; d <<= 1) {
        int v = (t >= d) ? s_part[t - d] : 0;
        __syncthreads();
        s_part[t] += v;
        __syncthreads();
    }
    int run = (t == 0) ? 0 : s_part[t - 1];
    for (int j = 0; j < 40; ++j) {
        int idx = base + j;
        if (idx < N_NODES) { offs[idx] = run; run += cnt[idx]; }
    }
    if (t == 1023) offs[N_NODES] = run;
}

__global__ void scatter_kernel(const void* __restrict__ eidx,
                               const int* __restrict__ offs, int* __restrict__ cur,
                               int* __restrict__ ssrc, int* __restrict__ sdst,
                               const int* __restrict__ flags) {
    int e = blockIdx.x * blockDim.x + threadIdx.x;
    if (e >= N_EDGES) return;
    int sn, dn;
    if (flags[1]) {
        sn = (int)((const long long*)eidx)[e];
        dn = (int)((const long long*)eidx)[N_EDGES + e];
    } else {
        sn = ((const int*)eidx)[e];
        dn = ((const int*)eidx)[N_EDGES + e];
    }
    int p = offs[dn] + atomicAdd(&cur[dn], 1);
    ssrc[p] = sn;
    sdst[p] = dn;
}

// ---------------- pos init -> f32 ----------------
__global__ void posinit_kernel(const void* __restrict__ pos_raw, float* __restrict__ posf,
                               const int* __restrict__ flags) {
    int i = blockIdx.x * blockDim.x + threadIdx.x;
    if (i < N_NODES * 3)
        posf[i] = flags[0] ? bf2f(((const u16*)pos_raw)[i]) : ((const float*)pos_raw)[i];
}

#define ACT_STRIDE 136

// ================= fused embed + uv(layer0) =================
__global__ __launch_bounds__(256, 3) void embed_uv_kernel(
    const void* __restrict__ x_raw, const u16* __restrict__ embWt, const float* __restrict__ embB,
    const u16* __restrict__ W1abt, const float* __restrict__ b1,
    u16* __restrict__ h, u16* __restrict__ uv, const int* __restrict__ flags)
{
    __shared__ __align__(16) u16 s_x[64 * 72];
    __shared__ __align__(16) u16 s_h[64 * ACT_STRIDE];
    __shared__ __align__(16) u16 s_w[128 * W_STRIDE];

    const int t = threadIdx.x;
    const int n0 = blockIdx.x * 64;
    const int wv = t >> 6, lane = t & 63, quad = lane >> 4, li = lane & 15;
    const int rowA = wv * 16 + li;
    const int rowC = wv * 16 + quad * 4;

    {   // load x rows -> bf16 LDS
        int el = t >> 2, pt4 = t & 3;
        u32* op = (u32*)s_x + el * 36 + pt4 * 8;
        if (flags[0]) {
            const u32* xp = (const u32*)x_raw + (size_t)(n0 + el) * 32 + pt4 * 8;
            *(uint4*)(op)     = *(const uint4*)(xp);
            *(uint4*)(op + 4) = *(const uint4*)(xp + 4);
        } else {
            const float* xp = (const float*)x_raw + (size_t)(n0 + el) * 64 + pt4 * 16;
#pragma unroll
            for (int j = 0; j < 8; ++j) op[j] = pk2bf(xp[2 * j], xp[2 * j + 1]);
        }
    }
    stage_w64(embWt, s_w, t, 0, 32);
    __syncthreads();

    // h = x @ embW + b  (K=64)   [permuted B: lane li -> canonical cols li*8..+7]
    float4v acc[8];
#pragma unroll
    for (int c = 0; c < 8; ++c) {
        float bias = embB[li * 8 + c];
#pragma unroll
        for (int r = 0; r < 4; ++r) acc[c][r] = bias;
    }
#pragma unroll
    for (int kk2 = 0; kk2 < 2; ++kk2) {
        const bf16x8 av = *(const bf16x8*)(s_x + rowA * 72 + kk2 * 32 + quad * 8);
#pragma unroll
        for (int c = 0; c < 8; ++c) {
            const bf16x8 bv = *(const bf16x8*)(s_w + (c * 16 + li) * W_STRIDE + kk2 * 32 + quad * 8);
            acc[c] = __builtin_amdgcn_mfma_f32_16x16x32_bf16(av, bv, acc[c], 0, 0, 0);
        }
    }
    // write h (global + LDS): contiguous uint4 per row
#pragma unroll
    for (int r = 0; r < 4; ++r) {
        u32 res[4];
#pragma unroll
        for (int c2 = 0; c2 < 4; ++c2)
            res[c2] = pk2bf(acc[2 * c2][r], acc[2 * c2 + 1][r]);
        *(uint4*)((u32*)s_h + (rowC + r) * (ACT_STRIDE / 2) + li * 4) = *(uint4*)res;
        *(uint4*)((u32*)h + (size_t)(n0 + rowC + r) * 64 + li * 4) = *(uint4*)res;
    }

    // uv = [h@W1a + b1 | h@W1b]   [permuted B per half]
    float4v a2[16];
#pragma unroll
    for (int ct = 0; ct < 16; ++ct) {
        float bias = (ct < 8) ? b1[li * 8 + ct] : 0.0f;
#pragma unroll
        for (int r = 0; r < 4; ++r) a2[ct][r] = bias;
    }
#pragma unroll
    for (int half = 0; half < 2; ++half) {
#pragma unroll
        for (int chunk = 0; chunk < 2; ++chunk) {
            __syncthreads();
            stage_w64(W1abt + half * 16384, s_w, t, chunk, 64);
            __syncthreads();
#pragma unroll
            for (int kk2 = 0; kk2 < 2; ++kk2) {
                const bf16x8 av = *(const bf16x8*)(s_h + rowA * ACT_STRIDE + chunk * 64 + kk2 * 32 + quad * 8);
#pragma unroll
                for (int c = 0; c < 8; ++c) {
                    const bf16x8 bv = *(const bf16x8*)(s_w + (c * 16 + li) * W_STRIDE + kk2 * 32 + quad * 8);
                    a2[half * 8 + c] = __builtin_amdgcn_mfma_f32_16x16x32_bf16(av, bv, a2[half * 8 + c], 0, 0, 0);
                }
            }
        }
    }
#pragma unroll
    for (int half = 0; half < 2; ++half) {
#pragma unroll
        for (int r = 0; r < 4; ++r) {
            u32 res[4];
#pragma unroll
            for (int c2 = 0; c2 < 4; ++c2)
                res[c2] = pk2bf(a2[half * 8 + 2 * c2][r], a2[half * 8 + 2 * c2 + 1][r]);
            *(uint4*)((u32*)uv + (size_t)(n0 + rowC + r) * 128 + half * 64 + li * 4) = *(uint4*)res;
        }
    }
}

// ================= edge kernel =================
#define TILE_E 64

__global__ __launch_bounds__(256, 4) void edge_mfma_kernel(
    const int* __restrict__ ssrc, const int* __restrict__ sdst,
    const u16* __restrict__ uv, const float* __restrict__ posf,
    const float* __restrict__ w1c_g,
    const u16* __restrict__ W2t, const float* __restrict__ b2,
    const u16* __restrict__ pW1t, const float* __restrict__ pb1,
    const float* __restrict__ pW2, const float* __restrict__ pb2,
    float* __restrict__ agg, float* __restrict__ pd)
{
    __shared__ __align__(16) u16 s_act[TILE_E * ACT_STRIDE];
    __shared__ __align__(16) u16 s_w[128 * W_STRIDE];
    __shared__ float s_w1c[128];
    __shared__ float s_d2[TILE_E];
    __shared__ float s_rel[TILE_E * 3];
    __shared__ int s_dstn[TILE_E];

    const int t = threadIdx.x;
    const int e0 = blockIdx.x * TILE_E;
    const int wv = t >> 6, lane = t & 63, quad = lane >> 4, li = lane & 15;
    const int rowA = wv * 16 + li;
    const int rowC = wv * 16 + quad * 4;

    // ---- gather + meta ----
    {
        const int el = t >> 2, pt4 = t & 3;
        int eg = e0 + el;
        int dNg = sdst[eg], sNg = ssrc[eg];
        const uint4* up = (const uint4*)((const u32*)uv + (size_t)dNg * 128 + pt4 * 16);
        const uint4* vp = (const uint4*)((const u32*)uv + (size_t)sNg * 128 + 64 + pt4 * 16);
        uint4 uu[4], vv[4];
#pragma unroll
        for (int q4 = 0; q4 < 4; ++q4) { uu[q4] = up[q4]; vv[q4] = vp[q4]; }

        if (t < TILE_E) {
            int e = e0 + t;
            int sN = ssrc[e], dN = sdst[e];
            s_dstn[t] = dN;
            float r0 = posf[dN * 3 + 0] - posf[sN * 3 + 0];
            float r1 = posf[dN * 3 + 1] - posf[sN * 3 + 1];
            float r2 = posf[dN * 3 + 2] - posf[sN * 3 + 2];
            s_rel[t * 3 + 0] = r0; s_rel[t * 3 + 1] = r1; s_rel[t * 3 + 2] = r2;
            s_d2[t] = r0 * r0 + r1 * r1 + r2 * r2;
        }
        if (t < 128) s_w1c[t] = w1c_g[t];
        stage_w64(W2t, s_w, t, 0, 64);
        __syncthreads();

        // ---- t1 = silu(u[dst] + v[src] + d2*w1c) ----
        float d2 = s_d2[el];
        u32* outp = (u32*)s_act + el * (ACT_STRIDE / 2) + pt4 * 16;
        const float* wc = s_w1c + pt4 * 32;
#pragma unroll
        for (int q4 = 0; q4 < 4; ++q4) {
            u32 res[4];
#pragma unroll
            for (int j = 0; j < 4; ++j) {
                u32 ua = ((const u32*)&uu[q4])[j], va = ((const u32*)&vv[q4])[j];
                int col = q4 * 8 + j * 2;
                float x0 = fmaf(d2, wc[col],     bflo(ua) + bflo(va));
                float x1 = fmaf(d2, wc[col + 1], bfhi(ua) + bfhi(va));
                res[j] = pk2bf(silu_f(x0), silu_f(x1));
            }
            *(uint4*)(outp + q4 * 4) = *(uint4*)res;
        }
    }
    __syncthreads();

    // m_pre = t1 @ W2 + b2   [permuted B: lane li -> canonical cols li*8..+7]
    float4v acc[8];
#pragma unroll
    for (int c = 0; c < 8; ++c) {
        float bias = b2[li * 8 + c];
#pragma unroll
        for (int r = 0; r < 4; ++r) acc[c][r] = bias;
    }
#pragma unroll
    for (int p = 0; p < 2; ++p) {
        if (p) {
            __syncthreads();
            stage_w64(W2t, s_w, t, 1, 64);
            __syncthreads();
        }
#pragma unroll
        for (int kk2 = 0; kk2 < 2; ++kk2) {
            const bf16x8 av = *(const bf16x8*)(s_act + rowA * ACT_STRIDE + p * 64 + kk2 * 32 + quad * 8);
#pragma unroll
            for (int c = 0; c < 8; ++c) {
                const bf16x8 bv = *(const bf16x8*)(s_w + (c * 16 + li) * W_STRIDE + kk2 * 32 + quad * 8);
                acc[c] = __builtin_amdgcn_mfma_f32_16x16x32_bf16(av, bv, acc[c], 0, 0, 0);
            }
        }
    }
    __syncthreads();

    // m -> s_act: canonical order, contiguous ds_write_b128 per row
#pragma unroll
    for (int r = 0; r < 4; ++r) {
        u32 res[4];
#pragma unroll
        for (int c2 = 0; c2 < 4; ++c2)
            res[c2] = pk2bf(silu_f(acc[2 * c2][r]), silu_f(acc[2 * c2 + 1][r]));
        *(uint4*)((u32*)s_act + (rowC + r) * (ACT_STRIDE / 2) + li * 4) = *(uint4*)res;
    }
    stage_w64(pW1t, s_w, t, 0, 64);
    __syncthreads();

    // agg segmented reduction (m is canonical in LDS)
    {
        int c32 = t & 63, grp = t >> 6;
        int r0 = grp * 16;
        float run0 = 0.f, run1 = 0.f;
        int cur = s_dstn[r0];
        for (int r = r0; r < r0 + 16; ++r) {
            int dn = s_dstn[r];
            if (dn != cur) {
                atomicAdd(&agg[(size_t)cur * HID + 2 * c32], run0);
                atomicAdd(&agg[(size_t)cur * HID + 2 * c32 + 1], run1);
                run0 = run1 = 0.f; cur = dn;
            }
            u32 mm = *((const u32*)s_act + r * (ACT_STRIDE / 2) + c32);
            run0 += bflo(mm);
            run1 += bfhi(mm);
        }
        atomicAdd(&agg[(size_t)cur * HID + 2 * c32], run0);
        atomicAdd(&agg[(size_t)cur * HID + 2 * c32 + 1], run1);
    }

    // pos MLP (pW1t NOT permuted: cols stay c*16+li, output dot-reduced only)
#pragma unroll
    for (int c = 0; c < 8; ++c) {
        float bias = pb1[c * 16 + li];
#pragma unroll
        for (int r = 0; r < 4; ++r) acc[c][r] = bias;
    }
#pragma unroll
    for (int p = 0; p < 2; ++p) {
        if (p) {
            __syncthreads();
            stage_w64(pW1t, s_w, t, 1, 64);
            __syncthreads();
        }
#pragma unroll
        for (int kk2 = 0; kk2 < 2; ++kk2) {
            const bf16x8 av = *(const bf16x8*)(s_act + rowA * ACT_STRIDE + p * 64 + kk2 * 32 + quad * 8);
#pragma unroll
            for (int c = 0; c < 8; ++c) {
                const bf16x8 bv = *(const bf16x8*)(s_w + (c * 16 + li) * W_STRIDE + kk2 * 32 + quad * 8);
                acc[c] = __builtin_amdgcn_mfma_f32_16x16x32_bf16(av, bv, acc[c], 0, 0, 0);
            }
        }
    }
    float part[4] = {0.f, 0.f, 0.f, 0.f};
#pragma unroll
    for (int c = 0; c < 8; ++c) {
        float pw = pW2[c * 16 + li];
#pragma unroll
        for (int r = 0; r < 4; ++r) part[r] += silu_f(acc[c][r]) * pw;
    }
#pragma unroll
    for (int r = 0; r < 4; ++r) {
        part[r] += __shfl_xor(part[r], 1, 64);
        part[r] += __shfl_xor(part[r], 2, 64);
        part[r] += __shfl_xor(part[r], 4, 64);
        part[r] += __shfl_xor(part[r], 8, 64);
    }
    __syncthreads();
    if (li == 0) {
        float pb2v = pb2[0];
#pragma unroll
        for (int r = 0; r < 4; ++r) s_d2[rowC + r] = part[r] + pb2v;
    }
    __syncthreads();
    if (t < 12) {
        int a = t % 3, grp = t / 3;
        int r0 = grp * 16;
        float run = 0.f;
        int cur = s_dstn[r0];
        for (int r = r0; r < r0 + 16; ++r) {
            int dn = s_dstn[r];
            if (dn != cur) {
                atomicAdd(&pd[(size_t)cur * 3 + a], run);
                run = 0.f; cur = dn;
            }
            run += s_rel[r * 3 + a] * s_d2[r];
        }
        atomicAdd(&pd[(size_t)cur * 3 + a], run);
    }
}

// ================= fused node MLP + uv(next layer) + output =================
#define A_STRIDE 264

__global__ __launch_bounds__(256, 3) void node_uv_kernel(
    const u16* __restrict__ h_in, float* __restrict__ agg,
    const u16* __restrict__ W1t, const float* __restrict__ b1,
    const u16* __restrict__ W2t, const float* __restrict__ b2,
    const u16* __restrict__ W1abt_nx, const float* __restrict__ b1_nx,
    u16* __restrict__ h_out, u16* __restrict__ uv,
    float* __restrict__ posf, float* __restrict__ pd, const int* __restrict__ cnt,
    void* __restrict__ outp, const int* __restrict__ flags, int do_out)
{
    __shared__ __align__(16) u16 s_a[64 * A_STRIDE];
    __shared__ __align__(16) u16 s_w[128 * W_STRIDE];

    const int t = threadIdx.x;
    const int n0 = blockIdx.x * 64;
    const int wv = t >> 6, lane = t & 63, quad = lane >> 4, li = lane & 15;
    const int rowA = wv * 16 + li;
    const int rowC = wv * 16 + quad * 4;

    {   // A = [h | bf16(agg)]; zero agg after read
        int nl = t >> 2, pt4 = t & 3;
        const uint4* hp = (const uint4*)((const u32*)h_in + (size_t)(n0 + nl) * 64 + pt4 * 16);
        u32* rowp = (u32*)s_a + nl * (A_STRIDE / 2) + pt4 * 16;
#pragma unroll
        for (int j = 0; j < 4; ++j) *(uint4*)(rowp + j * 4) = hp[j];
        float* ap = agg + (size_t)(n0 + nl) * HID + pt4 * 32;
        rowp += 64;
#pragma unroll
        for (int j = 0; j < 16; ++j) {
            float2 v = *(const float2*)(ap + j * 2);
            rowp[j] = pk2bf(v.x, v.y);
        }
        float4 z = {0.f, 0.f, 0.f, 0.f};
#pragma unroll
        for (int j = 0; j < 8; ++j) *(float4*)(ap + j * 4) = z;
    }
    stage_w64(W1t, s_w, t, 0, 128);
    __syncthreads();

    float4v acc[8];
#pragma unroll
    for (int c = 0; c < 8; ++c) {
        float bias = b1[li * 8 + c];
#pragma unroll
        for (int r = 0; r < 4; ++r) acc[c][r] = bias;
    }
#pragma unroll
    for (int p = 0; p < 4; ++p) {
        if (p) {
            __syncthreads();
            stage_w64(W1t, s_w, t, p, 128);
            __syncthreads();
        }
#pragma unroll
        for (int kk2 = 0; kk2 < 2; ++kk2) {
            const bf16x8 av = *(const bf16x8*)(s_a + rowA * A_STRIDE + p * 64 + kk2 * 32 + quad * 8);
#pragma unroll
            for (int c = 0; c < 8; ++c) {
                const bf16x8 bv = *(const bf16x8*)(s_w + (c * 16 + li) * W_STRIDE + kk2 * 32 + quad * 8);
                acc[c] = __builtin_amdgcn_mfma_f32_16x16x32_bf16(av, bv, acc[c], 0, 0, 0);
            }
        }
    }

    __syncthreads();
    u16* s_t1 = s_a;   // overlay; t1 canonical via permuted nW1t
#pragma unroll
    for (int r = 0; r < 4; ++r) {
        u32 res[4];
#pragma unroll
        for (int c2 = 0; c2 < 4; ++c2)
            res[c2] = pk2bf(silu_f(acc[2 * c2][r]), silu_f(acc[2 * c2 + 1][r]));
        *(uint4*)((u32*)s_t1 + (rowC + r) * (ACT_STRIDE / 2) + li * 4) = *(uint4*)res;
    }
    stage_w64(W2t, s_w, t, 0, 64);
    __syncthreads();

#pragma unroll
    for (int c = 0; c < 8; ++c) {
        float bias = b2[li * 8 + c];
#pragma unroll
        for (int r = 0; r < 4; ++r) acc[c][r] = bias;
    }
#pragma unroll
    for (int p = 0; p < 2; ++p) {
        if (p) {
            __syncthreads();
            stage_w64(W2t, s_w, t, 1, 64);
            __syncthreads();
        }
#pragma unroll
        for (int kk2 = 0; kk2 < 2; ++kk2) {
            const bf16x8 av = *(const bf16x8*)(s_t1 + rowA * ACT_STRIDE + p * 64 + kk2 * 32 + quad * 8);
#pragma unroll
            for (int c = 0; c < 8; ++c) {
                const bf16x8 bv = *(const bf16x8*)(s_w + (c * 16 + li) * W_STRIDE + kk2 * 32 + quad * 8);
                acc[c] = __builtin_amdgcn_mfma_f32_16x16x32_bf16(av, bv, acc[c], 0, 0, 0);
            }
        }
    }

    // epilogue: h (canonical cols li*8..+7 per lane)
    if (do_out) {
        if (flags[0]) {
#pragma unroll
            for (int r = 0; r < 4; ++r) {
                u32 res[4];
#pragma unroll
                for (int c2 = 0; c2 < 4; ++c2)
                    res[c2] = pk2bf(acc[2 * c2][r], acc[2 * c2 + 1][r]);
                *(uint4*)((u32*)outp + (size_t)(n0 + rowC + r) * 64 + li * 4) = *(uint4*)res;
            }
        } else {
#pragma unroll
            for (int r = 0; r < 4; ++r) {
                float* op = (float*)outp + (size_t)(n0 + rowC + r) * HID + li * 8;
                float4 lo = {acc[0][r], acc[1][r], acc[2][r], acc[3][r]};
                float4 hi = {acc[4][r], acc[5][r], acc[6][r], acc[7][r]};
                *(float4*)op = lo;
                *(float4*)(op + 4) = hi;
            }
        }
    } else {
#pragma unroll
        for (int r = 0; r < 4; ++r) {
            u32 res[4];
#pragma unroll
            for (int c2 = 0; c2 < 4; ++c2)
                res[c2] = pk2bf(acc[2 * c2][r], acc[2 * c2 + 1][r]);
            *(uint4*)((u32*)s_t1 + (rowC + r) * (ACT_STRIDE / 2) + li * 4) = *(uint4*)res;
            *(uint4*)((u32*)h_out + (size_t)(n0 + rowC + r) * 64 + li * 4) = *(uint4*)res;
        }
    }

    // pos update + pd zero (+ pos out)
    if (t < 192) {
        int nl = t / 3, a = t % 3;
        int n = n0 + nl;
        float dg = (float)cnt[n];
        dg = dg < 1.0f ? 1.0f : dg;
        float np = posf[n * 3 + a] + pd[n * 3 + a] / dg;
        posf[n * 3 + a] = np;
        pd[n * 3 + a] = 0.f;
        if (do_out) {
            if (flags[0]) ((u16*)outp)[(size_t)N_NODES * HID + n * 3 + a] = f2bf(np);
            else          ((float*)outp)[(size_t)N_NODES * HID + n * 3 + a] = np;
        }
    }

    if (do_out) return;

    // uv for next layer (reads s_t1 = new h, written above canonical)
    float4v a2[16];
#pragma unroll
    for (int ct = 0; ct < 16; ++ct) {
        float bias = (ct < 8) ? b1_nx[li * 8 + ct] : 0.0f;
#pragma unroll
        for (int r = 0; r < 4; ++r) a2[ct][r] = bias;
    }
#pragma unroll
    for (int half = 0; half < 2; ++half) {
#pragma unroll
        for (int chunk = 0; chunk < 2; ++chunk) {
            __syncthreads();
            stage_w64(W1abt_nx + half * 16384, s_w, t, chunk, 64);
            __syncthreads();
#pragma unroll
            for (int kk2 = 0; kk2 < 2; ++kk2) {
                const bf16x8 av = *(const bf16x8*)(s_t1 + rowA * ACT_STRIDE + chunk * 64 + kk2 * 32 + quad * 8);
#pragma unroll
                for (int c = 0; c < 8; ++c) {
                    const bf16x8 bv = *(const bf16x8*)(s_w + (c * 16 + li) * W_STRIDE + kk2 * 32 + quad * 8);
                    a2[half * 8 + c] = __builtin_amdgcn_mfma_f32_16x16x32_bf16(av, bv, a2[half * 8 + c], 0, 0, 0);
                }
            }
        }
    }
#pragma unroll
    for (int half = 0; half < 2; ++half) {
#pragma unroll
        for (int r = 0; r < 4; ++r) {
            u32 res[4];
#pragma unroll
            for (int c2 = 0; c2 < 4; ++c2)
                res[c2] = pk2bf(a2[half * 8 + 2 * c2][r], a2[half * 8 + 2 * c2 + 1][r]);
            *(uint4*)((u32*)uv + (size_t)(n0 + rowC + r) * 128 + half * 64 + li * 4) = *(uint4*)res;
        }
    }
}

extern "C" void kernel_launch(void* const* d_in, const int* in_sizes, int n_in,
                              void* d_out, int out_size, void* d_ws, size_t ws_size,
                              hipStream_t stream) {
    (void)in_sizes; (void)n_in; (void)out_size; (void)ws_size;

    const void* eidx_raw = d_in[0];
    const void* x_raw    = d_in[1];
    const void* pos_raw  = d_in[2];
    const void* embW_raw = d_in[3];
    const void* embB_raw = d_in[4];
    const void* eW1_raw  = d_in[5];
    const void* eB1_raw  = d_in[6];
    const void* eW2_raw  = d_in[7];
    const void* eB2_raw  = d_in[8];
    const void* nW1_raw  = d_in[9];
    const void* nB1_raw  = d_in[10];
    const void* nW2_raw  = d_in[11];
    const void* nB2_raw  = d_in[12];
    const void* pW1_raw  = d_in[13];
    const void* pB1_raw  = d_in[14];
    const void* pW2_raw  = d_in[15];
    const void* pB2_raw  = d_in[16];

    float* ws   = (float*)d_ws;
    float* posf = ws;                            //   120,000
    float* agg  = posf + (size_t)N_NODES * 3;    // 5,120,000
    float* pd   = agg + (size_t)N_NODES * HID;   //   120,000 (contiguous w/ agg)
    float* smallf = pd + (size_t)N_NODES * 3;    //     2,820
    float* embB = smallf;                        // [0,128)
    float* eB1f = smallf + 128;                  // [128,512)
    float* eB2f = smallf + 512;
    float* pB1f = smallf + 896;
    float* pB2f = smallf + 1280;
    float* pW2f = smallf + 1284;
    float* W1r  = smallf + 1668;
    float* nB1f = smallf + 2052;
    float* nB2f = smallf + 2436;

    u16* W1abt = (u16*)(smallf + 2820);          // 98,304
    u16* W2t   = W1abt + 3 * 256 * 128;          // 49,152
    u16* pW1t  = W2t + 3 * 128 * 128;            // 49,152
    u16* nW1t  = pW1t + 3 * 128 * 128;           // 98,304
    u16* nW2t  = nW1t + 3 * 128 * 256;           // 49,152
    u16* embWt = nW2t + 3 * 128 * 128;           //  8,192
    u16* h0    = embWt + 8192;                   // 5,120,000
    u16* h1    = h0 + (size_t)N_NODES * HID;     // 5,120,000
    u16* uvb   = h1 + (size_t)N_NODES * HID;     // 10,240,000
    int* ssrc  = (int*)(uvb + (size_t)N_NODES * 256);
    int* sdst  = ssrc + N_EDGES;
    int* cnt   = sdst + N_EDGES;                 // 40,000
    int* cur   = cnt + N_NODES;                  // 40,000 (contiguous for memset)
    int* offs  = cur + N_NODES;                  // 40,001
    int* flags = offs + N_NODES + 3;
    // total ws ≈ 68.7 MB

    detect_kernel<<<1, 256, 0, stream>>>(embW_raw, eidx_raw, flags);
    small_cvt_kernel<<<12, 256, 0, stream>>>(embB_raw, eB1_raw, eB2_raw, pB1_raw, pB2_raw,
                                             pW2_raw, eW1_raw, nB1_raw, nB2_raw, smallf, flags);
    wcvt_kernel<<<dim3(128, 3, 6), 256, 0, stream>>>(
        eW1_raw, eW2_raw, pW1_raw, nW1_raw, nW2_raw, embW_raw,
        W1abt, W2t, pW1t, nW1t, nW2t, embWt, flags);

    hipMemsetAsync(cnt, 0, 2 * (size_t)N_NODES * sizeof(int), stream);
    cnt_kernel<<<(N_EDGES + 255) / 256, 256, 0, stream>>>(eidx_raw, cnt, flags);
    scan_kernel<<<1, 1024, 0, stream>>>(cnt, offs);
    scatter_kernel<<<(N_EDGES + 255) / 256, 256, 0, stream>>>(eidx_raw, offs, cur, ssrc, sdst, flags);

    posinit_kernel<<<(N_NODES * 3 + 255) / 256, 256, 0, stream>>>(pos_raw, posf, flags);
    hipMemsetAsync(agg, 0, ((size_t)N_NODES * HID + (size_t)N_NODES * 3) * sizeof(float), stream);

    embed_uv_kernel<<<N_NODES / 64, 256, 0, stream>>>(x_raw, embWt, embB, W1abt, eB1f, h0, uvb, flags);

    u16* hin = h0;
    u16* hout = h1;
    for (int l = 0; l < N_LAYERS; ++l) {
        int last = (l == N_LAYERS - 1);
        edge_mfma_kernel<<<N_EDGES / TILE_E, 256, 0, stream>>>(
            ssrc, sdst, uvb, posf,
            W1r + l * HID,
            W2t + (size_t)l * 128 * 128, eB2f + l * HID,
            pW1t + (size_t)l * 128 * 128, pB1f + l * HID,
            pW2f + l * HID, pB2f + l,
            agg, pd);
        node_uv_kernel<<<N_NODES / 64, 256, 0, stream>>>(
            hin, agg,
            nW1t + (size_t)l * 128 * 256, nB1f + l * HID,
            nW2t + (size_t)l * 128 * 128, nB2f + l * HID,
            W1abt + (size_t)(last ? 0 : (l + 1)) * 32768, eB1f + (last ? 0 : (l + 1)) * HID,
            hout, uvb,
            posf, pd, cnt,
            d_out, flags, last ? 1 : 0);
        u16* tmp = hin; hin = hout; hout = tmp;
    }
}